// Round 4
// baseline (1579.722 us; speedup 1.0000x reference)
//
#include <hip/hip_runtime.h>
#include <hip/hip_bf16.h>

#define B_  2
#define S_  2048
#define DM_ 1024
#define H_  16
#define DK_ 64
#define SK_ 40   // SAMPLE_K
#define U_  40   // top-k u

// ================= fp32 tiled GEMM =================
// C[r, bx*64+c] = scale * sum_k A[r,k] * Bm[k, bcol0 + bx*64 + c]
// A: M x K row-major (ld = K). Bm: ld = ldb. C: ld = ldc.
// grid = (M/64) * (Ncols/64) blocks, 256 threads, 4x4 microtile.
__global__ void sgemm(const float* __restrict__ A, const float* __restrict__ Bm,
                      float* __restrict__ C, int M, int Ncols, int K,
                      int ldb, int ldc, int bcol0, float scale) {
    __shared__ float As[16][65];
    __shared__ float Bs[16][65];
    int ntx = Ncols >> 6;
    int by = blockIdx.x / ntx, bx = blockIdx.x % ntx;
    int t = threadIdx.x;
    int tx = t & 15, ty = t >> 4;
    float acc[4][4] = {{0.f}};
    const float* Ab = A + (size_t)(by * 64) * K;
    const float* Bb = Bm + bcol0 + bx * 64;

    int ar = t >> 2, akq = (t & 3) << 2;   // A-tile load: row, 4-k chunk
    int bk = t >> 4, bc = (t & 15) << 2;   // B-tile load: k, 4-col chunk

    for (int k0 = 0; k0 < K; k0 += 16) {
        float4 av = *(const float4*)(Ab + (size_t)ar * K + k0 + akq);
        As[akq + 0][ar] = av.x; As[akq + 1][ar] = av.y;
        As[akq + 2][ar] = av.z; As[akq + 3][ar] = av.w;
        float4 bv = *(const float4*)(Bb + (size_t)(k0 + bk) * ldb + bc);
        Bs[bk][bc + 0] = bv.x; Bs[bk][bc + 1] = bv.y;
        Bs[bk][bc + 2] = bv.z; Bs[bk][bc + 3] = bv.w;
        __syncthreads();
#pragma unroll
        for (int kk = 0; kk < 16; ++kk) {
            float a[4], b[4];
#pragma unroll
            for (int i = 0; i < 4; ++i) a[i] = As[kk][ty * 4 + i];
#pragma unroll
            for (int j = 0; j < 4; ++j) b[j] = Bs[kk][tx * 4 + j];
#pragma unroll
            for (int i = 0; i < 4; ++i)
#pragma unroll
                for (int j = 0; j < 4; ++j) acc[i][j] += a[i] * b[j];
        }
        __syncthreads();
    }
#pragma unroll
    for (int i = 0; i < 4; ++i)
#pragma unroll
        for (int j = 0; j < 4; ++j)
            C[(size_t)(by * 64 + ty * 4 + i) * ldc + bx * 64 + tx * 4 + j] =
                acc[i][j] * scale;
}

// ================= m = max - sum/S over sampled dots, one wave per (b,h,l)
__global__ void m_score_kernel(const float* __restrict__ q,
                               const float* __restrict__ k,
                               const int* __restrict__ idxs,
                               float* __restrict__ m_out) {
    int gwave = blockIdx.x * 4 + (threadIdx.x >> 6);
    int lane = threadIdx.x & 63;
    if (gwave >= B_ * H_ * S_) return;
    int l = gwave % S_;
    int bh = gwave / S_;
    int h = bh % H_, b = bh / H_;

    float qv = q[((size_t)(b * S_ + l)) * DM_ + h * DK_ + lane];
    const float* kb = k + (size_t)b * S_ * DM_ + h * DK_;
    float maxv = -INFINITY, sumv = 0.f;
    for (int s = 0; s < SK_; ++s) {
        int idx = idxs[l * SK_ + s];
        idx = (idx < 0) ? 0 : (idx >= S_ ? S_ - 1 : idx);
        float p = qv * kb[(size_t)idx * DM_ + lane];
#pragma unroll
        for (int off = 32; off; off >>= 1) p += __shfl_xor(p, off, 64);
        maxv = fmaxf(maxv, p);
        sumv += p;
    }
    if (lane == 0) m_out[(size_t)bh * S_ + l] = maxv - sumv * (1.f / (float)S_);
}

// ================= top-40 per block: iterative masked argmax
__global__ void topk_kernel(const float* __restrict__ m, int* __restrict__ mtop) {
    __shared__ float vals[S_];
    __shared__ float rv[256];
    __shared__ int ri[256];
    int bh = blockIdx.x, tid = threadIdx.x;
    for (int i = tid; i < S_; i += 256) vals[i] = m[(size_t)bh * S_ + i];
    __syncthreads();
    for (int it = 0; it < U_; ++it) {
        float best = -INFINITY;
        int bi = -1;
        for (int i = tid; i < S_; i += 256) {
            float v = vals[i];
            if (v > best) { best = v; bi = i; }
        }
        rv[tid] = best; ri[tid] = bi;
        __syncthreads();
        for (int s = 128; s; s >>= 1) {
            if (tid < s) {
                if ((ri[tid] < 0 && ri[tid + s] >= 0) ||
                    (ri[tid + s] >= 0 &&
                     (rv[tid + s] > rv[tid] ||
                      (rv[tid + s] == rv[tid] && ri[tid + s] < ri[tid])))) {
                    rv[tid] = rv[tid + s]; ri[tid] = ri[tid + s];
                }
            }
            __syncthreads();
        }
        if (tid == 0) {
            int r0 = (ri[0] >= 0 && ri[0] < S_) ? ri[0] : 0;  // defensive: never OOB
            mtop[bh * U_ + it] = r0;
            vals[r0] = -INFINITY;
        }
        __syncthreads();
    }
}

// ================= v mean over S per (b,h)
__global__ void vmean_kernel(const float* __restrict__ v, float* __restrict__ vm) {
    __shared__ float part[4][DK_];
    int bh = blockIdx.x, tid = threadIdx.x;
    int wave = tid >> 6, lane = tid & 63;
    int b = bh / H_, h = bh % H_;
    const float* vb = v + (size_t)b * S_ * DM_ + h * DK_;
    float s = 0.f;
    for (int l = wave; l < S_; l += 4) s += vb[(size_t)l * DM_ + lane];
    part[wave][lane] = s;
    __syncthreads();
    if (tid < DK_)
        vm[bh * DK_ + tid] =
            (part[0][tid] + part[1][tid] + part[2][tid] + part[3][tid]) * (1.f / (float)S_);
}

// ================= dense attention for selected rows: block per (b,h,u)
__global__ void attn_kernel(const float* __restrict__ q, const float* __restrict__ k,
                            const float* __restrict__ v, const int* __restrict__ mtop,
                            float* __restrict__ upd) {
    __shared__ float sc[S_];
    __shared__ float red[256];
    __shared__ float part[4][DK_];
    int blk = blockIdx.x;          // bh*40 + u
    int bh = blk / U_;
    int b = bh / H_, h = bh % H_;
    int tid = threadIdx.x, wave = tid >> 6, lane = tid & 63;

    int row = mtop[blk];
    row = (row < 0) ? 0 : (row >= S_ ? S_ - 1 : row);
    float qv = q[((size_t)(b * S_ + row)) * DM_ + h * DK_ + lane];
    const float* kb = k + (size_t)b * S_ * DM_ + h * DK_;
    for (int kk = wave; kk < S_; kk += 4) {
        float p = qv * kb[(size_t)kk * DM_ + lane];
#pragma unroll
        for (int off = 32; off; off >>= 1) p += __shfl_xor(p, off, 64);
        if (lane == 0) sc[kk] = p;
    }
    __syncthreads();
    float mx = -INFINITY;
    for (int i = tid; i < S_; i += 256) mx = fmaxf(mx, sc[i]);
    red[tid] = mx;
    __syncthreads();
    for (int s = 128; s; s >>= 1) {
        if (tid < s) red[tid] = fmaxf(red[tid], red[tid + s]);
        __syncthreads();
    }
    mx = red[0];
    __syncthreads();
    float sm = 0.f;
    for (int i = tid; i < S_; i += 256) {
        float e = expf(sc[i] - mx);
        sc[i] = e;
        sm += e;
    }
    red[tid] = sm;
    __syncthreads();
    for (int s = 128; s; s >>= 1) {
        if (tid < s) red[tid] += red[tid + s];
        __syncthreads();
    }
    float denom = red[0];
    __syncthreads();
    const float* vb = v + (size_t)b * S_ * DM_ + h * DK_;
    float acc = 0.f;
    for (int kk = wave; kk < S_; kk += 4) acc += sc[kk] * vb[(size_t)kk * DM_ + lane];
    part[wave][lane] = acc;
    __syncthreads();
    if (tid < DK_) {
        float tot = part[0][tid] + part[1][tid] + part[2][tid] + part[3][tid];
        upd[(size_t)blk * DK_ + tid] = tot / denom;
    }
}

// ================= ctx = broadcast v_mean (fp32)
__global__ void ctx_fill(const float* __restrict__ vm, float* __restrict__ ctx) {
    size_t i = (size_t)blockIdx.x * 256 + threadIdx.x;  // over B*S*DM
    int c = (int)(i & (DM_ - 1));
    size_t bl = i >> 10;
    int b = (int)(bl >> 11);
    int h = c >> 6, d = c & (DK_ - 1);
    ctx[i] = vm[(b * H_ + h) * DK_ + d];
}

// ================= scatter upd rows into ctx
__global__ void ctx_scatter(const float* __restrict__ upd, const int* __restrict__ mtop,
                            float* __restrict__ ctx) {
    int blk = blockIdx.x;
    int bh = blk / U_;
    int b = bh / H_, h = bh % H_;
    int lane = threadIdx.x;
    int row = mtop[blk];
    row = (row < 0) ? 0 : (row >= S_ ? S_ - 1 : row);
    ctx[((size_t)(b * S_ + row)) * DM_ + h * DK_ + lane] = upd[(size_t)blk * DK_ + lane];
}

// ================= bias + residual + LayerNorm, block per row (all fp32)
__global__ void ln_kernel(const float* __restrict__ fcout, const float* __restrict__ fcb,
                          const float* __restrict__ resid,
                          const float* __restrict__ lnw, const float* __restrict__ lnb,
                          float* __restrict__ out) {
    __shared__ float red[256];
    int row = blockIdx.x, tid = threadIdx.x;
    float x[4];
#pragma unroll
    for (int j = 0; j < 4; ++j) {
        int c = tid + j * 256;
        x[j] = fcout[(size_t)row * DM_ + c] + fcb[c] + resid[(size_t)row * DM_ + c];
    }
    float s = x[0] + x[1] + x[2] + x[3];
    red[tid] = s;
    __syncthreads();
    for (int st = 128; st; st >>= 1) {
        if (tid < st) red[tid] += red[tid + st];
        __syncthreads();
    }
    float mu = red[0] * (1.f / (float)DM_);
    __syncthreads();
    float vs = 0.f;
#pragma unroll
    for (int j = 0; j < 4; ++j) { float d = x[j] - mu; vs += d * d; }
    red[tid] = vs;
    __syncthreads();
    for (int st = 128; st; st >>= 1) {
        if (tid < st) red[tid] += red[tid + st];
        __syncthreads();
    }
    float rstd = rsqrtf(red[0] * (1.f / (float)DM_) + 1e-6f);
#pragma unroll
    for (int j = 0; j < 4; ++j) {
        int c = tid + j * 256;
        out[(size_t)row * DM_ + c] = (x[j] - mu) * rstd * lnw[c] + lnb[c];
    }
}

// ================= Path B extras (small ws, per-(b,h)) =================

__global__ void m_score_h(const float* __restrict__ qh, const float* __restrict__ kh,
                          const int* __restrict__ idxs, float* __restrict__ m_out) {
    int l = blockIdx.x * 4 + (threadIdx.x >> 6);
    int lane = threadIdx.x & 63;
    float qv = qh[(size_t)l * DK_ + lane];
    float maxv = -INFINITY, sumv = 0.f;
    for (int s = 0; s < SK_; ++s) {
        int idx = idxs[l * SK_ + s];
        idx = (idx < 0) ? 0 : (idx >= S_ ? S_ - 1 : idx);
        float p = qv * kh[(size_t)idx * DK_ + lane];
#pragma unroll
        for (int off = 32; off; off >>= 1) p += __shfl_xor(p, off, 64);
        maxv = fmaxf(maxv, p);
        sumv += p;
    }
    if (lane == 0) m_out[l] = maxv - sumv * (1.f / (float)S_);
}

__global__ void vmean_h(const float* __restrict__ vh, float* __restrict__ vm) {
    __shared__ float part[4][DK_];
    int tid = threadIdx.x, wave = tid >> 6, lane = tid & 63;
    float s = 0.f;
    for (int l = wave; l < S_; l += 4) s += vh[(size_t)l * DK_ + lane];
    part[wave][lane] = s;
    __syncthreads();
    if (tid < DK_)
        vm[tid] = (part[0][tid] + part[1][tid] + part[2][tid] + part[3][tid]) *
                  (1.f / (float)S_);
}

__global__ void attn_h(const float* __restrict__ qh, const float* __restrict__ kh,
                       const float* __restrict__ vh, const int* __restrict__ mtop,
                       float* __restrict__ upd) {
    __shared__ float sc[S_];
    __shared__ float red[256];
    __shared__ float part[4][DK_];
    int blk = blockIdx.x;
    int tid = threadIdx.x, wave = tid >> 6, lane = tid & 63;
    int row = mtop[blk];
    row = (row < 0) ? 0 : (row >= S_ ? S_ - 1 : row);
    float qv = qh[(size_t)row * DK_ + lane];
    for (int kk = wave; kk < S_; kk += 4) {
        float p = qv * kh[(size_t)kk * DK_ + lane];
#pragma unroll
        for (int off = 32; off; off >>= 1) p += __shfl_xor(p, off, 64);
        if (lane == 0) sc[kk] = p;
    }
    __syncthreads();
    float mx = -INFINITY;
    for (int i = tid; i < S_; i += 256) mx = fmaxf(mx, sc[i]);
    red[tid] = mx;
    __syncthreads();
    for (int s = 128; s; s >>= 1) {
        if (tid < s) red[tid] = fmaxf(red[tid], red[tid + s]);
        __syncthreads();
    }
    mx = red[0];
    __syncthreads();
    float sm = 0.f;
    for (int i = tid; i < S_; i += 256) {
        float e = expf(sc[i] - mx);
        sc[i] = e;
        sm += e;
    }
    red[tid] = sm;
    __syncthreads();
    for (int s = 128; s; s >>= 1) {
        if (tid < s) red[tid] += red[tid + s];
        __syncthreads();
    }
    float denom = red[0];
    __syncthreads();
    float acc = 0.f;
    for (int kk = wave; kk < S_; kk += 4) acc += sc[kk] * vh[(size_t)kk * DK_ + lane];
    part[wave][lane] = acc;
    __syncthreads();
    if (tid < DK_) {
        float tot = part[0][tid] + part[1][tid] + part[2][tid] + part[3][tid];
        upd[(size_t)blk * DK_ + tid] = tot / denom;
    }
}

__global__ void fill_h(const float* __restrict__ vm, float* __restrict__ ctx,
                       int b, int h) {
    int i = blockIdx.x * 256 + threadIdx.x;  // < S_*DK_
    int l = i >> 6, d = i & 63;
    ctx[((size_t)(b * S_ + l)) * DM_ + h * DK_ + d] = vm[d];
}

__global__ void scatter_h(const float* __restrict__ upd, const int* __restrict__ mtop,
                          float* __restrict__ ctx, int b, int h) {
    int blk = blockIdx.x;
    int lane = threadIdx.x;
    int row = mtop[blk];
    row = (row < 0) ? 0 : (row >= S_ ? S_ - 1 : row);
    ctx[((size_t)(b * S_ + row)) * DM_ + h * DK_ + lane] = upd[(size_t)blk * DK_ + lane];
}

// Fused fc + bias + residual + LN, row-local, in-place safe on ctx==out.
__global__ void fcln_kernel(const float* __restrict__ ctx, const float* __restrict__ fcw,
                            const float* __restrict__ fcb, const float* __restrict__ resid,
                            const float* __restrict__ lnw, const float* __restrict__ lnb,
                            float* __restrict__ out) {
    __shared__ float crow[DM_];
    __shared__ float red[256];
    int row = blockIdx.x, tid = threadIdx.x;
    for (int i = tid; i < DM_; i += 256) crow[i] = ctx[(size_t)row * DM_ + i];
    __syncthreads();
    float acc[4] = {0.f, 0.f, 0.f, 0.f};
    for (int jj = 0; jj < DM_; ++jj) {
        float cv = crow[jj];
#pragma unroll
        for (int j = 0; j < 4; ++j) acc[j] += cv * fcw[(size_t)jj * DM_ + tid + j * 256];
    }
    float x[4];
#pragma unroll
    for (int j = 0; j < 4; ++j) {
        int c = tid + j * 256;
        x[j] = acc[j] + fcb[c] + resid[(size_t)row * DM_ + c];
    }
    float s = x[0] + x[1] + x[2] + x[3];
    red[tid] = s;
    __syncthreads();
    for (int st = 128; st; st >>= 1) {
        if (tid < st) red[tid] += red[tid + st];
        __syncthreads();
    }
    float mu = red[0] * (1.f / (float)DM_);
    __syncthreads();
    float vs = 0.f;
#pragma unroll
    for (int j = 0; j < 4; ++j) { float d = x[j] - mu; vs += d * d; }
    red[tid] = vs;
    __syncthreads();
    for (int st = 128; st; st >>= 1) {
        if (tid < st) red[tid] += red[tid + st];
        __syncthreads();
    }
    float rstd = rsqrtf(red[0] * (1.f / (float)DM_) + 1e-6f);
#pragma unroll
    for (int j = 0; j < 4; ++j) {
        int c = tid + j * 256;
        out[(size_t)row * DM_ + c] = (x[j] - mu) * rstd * lnw[c] + lnb[c];
    }
}

// ================= launch =================

extern "C" void kernel_launch(void* const* d_in, const int* in_sizes, int n_in,
                              void* d_out, int out_size, void* d_ws, size_t ws_size,
                              hipStream_t stream) {
    if (n_in < 9 || d_ws == nullptr || d_out == nullptr) return;

    const float* hs  = (const float*)d_in[0];
    const float* wq  = (const float*)d_in[1];
    const float* wk  = (const float*)d_in[2];
    const float* wv  = (const float*)d_in[3];
    const float* fcw = (const float*)d_in[4];
    const float* fcb = (const float*)d_in[5];
    const float* lnw = (const float*)d_in[6];
    const float* lnb = (const float*)d_in[7];
    const int* idxs  = (const int*)d_in[8];

    const size_t MD = (size_t)B_ * S_ * DM_;  // 4194304
    const int M = B_ * S_;                    // 4096
    float* ws = (float*)d_ws;
    float* out = (float*)d_out;

    const size_t needA = 34ull * 1024 * 1024 + (1ull << 20);  // ≈35MB > 32.6MB used
    const size_t needB = 2ull << 20;

    if (ws_size >= needA) {
        // Path A: q [0,MD), k [MD,2MD), smalls [2MD,+0.6MB); v lives in d_out;
        // ctx aliases q (dead after attn); fcout aliases k (dead after attn).
        float* q = ws;
        float* k = ws + MD;
        float* mbuf = ws + 2 * MD;                             // B*H*S
        float* vmean = mbuf + (size_t)B_ * H_ * S_;            // 2048
        float* upd = vmean + B_ * H_ * DK_;                    // 81920
        int* mtop = (int*)(upd + (size_t)B_ * H_ * U_ * DK_);  // 1280
        float* v = out;       // 16 MB fp32, dead before ln writes out
        float* ctx = q;
        float* fcout = k;

        sgemm<<<1024, 256, 0, stream>>>(hs, wq, q, M, DM_, DM_, DM_, DM_, 0, 0.125f);
        sgemm<<<1024, 256, 0, stream>>>(hs, wk, k, M, DM_, DM_, DM_, DM_, 0, 1.0f);
        sgemm<<<1024, 256, 0, stream>>>(hs, wv, v, M, DM_, DM_, DM_, DM_, 0, 1.0f);

        m_score_kernel<<<(B_ * H_ * S_) / 4, 256, 0, stream>>>(q, k, idxs, mbuf);
        topk_kernel<<<B_ * H_, 256, 0, stream>>>(mbuf, mtop);
        vmean_kernel<<<B_ * H_, 256, 0, stream>>>(v, vmean);
        attn_kernel<<<B_ * H_ * U_, 256, 0, stream>>>(q, k, v, mtop, upd);

        ctx_fill<<<(int)(MD / 256), 256, 0, stream>>>(vmean, ctx);
        ctx_scatter<<<B_ * H_ * U_, 64, 0, stream>>>(upd, mtop, ctx);

        sgemm<<<1024, 256, 0, stream>>>(ctx, fcw, fcout, M, DM_, DM_, DM_, DM_, 0, 1.0f);
        ln_kernel<<<M, 256, 0, stream>>>(fcout, fcb, hs, lnw, lnb, out);
    } else if (ws_size >= needB) {
        // Path B: per-(b,h) slices; ctx lives in d_out; fused in-place fc+LN.
        float* qh = ws;                        // 131072 f
        float* kh = qh + (size_t)S_ * DK_;
        float* vh = kh + (size_t)S_ * DK_;
        float* mbufh = vh + (size_t)S_ * DK_;  // 2048 f
        float* vmh = mbufh + S_;               // 64 f
        float* updh = vmh + DK_;               // 2560 f
        int* mtoph = (int*)(updh + U_ * DK_);  // 40 i
        float* ctx = out;

        for (int b = 0; b < B_; ++b) {
            const float* hsb = hs + (size_t)b * S_ * DM_;
            for (int h = 0; h < H_; ++h) {
                sgemm<<<32, 256, 0, stream>>>(hsb, wq, qh, S_, 64, DM_, DM_, 64, h * DK_, 0.125f);
                sgemm<<<32, 256, 0, stream>>>(hsb, wk, kh, S_, 64, DM_, DM_, 64, h * DK_, 1.0f);
                sgemm<<<32, 256, 0, stream>>>(hsb, wv, vh, S_, 64, DM_, DM_, 64, h * DK_, 1.0f);
                m_score_h<<<512, 256, 0, stream>>>(qh, kh, idxs, mbufh);
                topk_kernel<<<1, 256, 0, stream>>>(mbufh, mtoph);
                vmean_h<<<1, 256, 0, stream>>>(vh, vmh);
                attn_h<<<U_, 256, 0, stream>>>(qh, kh, vh, mtoph, updh);
                fill_h<<<512, 256, 0, stream>>>(vmh, ctx, b, h);
                scatter_h<<<U_, 64, 0, stream>>>(updh, mtoph, ctx, b, h);
            }
        }
        fcln_kernel<<<M, 256, 0, stream>>>(ctx, fcw, fcb, hs, lnw, lnb, out);
    }
    // else: ws too small — launch nothing (clean absmax fail = diagnostic)
}

// Round 6
// 1059.244 us; speedup vs baseline: 1.4914x; 1.4914x over previous
//
#include <hip/hip_runtime.h>
#include <hip/hip_bf16.h>

#define B_  2
#define S_  2048
#define DM_ 1024
#define H_  16
#define DK_ 64
#define SK_ 40   // SAMPLE_K
#define U_  40   // top-k u

typedef __attribute__((ext_vector_type(8))) short short8;
typedef __attribute__((ext_vector_type(4))) float f32x4;

union BF16S { __hip_bfloat16 h; short s; };
static __device__ __forceinline__ short f2bs(float x) {
    BF16S u; u.h = __float2bfloat16(x); return u.s;
}

// ================= fp32 GEMM, 128x128 tile, 8x8 microtile (for q,k: fp32-exact)
__global__ __launch_bounds__(256) void sgemm_v2(const float* __restrict__ A,
                                                const float* __restrict__ Bm,
                                                float* __restrict__ C,
                                                int M, int N, int K, float scale) {
    __shared__ float As[16][136];  // [k][m], padded
    __shared__ float Bs[16][136];  // [k][n], padded
    int nbx = N >> 7;
    int by = blockIdx.x / nbx, bx = blockIdx.x % nbx;
    int tid = threadIdx.x;
    int tx = tid & 15, ty = tid >> 4;
    float acc[8][8] = {{0.f}};
    const float* Ab = A + (size_t)(by * 128) * K;
    const float* Bb = Bm + bx * 128;
    int arow = tid >> 1, akq = (tid & 1) * 8;
    int bkk = tid >> 4, bnq = (tid & 15) * 8;

    for (int k0 = 0; k0 < K; k0 += 16) {
        float4 a0 = *(const float4*)(Ab + (size_t)arow * K + k0 + akq);
        float4 a1 = *(const float4*)(Ab + (size_t)arow * K + k0 + akq + 4);
        As[akq + 0][arow] = a0.x; As[akq + 1][arow] = a0.y;
        As[akq + 2][arow] = a0.z; As[akq + 3][arow] = a0.w;
        As[akq + 4][arow] = a1.x; As[akq + 5][arow] = a1.y;
        As[akq + 6][arow] = a1.z; As[akq + 7][arow] = a1.w;
        float4 b0 = *(const float4*)(Bb + (size_t)(k0 + bkk) * N + bnq);
        float4 b1 = *(const float4*)(Bb + (size_t)(k0 + bkk) * N + bnq + 4);
        *(float4*)&Bs[bkk][bnq] = b0;
        *(float4*)&Bs[bkk][bnq + 4] = b1;
        __syncthreads();
#pragma unroll
        for (int kk = 0; kk < 16; ++kk) {
            float av[8], bv[8];
            *(float4*)&av[0] = *(const float4*)&As[kk][ty * 8];
            *(float4*)&av[4] = *(const float4*)&As[kk][ty * 8 + 4];
            *(float4*)&bv[0] = *(const float4*)&Bs[kk][tx * 8];
            *(float4*)&bv[4] = *(const float4*)&Bs[kk][tx * 8 + 4];
#pragma unroll
            for (int i = 0; i < 8; ++i)
#pragma unroll
                for (int j = 0; j < 8; ++j) acc[i][j] += av[i] * bv[j];
        }
        __syncthreads();
    }
#pragma unroll
    for (int i = 0; i < 8; ++i) {
        int row = by * 128 + ty * 8 + i;
        float4 c0 = {acc[i][0] * scale, acc[i][1] * scale, acc[i][2] * scale, acc[i][3] * scale};
        float4 c1 = {acc[i][4] * scale, acc[i][5] * scale, acc[i][6] * scale, acc[i][7] * scale};
        *(float4*)&C[(size_t)row * N + bx * 128 + tx * 8] = c0;
        *(float4*)&C[(size_t)row * N + bx * 128 + tx * 8 + 4] = c1;
    }
}

// ================= bf16 MFMA GEMM (fp32 in/out, convert in staging), 128x128, BK=32
__global__ __launch_bounds__(256) void mfma_gemm(const float* __restrict__ A,
                                                 const float* __restrict__ Bm,
                                                 float* __restrict__ C,
                                                 int M, int N, int K, float scale) {
    __shared__ __hip_bfloat16 Asb[128][40];  // [m][k], pad 32->40
    __shared__ __hip_bfloat16 Bsb[128][40];  // [n][k] (transposed)
    int nbx = N >> 7;
    int by = blockIdx.x / nbx, bx = blockIdx.x % nbx;
    int tid = threadIdx.x;
    int lane = tid & 63, w = tid >> 6;
    int wm = (w & 1) * 64, wn = (w >> 1) * 64;
    int ml = lane & 15, kq = lane >> 4;

    f32x4 acc[4][4];
#pragma unroll
    for (int i = 0; i < 4; ++i)
#pragma unroll
        for (int j = 0; j < 4; ++j) acc[i][j] = (f32x4){0.f, 0.f, 0.f, 0.f};

    const float* Ab = A + (size_t)(by * 128) * K;
    const float* Bb = Bm + bx * 128;
    int arow = tid >> 3, akq = (tid & 7) * 4;
    int bkk = tid >> 3, bnq = (tid & 7) * 4;

    for (int k0 = 0; k0 < K; k0 += 32) {
#pragma unroll
        for (int i = 0; i < 4; ++i) {
            int r = arow + i * 32;
            float4 v4 = *(const float4*)(Ab + (size_t)r * K + k0 + akq);
            Asb[r][akq + 0] = __float2bfloat16(v4.x);
            Asb[r][akq + 1] = __float2bfloat16(v4.y);
            Asb[r][akq + 2] = __float2bfloat16(v4.z);
            Asb[r][akq + 3] = __float2bfloat16(v4.w);
        }
#pragma unroll
        for (int i = 0; i < 4; ++i) {
            int n = bnq + i * 32;
            float4 v4 = *(const float4*)(Bb + (size_t)(k0 + bkk) * N + n);
            Bsb[n + 0][bkk] = __float2bfloat16(v4.x);
            Bsb[n + 1][bkk] = __float2bfloat16(v4.y);
            Bsb[n + 2][bkk] = __float2bfloat16(v4.z);
            Bsb[n + 3][bkk] = __float2bfloat16(v4.w);
        }
        __syncthreads();
        short8 af[4], bf[4];
#pragma unroll
        for (int t = 0; t < 4; ++t) af[t] = *(const short8*)&Asb[wm + t * 16 + ml][kq * 8];
#pragma unroll
        for (int t = 0; t < 4; ++t) bf[t] = *(const short8*)&Bsb[wn + t * 16 + ml][kq * 8];
#pragma unroll
        for (int i = 0; i < 4; ++i)
#pragma unroll
            for (int j = 0; j < 4; ++j)
                acc[i][j] = __builtin_amdgcn_mfma_f32_16x16x32_bf16(af[i], bf[j], acc[i][j], 0, 0, 0);
        __syncthreads();
    }
#pragma unroll
    for (int i = 0; i < 4; ++i)
#pragma unroll
        for (int j = 0; j < 4; ++j)
#pragma unroll
            for (int r = 0; r < 4; ++r) {
                int row = by * 128 + wm + i * 16 + kq * 4 + r;
                int col = bx * 128 + wn + j * 16 + ml;
                C[(size_t)row * N + col] = acc[i][j][r] * scale;
            }
}

// ================= m = max - sum/S over sampled dots, one wave per (b,h,l)
__global__ void m_score_kernel(const float* __restrict__ q, const float* __restrict__ k,
                               const int* __restrict__ idxs, float* __restrict__ m_out) {
    int gwave = blockIdx.x * 4 + (threadIdx.x >> 6);
    int lane = threadIdx.x & 63;
    if (gwave >= B_ * H_ * S_) return;
    int l = gwave % S_;
    int bh = gwave / S_;
    int h = bh % H_, b = bh / H_;

    float qv = q[((size_t)(b * S_ + l)) * DM_ + h * DK_ + lane];
    const float* kb = k + (size_t)b * S_ * DM_ + h * DK_;
    float maxv = -INFINITY, sumv = 0.f;
    for (int s = 0; s < SK_; ++s) {
        int idx = idxs[l * SK_ + s];
        idx = (idx < 0) ? 0 : (idx >= S_ ? S_ - 1 : idx);
        float p = qv * kb[(size_t)idx * DM_ + lane];
#pragma unroll
        for (int off = 32; off; off >>= 1) p += __shfl_xor(p, off, 64);
        maxv = fmaxf(maxv, p);
        sumv += p;
    }
    if (lane == 0) m_out[(size_t)bh * S_ + l] = maxv - sumv * (1.f / (float)S_);
}

// ================= top-40 per block: iterative masked argmax
__global__ void topk_kernel(const float* __restrict__ m, int* __restrict__ mtop) {
    __shared__ float vals[S_];
    __shared__ float rv[256];
    __shared__ int ri[256];
    int bh = blockIdx.x, tid = threadIdx.x;
    for (int i = tid; i < S_; i += 256) vals[i] = m[(size_t)bh * S_ + i];
    __syncthreads();
    for (int it = 0; it < U_; ++it) {
        float best = -INFINITY;
        int bi = -1;
        for (int i = tid; i < S_; i += 256) {
            float v = vals[i];
            if (v > best) { best = v; bi = i; }
        }
        rv[tid] = best; ri[tid] = bi;
        __syncthreads();
        for (int s = 128; s; s >>= 1) {
            if (tid < s) {
                if ((ri[tid] < 0 && ri[tid + s] >= 0) ||
                    (ri[tid + s] >= 0 &&
                     (rv[tid + s] > rv[tid] ||
                      (rv[tid + s] == rv[tid] && ri[tid + s] < ri[tid])))) {
                    rv[tid] = rv[tid + s]; ri[tid] = ri[tid + s];
                }
            }
            __syncthreads();
        }
        if (tid == 0) {
            int r0 = (ri[0] >= 0 && ri[0] < S_) ? ri[0] : 0;
            mtop[bh * U_ + it] = r0;
            vals[r0] = -INFINITY;
        }
        __syncthreads();
    }
}

// ================= v mean over S per (b,h)
__global__ void vmean_kernel(const float* __restrict__ v, float* __restrict__ vm) {
    __shared__ float part[4][DK_];
    int bh = blockIdx.x, tid = threadIdx.x;
    int wave = tid >> 6, lane = tid & 63;
    int b = bh / H_, h = bh % H_;
    const float* vb = v + (size_t)b * S_ * DM_ + h * DK_;
    float s = 0.f;
    for (int l = wave; l < S_; l += 4) s += vb[(size_t)l * DM_ + lane];
    part[wave][lane] = s;
    __syncthreads();
    if (tid < DK_)
        vm[bh * DK_ + tid] =
            (part[0][tid] + part[1][tid] + part[2][tid] + part[3][tid]) * (1.f / (float)S_);
}

// ================= gather selected q rows -> qsel[bh][48][64] (rows 40..47 zero)
__global__ void gather_qsel(const float* __restrict__ q, const int* __restrict__ mtop,
                            float* __restrict__ qsel) {
    int bh = blockIdx.x;
    int b = bh >> 4, h = bh & 15;
    int tid = threadIdx.x;
    int u = tid >> 2, dq = (tid & 3) * 16;
    if (u >= 48) return;
    float* dst = qsel + ((size_t)bh * 48 + u) * 64 + dq;
    if (u < U_) {
        int row = mtop[bh * U_ + u];
        row = (row < 0) ? 0 : (row >= S_ ? S_ - 1 : row);
        const float* src = q + ((size_t)(b * S_ + row)) * DM_ + h * DK_ + dq;
#pragma unroll
        for (int j = 0; j < 16; j += 4) *(float4*)(dst + j) = *(const float4*)(src + j);
    } else {
        float4 z = {0.f, 0.f, 0.f, 0.f};
#pragma unroll
        for (int j = 0; j < 16; j += 4) *(float4*)(dst + j) = z;
    }
}

// ================= MFMA attention: block per (b,h). Sm = global scratch [32][48][2048]
__global__ __launch_bounds__(256) void attn_mfma(const float* __restrict__ qsel,
                                                 const float* __restrict__ k,
                                                 const float* __restrict__ v,
                                                 float* __restrict__ Sm,
                                                 float* __restrict__ upd) {
    __shared__ __hip_bfloat16 Qs[48][72];    // [u][d], pad 64->72
    __shared__ __hip_bfloat16 Vt[64][264];   // [d][kk-chunk], pad 256->264
    __shared__ float rmax[48], rsum[48];
    int bh = blockIdx.x;
    int b = bh >> 4, h = bh & 15;
    int tid = threadIdx.x, lane = tid & 63, w = tid >> 6;
    int ml = lane & 15, kq = lane >> 4;
    float* Sb = Sm + (size_t)bh * 48 * 2048;

    // load Qs (bf16)
    {
        int u = tid >> 2, dq = (tid & 3) * 16;
        if (u < 48) {
            const float* src = qsel + ((size_t)bh * 48 + u) * 64 + dq;
#pragma unroll
            for (int j = 0; j < 16; j += 4) {
                float4 v4 = *(const float4*)(src + j);
                Qs[u][dq + j + 0] = __float2bfloat16(v4.x);
                Qs[u][dq + j + 1] = __float2bfloat16(v4.y);
                Qs[u][dq + j + 2] = __float2bfloat16(v4.z);
                Qs[u][dq + j + 3] = __float2bfloat16(v4.w);
            }
        }
        if (tid < 48) { rmax[tid] = 0.f; rsum[tid] = 1.f; }
    }
    __syncthreads();

    // phase A: S[48][2048] = Qs @ K^T
    const float* Kb = k + (size_t)b * S_ * DM_ + h * DK_;
    for (int nt = w; nt < 128; nt += 4) {
        int krow = nt * 16 + ml;
        const float* kr = Kb + (size_t)krow * DM_;
        float4 x0 = *(const float4*)(kr + kq * 8);
        float4 x1 = *(const float4*)(kr + kq * 8 + 4);
        float4 y0 = *(const float4*)(kr + 32 + kq * 8);
        float4 y1 = *(const float4*)(kr + 32 + kq * 8 + 4);
        short8 b0, b1;
        b0[0] = f2bs(x0.x); b0[1] = f2bs(x0.y); b0[2] = f2bs(x0.z); b0[3] = f2bs(x0.w);
        b0[4] = f2bs(x1.x); b0[5] = f2bs(x1.y); b0[6] = f2bs(x1.z); b0[7] = f2bs(x1.w);
        b1[0] = f2bs(y0.x); b1[1] = f2bs(y0.y); b1[2] = f2bs(y0.z); b1[3] = f2bs(y0.w);
        b1[4] = f2bs(y1.x); b1[5] = f2bs(y1.y); b1[6] = f2bs(y1.z); b1[7] = f2bs(y1.w);
#pragma unroll
        for (int mt = 0; mt < 3; ++mt) {
            short8 a0 = *(const short8*)&Qs[mt * 16 + ml][kq * 8];
            short8 a1 = *(const short8*)&Qs[mt * 16 + ml][32 + kq * 8];
            f32x4 acc = {0.f, 0.f, 0.f, 0.f};
            acc = __builtin_amdgcn_mfma_f32_16x16x32_bf16(a0, b0, acc, 0, 0, 0);
            acc = __builtin_amdgcn_mfma_f32_16x16x32_bf16(a1, b1, acc, 0, 0, 0);
#pragma unroll
            for (int r = 0; r < 4; ++r)
                Sb[(size_t)(mt * 16 + kq * 4 + r) * 2048 + nt * 16 + ml] = acc[r];
        }
    }
    __syncthreads();

    // phase B: row max/sum (rows 0..39), wave w handles rows w*10..w*10+9
    for (int ri = 0; ri < 10; ++ri) {
        int r = w * 10 + ri;
        const float* sr = Sb + (size_t)r * 2048;
        float mx = -1e30f;
        for (int c = lane; c < 2048; c += 64) mx = fmaxf(mx, sr[c]);
#pragma unroll
        for (int off = 32; off; off >>= 1) mx = fmaxf(mx, __shfl_xor(mx, off, 64));
        float sm = 0.f;
        for (int c = lane; c < 2048; c += 64) sm += __expf(sr[c] - mx);
#pragma unroll
        for (int off = 32; off; off >>= 1) sm += __shfl_xor(sm, off, 64);
        if (lane == 0) { rmax[r] = mx; rsum[r] = sm; }
    }
    __syncthreads();

    // phase C: upd = softmax(S) @ V, chunks of 256 kk
    const float* Vb = v + (size_t)b * S_ * DM_ + h * DK_;
    f32x4 acc[3];
#pragma unroll
    for (int i = 0; i < 3; ++i) acc[i] = (f32x4){0.f, 0.f, 0.f, 0.f};
    float mxr[3], rsr[3];
#pragma unroll
    for (int mt = 0; mt < 3; ++mt) {
        int m = mt * 16 + ml;
        mxr[mt] = rmax[m];
        rsr[mt] = 1.f / rsum[m];
    }
    for (int c = 0; c < 8; ++c) {
        // stage V chunk transposed into LDS (bf16)
#pragma unroll
        for (int i = 0; i < 4; ++i) {
            int klocal = i * 64 + (tid >> 2);
            int dq = (tid & 3) * 16;
            const float* vr = Vb + (size_t)(c * 256 + klocal) * DM_ + dq;
#pragma unroll
            for (int jj = 0; jj < 16; jj += 4) {
                float4 v4 = *(const float4*)(vr + jj);
                Vt[dq + jj + 0][klocal] = __float2bfloat16(v4.x);
                Vt[dq + jj + 1][klocal] = __float2bfloat16(v4.y);
                Vt[dq + jj + 2][klocal] = __float2bfloat16(v4.z);
                Vt[dq + jj + 3][klocal] = __float2bfloat16(v4.w);
            }
        }
        __syncthreads();
#pragma unroll
        for (int kt = 0; kt < 8; ++kt) {
            short8 bfq = *(const short8*)&Vt[w * 16 + ml][kt * 32 + kq * 8];
#pragma unroll
            for (int mt = 0; mt < 3; ++mt) {
                int m = mt * 16 + ml;
                const float* sr = Sb + (size_t)m * 2048 + c * 256 + kt * 32 + kq * 8;
                float4 s0 = *(const float4*)sr;
                float4 s1 = *(const float4*)(sr + 4);
                float mx = mxr[mt], rs = rsr[mt];
                short8 af;
                af[0] = f2bs(__expf(s0.x - mx) * rs);
                af[1] = f2bs(__expf(s0.y - mx) * rs);
                af[2] = f2bs(__expf(s0.z - mx) * rs);
                af[3] = f2bs(__expf(s0.w - mx) * rs);
                af[4] = f2bs(__expf(s1.x - mx) * rs);
                af[5] = f2bs(__expf(s1.y - mx) * rs);
                af[6] = f2bs(__expf(s1.z - mx) * rs);
                af[7] = f2bs(__expf(s1.w - mx) * rs);
                acc[mt] = __builtin_amdgcn_mfma_f32_16x16x32_bf16(af, bfq, acc[mt], 0, 0, 0);
            }
        }
        __syncthreads();
    }
    // write upd rows (u < 40), cols w*16 + ml
#pragma unroll
    for (int mt = 0; mt < 3; ++mt)
#pragma unroll
        for (int r = 0; r < 4; ++r) {
            int u = mt * 16 + kq * 4 + r;
            if (u < U_) upd[((size_t)bh * U_ + u) * DK_ + w * 16 + ml] = acc[mt][r];
        }
}

// ================= ctx = broadcast v_mean (fp32)
__global__ void ctx_fill(const float* __restrict__ vm, float* __restrict__ ctx) {
    size_t i = (size_t)blockIdx.x * 256 + threadIdx.x;
    int c = (int)(i & (DM_ - 1));
    size_t bl = i >> 10;
    int b = (int)(bl >> 11);
    int h = c >> 6, d = c & (DK_ - 1);
    ctx[i] = vm[(b * H_ + h) * DK_ + d];
}

// ================= scatter upd rows into ctx
__global__ void ctx_scatter(const float* __restrict__ upd, const int* __restrict__ mtop,
                            float* __restrict__ ctx) {
    int blk = blockIdx.x;
    int bh = blk / U_;
    int b = bh / H_, h = bh % H_;
    int lane = threadIdx.x;
    int row = mtop[blk];
    row = (row < 0) ? 0 : (row >= S_ ? S_ - 1 : row);
    ctx[((size_t)(b * S_ + row)) * DM_ + h * DK_ + lane] = upd[(size_t)blk * DK_ + lane];
}

// ================= bias + residual + LayerNorm
__global__ void ln_kernel(const float* __restrict__ fcout, const float* __restrict__ fcb,
                          const float* __restrict__ resid,
                          const float* __restrict__ lnw, const float* __restrict__ lnb,
                          float* __restrict__ out) {
    __shared__ float red[256];
    int row = blockIdx.x, tid = threadIdx.x;
    float x[4];
#pragma unroll
    for (int j = 0; j < 4; ++j) {
        int c = tid + j * 256;
        x[j] = fcout[(size_t)row * DM_ + c] + fcb[c] + resid[(size_t)row * DM_ + c];
    }
    float s = x[0] + x[1] + x[2] + x[3];
    red[tid] = s;
    __syncthreads();
    for (int st = 128; st; st >>= 1) {
        if (tid < st) red[tid] += red[tid + st];
        __syncthreads();
    }
    float mu = red[0] * (1.f / (float)DM_);
    __syncthreads();
    float vs = 0.f;
#pragma unroll
    for (int j = 0; j < 4; ++j) { float d = x[j] - mu; vs += d * d; }
    red[tid] = vs;
    __syncthreads();
    for (int st = 128; st; st >>= 1) {
        if (tid < st) red[tid] += red[tid + st];
        __syncthreads();
    }
    float rstd = rsqrtf(red[0] * (1.f / (float)DM_) + 1e-6f);
#pragma unroll
    for (int j = 0; j < 4; ++j) {
        int c = tid + j * 256;
        out[(size_t)row * DM_ + c] = (x[j] - mu) * rstd * lnw[c] + lnb[c];
    }
}

// ================= launch =================

extern "C" void kernel_launch(void* const* d_in, const int* in_sizes, int n_in,
                              void* d_out, int out_size, void* d_ws, size_t ws_size,
                              hipStream_t stream) {
    if (n_in < 9 || d_ws == nullptr || d_out == nullptr) return;
    if (ws_size < 34ull * 1024 * 1024) return;

    const float* hs  = (const float*)d_in[0];
    const float* wq  = (const float*)d_in[1];
    const float* wk  = (const float*)d_in[2];
    const float* wv  = (const float*)d_in[3];
    const float* fcw = (const float*)d_in[4];
    const float* fcb = (const float*)d_in[5];
    const float* lnw = (const float*)d_in[6];
    const float* lnb = (const float*)d_in[7];
    const int* idxs  = (const int*)d_in[8];

    const size_t MD = (size_t)B_ * S_ * DM_;  // 4194304
    const int M = B_ * S_;                    // 4096
    float* ws = (float*)d_ws;
    float* out = (float*)d_out;

    // Layout: q [0,MD) fp32 (16MB) -> after gather_qsel dead -> Sm (12.6MB) -> ctx
    //         k [MD,2MD) fp32 (16MB) -> after attn dead -> fcout
    //         smalls [2MD, +~1MB): mbuf, vmean, upd, mtop, qsel
    //         v -> d_out (16MB), dead before ln writes
    float* q = ws;
    float* k = ws + MD;
    float* mbuf = ws + 2 * MD;                             // B*H*S = 65536 f
    float* vmean = mbuf + (size_t)B_ * H_ * S_;            // 2048 f
    float* upd = vmean + B_ * H_ * DK_;                    // 81920 f
    int* mtop = (int*)(upd + (size_t)B_ * H_ * U_ * DK_);  // 1280 i
    float* qsel = (float*)(mtop + B_ * H_ * U_);           // 98304 f
    float* v = out;
    float* Sm = q;     // after q dead (post-gather)
    float* ctx = q;    // after Sm dead (post-attn)
    float* fcout = k;  // after k dead (post-attn)

    sgemm_v2<<<256, 256, 0, stream>>>(hs, wq, q, M, DM_, DM_, 0.125f);  // 1/sqrt(64)
    sgemm_v2<<<256, 256, 0, stream>>>(hs, wk, k, M, DM_, DM_, 1.0f);
    mfma_gemm<<<256, 256, 0, stream>>>(hs, wv, v, M, DM_, DM_, 1.0f);

    m_score_kernel<<<(B_ * H_ * S_) / 4, 256, 0, stream>>>(q, k, idxs, mbuf);
    topk_kernel<<<B_ * H_, 256, 0, stream>>>(mbuf, mtop);
    vmean_kernel<<<B_ * H_, 256, 0, stream>>>(v, vmean);
    gather_qsel<<<B_ * H_, 256, 0, stream>>>(q, mtop, qsel);

    attn_mfma<<<B_ * H_, 256, 0, stream>>>(qsel, k, v, Sm, upd);

    ctx_fill<<<(int)(MD / 256), 256, 0, stream>>>(vmean, ctx);
    ctx_scatter<<<B_ * H_ * U_, 64, 0, stream>>>(upd, mtop, ctx);

    mfma_gemm<<<256, 256, 0, stream>>>(ctx, fcw, fcout, M, DM_, DM_, 1.0f);
    ln_kernel<<<M, 256, 0, stream>>>(fcout, fcb, hs, lnw, lnb, out);
}

// Round 7
// 887.961 us; speedup vs baseline: 1.7790x; 1.1929x over previous
//
#include <hip/hip_runtime.h>
#include <hip/hip_bf16.h>

#define B_  2
#define S_  2048
#define DM_ 1024
#define H_  16
#define DK_ 64
#define SK_ 40   // SAMPLE_K
#define U_  40   // top-k u
#define CH_ 128  // attn chunk columns
#define NCH_ (S_ / CH_)  // 16

typedef __attribute__((ext_vector_type(8))) short short8;
typedef __attribute__((ext_vector_type(4))) float f32x4;

union BF16S { __hip_bfloat16 h; short s; };
static __device__ __forceinline__ short f2bs(float x) {
    BF16S u; u.h = __float2bfloat16(x); return u.s;
}

// ================= fp32 GEMM, 128x128 tile, 8x8 microtile (for q,k: fp32-exact)
__global__ __launch_bounds__(256) void sgemm_v2(const float* __restrict__ A,
                                                const float* __restrict__ Bm,
                                                float* __restrict__ C,
                                                int M, int N, int K, float scale) {
    __shared__ float As[16][136];  // [k][m], padded
    __shared__ float Bs[16][136];  // [k][n], padded
    int nbx = N >> 7;
    int by = blockIdx.x / nbx, bx = blockIdx.x % nbx;
    int tid = threadIdx.x;
    int tx = tid & 15, ty = tid >> 4;
    float acc[8][8] = {{0.f}};
    const float* Ab = A + (size_t)(by * 128) * K;
    const float* Bb = Bm + bx * 128;
    int arow = tid >> 1, akq = (tid & 1) * 8;
    int bkk = tid >> 4, bnq = (tid & 15) * 8;

    for (int k0 = 0; k0 < K; k0 += 16) {
        float4 a0 = *(const float4*)(Ab + (size_t)arow * K + k0 + akq);
        float4 a1 = *(const float4*)(Ab + (size_t)arow * K + k0 + akq + 4);
        As[akq + 0][arow] = a0.x; As[akq + 1][arow] = a0.y;
        As[akq + 2][arow] = a0.z; As[akq + 3][arow] = a0.w;
        As[akq + 4][arow] = a1.x; As[akq + 5][arow] = a1.y;
        As[akq + 6][arow] = a1.z; As[akq + 7][arow] = a1.w;
        float4 b0 = *(const float4*)(Bb + (size_t)(k0 + bkk) * N + bnq);
        float4 b1 = *(const float4*)(Bb + (size_t)(k0 + bkk) * N + bnq + 4);
        *(float4*)&Bs[bkk][bnq] = b0;
        *(float4*)&Bs[bkk][bnq + 4] = b1;
        __syncthreads();
#pragma unroll
        for (int kk = 0; kk < 16; ++kk) {
            float av[8], bv[8];
            *(float4*)&av[0] = *(const float4*)&As[kk][ty * 8];
            *(float4*)&av[4] = *(const float4*)&As[kk][ty * 8 + 4];
            *(float4*)&bv[0] = *(const float4*)&Bs[kk][tx * 8];
            *(float4*)&bv[4] = *(const float4*)&Bs[kk][tx * 8 + 4];
#pragma unroll
            for (int i = 0; i < 8; ++i)
#pragma unroll
                for (int j = 0; j < 8; ++j) acc[i][j] += av[i] * bv[j];
        }
        __syncthreads();
    }
#pragma unroll
    for (int i = 0; i < 8; ++i) {
        int row = by * 128 + ty * 8 + i;
        float4 c0 = {acc[i][0] * scale, acc[i][1] * scale, acc[i][2] * scale, acc[i][3] * scale};
        float4 c1 = {acc[i][4] * scale, acc[i][5] * scale, acc[i][6] * scale, acc[i][7] * scale};
        *(float4*)&C[(size_t)row * N + bx * 128 + tx * 8] = c0;
        *(float4*)&C[(size_t)row * N + bx * 128 + tx * 8 + 4] = c1;
    }
}

// ================= bf16 MFMA GEMM (fp32 in/out, convert in staging), 128x128, BK=32
__global__ __launch_bounds__(256) void mfma_gemm(const float* __restrict__ A,
                                                 const float* __restrict__ Bm,
                                                 float* __restrict__ C,
                                                 int M, int N, int K, float scale) {
    __shared__ __hip_bfloat16 Asb[128][40];  // [m][k], pad 32->40
    __shared__ __hip_bfloat16 Bsb[128][40];  // [n][k] (transposed)
    int nbx = N >> 7;
    int by = blockIdx.x / nbx, bx = blockIdx.x % nbx;
    int tid = threadIdx.x;
    int lane = tid & 63, w = tid >> 6;
    int wm = (w & 1) * 64, wn = (w >> 1) * 64;
    int ml = lane & 15, kq = lane >> 4;

    f32x4 acc[4][4];
#pragma unroll
    for (int i = 0; i < 4; ++i)
#pragma unroll
        for (int j = 0; j < 4; ++j) acc[i][j] = (f32x4){0.f, 0.f, 0.f, 0.f};

    const float* Ab = A + (size_t)(by * 128) * K;
    const float* Bb = Bm + bx * 128;
    int arow = tid >> 3, akq = (tid & 7) * 4;
    int bkk = tid >> 3, bnq = (tid & 7) * 4;

    for (int k0 = 0; k0 < K; k0 += 32) {
#pragma unroll
        for (int i = 0; i < 4; ++i) {
            int r = arow + i * 32;
            float4 v4 = *(const float4*)(Ab + (size_t)r * K + k0 + akq);
            Asb[r][akq + 0] = __float2bfloat16(v4.x);
            Asb[r][akq + 1] = __float2bfloat16(v4.y);
            Asb[r][akq + 2] = __float2bfloat16(v4.z);
            Asb[r][akq + 3] = __float2bfloat16(v4.w);
        }
#pragma unroll
        for (int i = 0; i < 4; ++i) {
            int n = bnq + i * 32;
            float4 v4 = *(const float4*)(Bb + (size_t)(k0 + bkk) * N + n);
            Bsb[n + 0][bkk] = __float2bfloat16(v4.x);
            Bsb[n + 1][bkk] = __float2bfloat16(v4.y);
            Bsb[n + 2][bkk] = __float2bfloat16(v4.z);
            Bsb[n + 3][bkk] = __float2bfloat16(v4.w);
        }
        __syncthreads();
        short8 af[4], bf[4];
#pragma unroll
        for (int t = 0; t < 4; ++t) af[t] = *(const short8*)&Asb[wm + t * 16 + ml][kq * 8];
#pragma unroll
        for (int t = 0; t < 4; ++t) bf[t] = *(const short8*)&Bsb[wn + t * 16 + ml][kq * 8];
#pragma unroll
        for (int i = 0; i < 4; ++i)
#pragma unroll
            for (int j = 0; j < 4; ++j)
                acc[i][j] = __builtin_amdgcn_mfma_f32_16x16x32_bf16(af[i], bf[j], acc[i][j], 0, 0, 0);
        __syncthreads();
    }
#pragma unroll
    for (int i = 0; i < 4; ++i)
#pragma unroll
        for (int j = 0; j < 4; ++j)
#pragma unroll
            for (int r = 0; r < 4; ++r) {
                int row = by * 128 + wm + i * 16 + kq * 4 + r;
                int col = bx * 128 + wn + j * 16 + ml;
                C[(size_t)row * N + col] = acc[i][j][r] * scale;
            }
}

// ================= m = max - sum/S over sampled dots, one wave per (b,h,l)
__global__ void m_score_kernel(const float* __restrict__ q, const float* __restrict__ k,
                               const int* __restrict__ idxs, float* __restrict__ m_out) {
    int gwave = blockIdx.x * 4 + (threadIdx.x >> 6);
    int lane = threadIdx.x & 63;
    if (gwave >= B_ * H_ * S_) return;
    int l = gwave % S_;
    int bh = gwave / S_;
    int h = bh % H_, b = bh / H_;

    float qv = q[((size_t)(b * S_ + l)) * DM_ + h * DK_ + lane];
    const float* kb = k + (size_t)b * S_ * DM_ + h * DK_;
    float maxv = -INFINITY, sumv = 0.f;
    for (int s = 0; s < SK_; ++s) {
        int idx = idxs[l * SK_ + s];
        idx = (idx < 0) ? 0 : (idx >= S_ ? S_ - 1 : idx);
        float p = qv * kb[(size_t)idx * DM_ + lane];
#pragma unroll
        for (int off = 32; off; off >>= 1) p += __shfl_xor(p, off, 64);
        maxv = fmaxf(maxv, p);
        sumv += p;
    }
    if (lane == 0) m_out[(size_t)bh * S_ + l] = maxv - sumv * (1.f / (float)S_);
}

// ================= top-40 per block: iterative masked argmax
__global__ void topk_kernel(const float* __restrict__ m, int* __restrict__ mtop) {
    __shared__ float vals[S_];
    __shared__ float rv[256];
    __shared__ int ri[256];
    int bh = blockIdx.x, tid = threadIdx.x;
    for (int i = tid; i < S_; i += 256) vals[i] = m[(size_t)bh * S_ + i];
    __syncthreads();
    for (int it = 0; it < U_; ++it) {
        float best = -INFINITY;
        int bi = -1;
        for (int i = tid; i < S_; i += 256) {
            float v = vals[i];
            if (v > best) { best = v; bi = i; }
        }
        rv[tid] = best; ri[tid] = bi;
        __syncthreads();
        for (int s = 128; s; s >>= 1) {
            if (tid < s) {
                if ((ri[tid] < 0 && ri[tid + s] >= 0) ||
                    (ri[tid + s] >= 0 &&
                     (rv[tid + s] > rv[tid] ||
                      (rv[tid + s] == rv[tid] && ri[tid + s] < ri[tid])))) {
                    rv[tid] = rv[tid + s]; ri[tid] = ri[tid + s];
                }
            }
            __syncthreads();
        }
        if (tid == 0) {
            int r0 = (ri[0] >= 0 && ri[0] < S_) ? ri[0] : 0;
            mtop[bh * U_ + it] = r0;
            vals[r0] = -INFINITY;
        }
        __syncthreads();
    }
}

// ================= v mean over S per (b,h)
__global__ void vmean_kernel(const float* __restrict__ v, float* __restrict__ vm) {
    __shared__ float part[4][DK_];
    int bh = blockIdx.x, tid = threadIdx.x;
    int wave = tid >> 6, lane = tid & 63;
    int b = bh / H_, h = bh % H_;
    const float* vb = v + (size_t)b * S_ * DM_ + h * DK_;
    float s = 0.f;
    for (int l = wave; l < S_; l += 4) s += vb[(size_t)l * DM_ + lane];
    part[wave][lane] = s;
    __syncthreads();
    if (tid < DK_)
        vm[bh * DK_ + tid] =
            (part[0][tid] + part[1][tid] + part[2][tid] + part[3][tid]) * (1.f / (float)S_);
}

// ================= gather selected q rows -> qsel[bh][48][64] (rows 40..47 zero)
__global__ void gather_qsel(const float* __restrict__ q, const int* __restrict__ mtop,
                            float* __restrict__ qsel) {
    int bh = blockIdx.x;
    int b = bh >> 4, h = bh & 15;
    int tid = threadIdx.x;
    int u = tid >> 2, dq = (tid & 3) * 16;
    if (u >= 48) return;
    float* dst = qsel + ((size_t)bh * 48 + u) * 64 + dq;
    if (u < U_) {
        int row = mtop[bh * U_ + u];
        row = (row < 0) ? 0 : (row >= S_ ? S_ - 1 : row);
        const float* src = q + ((size_t)(b * S_ + row)) * DM_ + h * DK_ + dq;
#pragma unroll
        for (int j = 0; j < 16; j += 4) *(float4*)(dst + j) = *(const float4*)(src + j);
    } else {
        float4 z = {0.f, 0.f, 0.f, 0.f};
#pragma unroll
        for (int j = 0; j < 16; j += 4) *(float4*)(dst + j) = z;
    }
}

// ================= split-K flash attention, block per (b,h,chunk). 512 blocks.
// Writes unnormalized partial O (48x64) + per-row chunk max m and sum l.
__global__ __launch_bounds__(256) void attn_chunk(const float* __restrict__ qsel,
                                                  const float* __restrict__ k,
                                                  const float* __restrict__ v,
                                                  float* __restrict__ Opart,
                                                  float* __restrict__ Mpart,
                                                  float* __restrict__ Lpart) {
    __shared__ alignas(16) __hip_bfloat16 Qs[48][72];    // [u][d]
    __shared__ alignas(16) __hip_bfloat16 Vt[64][136];   // [d][k-in-chunk]
    __shared__ alignas(16) __hip_bfloat16 Ps[48][136];   // [u][k-in-chunk]
    __shared__ float mpart[4][48], lpart[4][48];
    __shared__ float mrow[48];
    int blk = blockIdx.x;
    int bh = blk / NCH_, ch = blk % NCH_;
    int b = bh >> 4, h = bh & 15;
    int c0 = ch * CH_;
    int tid = threadIdx.x, lane = tid & 63, w = tid >> 6;
    int ml = lane & 15, kq = lane >> 4;

    // stage Q (48x64 bf16)
    {
        int u = tid >> 2, dq = (tid & 3) * 16;
        if (u < 48) {
            const float* src = qsel + ((size_t)bh * 48 + u) * 64 + dq;
#pragma unroll
            for (int j = 0; j < 16; j += 4) {
                float4 v4 = *(const float4*)(src + j);
                Qs[u][dq + j + 0] = __float2bfloat16(v4.x);
                Qs[u][dq + j + 1] = __float2bfloat16(v4.y);
                Qs[u][dq + j + 2] = __float2bfloat16(v4.z);
                Qs[u][dq + j + 3] = __float2bfloat16(v4.w);
            }
        }
    }
    // stage V chunk transposed (128 rows x 64 d) -> Vt[d][klocal]
    {
        int klocal = tid >> 1, dq = (tid & 1) * 32;
        const float* vr = v + (size_t)(b * S_ + c0 + klocal) * DM_ + h * DK_ + dq;
#pragma unroll
        for (int jj = 0; jj < 32; jj += 4) {
            float4 v4 = *(const float4*)(vr + jj);
            Vt[dq + jj + 0][klocal] = __float2bfloat16(v4.x);
            Vt[dq + jj + 1][klocal] = __float2bfloat16(v4.y);
            Vt[dq + jj + 2][klocal] = __float2bfloat16(v4.z);
            Vt[dq + jj + 3][klocal] = __float2bfloat16(v4.w);
        }
    }
    __syncthreads();

    // QK^T: wave w handles n-tiles 2w, 2w+1 (32 cols); S in registers
    const float* Kb = k + (size_t)b * S_ * DM_ + h * DK_;
    f32x4 sreg[3][2];
#pragma unroll
    for (int i = 0; i < 3; ++i)
#pragma unroll
        for (int j = 0; j < 2; ++j) sreg[i][j] = (f32x4){0.f, 0.f, 0.f, 0.f};
#pragma unroll
    for (int ntl = 0; ntl < 2; ++ntl) {
        int krow = c0 + (w * 2 + ntl) * 16 + ml;
        const float* kr = Kb + (size_t)krow * DM_;
        float4 x0 = *(const float4*)(kr + kq * 8);
        float4 x1 = *(const float4*)(kr + kq * 8 + 4);
        float4 y0 = *(const float4*)(kr + 32 + kq * 8);
        float4 y1 = *(const float4*)(kr + 32 + kq * 8 + 4);
        short8 b0, b1;
        b0[0] = f2bs(x0.x); b0[1] = f2bs(x0.y); b0[2] = f2bs(x0.z); b0[3] = f2bs(x0.w);
        b0[4] = f2bs(x1.x); b0[5] = f2bs(x1.y); b0[6] = f2bs(x1.z); b0[7] = f2bs(x1.w);
        b1[0] = f2bs(y0.x); b1[1] = f2bs(y0.y); b1[2] = f2bs(y0.z); b1[3] = f2bs(y0.w);
        b1[4] = f2bs(y1.x); b1[5] = f2bs(y1.y); b1[6] = f2bs(y1.z); b1[7] = f2bs(y1.w);
#pragma unroll
        for (int mt = 0; mt < 3; ++mt) {
            short8 a0 = *(const short8*)&Qs[mt * 16 + ml][kq * 8];
            short8 a1 = *(const short8*)&Qs[mt * 16 + ml][32 + kq * 8];
            sreg[mt][ntl] = __builtin_amdgcn_mfma_f32_16x16x32_bf16(a0, b0, sreg[mt][ntl], 0, 0, 0);
            sreg[mt][ntl] = __builtin_amdgcn_mfma_f32_16x16x32_bf16(a1, b1, sreg[mt][ntl], 0, 0, 0);
        }
    }

    // per-row max within wave's 32 cols, then across waves via LDS
    {
        float vmx[3][4];
#pragma unroll
        for (int mt = 0; mt < 3; ++mt)
#pragma unroll
            for (int r = 0; r < 4; ++r)
                vmx[mt][r] = fmaxf(sreg[mt][0][r], sreg[mt][1][r]);
#pragma unroll
        for (int mask = 1; mask <= 8; mask <<= 1)
#pragma unroll
            for (int mt = 0; mt < 3; ++mt)
#pragma unroll
                for (int r = 0; r < 4; ++r)
                    vmx[mt][r] = fmaxf(vmx[mt][r], __shfl_xor(vmx[mt][r], mask, 64));
        if (ml == 0)
#pragma unroll
            for (int mt = 0; mt < 3; ++mt)
#pragma unroll
                for (int r = 0; r < 4; ++r)
                    mpart[w][mt * 16 + kq * 4 + r] = vmx[mt][r];
    }
    __syncthreads();
    if (tid < 48)
        mrow[tid] = fmaxf(fmaxf(mpart[0][tid], mpart[1][tid]),
                          fmaxf(mpart[2][tid], mpart[3][tid]));
    __syncthreads();

    // P = exp(S - mrow) -> Ps (bf16) + per-row partial sums
    {
        float vsum[3][4] = {{0.f}};
#pragma unroll
        for (int mt = 0; mt < 3; ++mt)
#pragma unroll
            for (int ntl = 0; ntl < 2; ++ntl) {
                int col = (w * 2 + ntl) * 16 + ml;
#pragma unroll
                for (int r = 0; r < 4; ++r) {
                    int row = mt * 16 + kq * 4 + r;
                    float p = __expf(sreg[mt][ntl][r] - mrow[row]);
                    Ps[row][col] = __float2bfloat16(p);
                    vsum[mt][r] += p;
                }
            }
#pragma unroll
        for (int mask = 1; mask <= 8; mask <<= 1)
#pragma unroll
            for (int mt = 0; mt < 3; ++mt)
#pragma unroll
                for (int r = 0; r < 4; ++r)
                    vsum[mt][r] += __shfl_xor(vsum[mt][r], mask, 64);
        if (ml == 0)
#pragma unroll
            for (int mt = 0; mt < 3; ++mt)
#pragma unroll
                for (int r = 0; r < 4; ++r)
                    lpart[w][mt * 16 + kq * 4 + r] = vsum[mt][r];
    }
    __syncthreads();

    // PV: A = Ps (48x128), B = Vt; wave w owns output n-tile w (16 of 64 cols)
    f32x4 oreg[3];
#pragma unroll
    for (int i = 0; i < 3; ++i) oreg[i] = (f32x4){0.f, 0.f, 0.f, 0.f};
#pragma unroll
    for (int kt = 0; kt < 4; ++kt) {
        short8 bfq = *(const short8*)&Vt[w * 16 + ml][kt * 32 + kq * 8];
#pragma unroll
        for (int mt = 0; mt < 3; ++mt) {
            short8 af = *(const short8*)&Ps[mt * 16 + ml][kt * 32 + kq * 8];
            oreg[mt] = __builtin_amdgcn_mfma_f32_16x16x32_bf16(af, bfq, oreg[mt], 0, 0, 0);
        }
    }
    // write partials
#pragma unroll
    for (int mt = 0; mt < 3; ++mt)
#pragma unroll
        for (int r = 0; r < 4; ++r) {
            int row = mt * 16 + kq * 4 + r;
            Opart[((size_t)blk * 48 + row) * 64 + w * 16 + ml] = oreg[mt][r];
        }
    if (tid < 48) {
        Mpart[(size_t)blk * 48 + tid] = mrow[tid];
        Lpart[(size_t)blk * 48 + tid] =
            lpart[0][tid] + lpart[1][tid] + lpart[2][tid] + lpart[3][tid];
    }
}

// ================= combine chunk partials -> upd (block per bh)
__global__ void attn_combine(const float* __restrict__ Opart, const float* __restrict__ Mpart,
                             const float* __restrict__ Lpart, float* __restrict__ upd) {
    __shared__ float wfac[NCH_][48];
    __shared__ float lfin[48];
    int bh = blockIdx.x, tid = threadIdx.x;
    if (tid < 48) {
        float m = -1e30f;
        for (int c = 0; c < NCH_; ++c)
            m = fmaxf(m, Mpart[(size_t)(bh * NCH_ + c) * 48 + tid]);
        float l = 0.f;
        for (int c = 0; c < NCH_; ++c) {
            float wf = __expf(Mpart[(size_t)(bh * NCH_ + c) * 48 + tid] - m);
            wfac[c][tid] = wf;
            l += wf * Lpart[(size_t)(bh * NCH_ + c) * 48 + tid];
        }
        lfin[tid] = l;
    }
    __syncthreads();
    for (int e = tid; e < U_ * DK_; e += 256) {
        int row = e >> 6, col = e & 63;
        float o = 0.f;
        for (int c = 0; c < NCH_; ++c)
            o += wfac[c][row] * Opart[((size_t)(bh * NCH_ + c) * 48 + row) * 64 + col];
        upd[((size_t)bh * U_ + row) * DK_ + col] = o / lfin[row];
    }
}

// ================= ctx = broadcast v_mean (fp32)
__global__ void ctx_fill(const float* __restrict__ vm, float* __restrict__ ctx) {
    size_t i = (size_t)blockIdx.x * 256 + threadIdx.x;
    int c = (int)(i & (DM_ - 1));
    size_t bl = i >> 10;
    int b = (int)(bl >> 11);
    int h = c >> 6, d = c & (DK_ - 1);
    ctx[i] = vm[(b * H_ + h) * DK_ + d];
}

// ================= scatter upd rows into ctx
__global__ void ctx_scatter(const float* __restrict__ upd, const int* __restrict__ mtop,
                            float* __restrict__ ctx) {
    int blk = blockIdx.x;
    int bh = blk / U_;
    int b = bh / H_, h = bh % H_;
    int lane = threadIdx.x;
    int row = mtop[blk];
    row = (row < 0) ? 0 : (row >= S_ ? S_ - 1 : row);
    ctx[((size_t)(b * S_ + row)) * DM_ + h * DK_ + lane] = upd[(size_t)blk * DK_ + lane];
}

// ================= bias + residual + LayerNorm
__global__ void ln_kernel(const float* __restrict__ fcout, const float* __restrict__ fcb,
                          const float* __restrict__ resid,
                          const float* __restrict__ lnw, const float* __restrict__ lnb,
                          float* __restrict__ out) {
    __shared__ float red[256];
    int row = blockIdx.x, tid = threadIdx.x;
    float x[4];
#pragma unroll
    for (int j = 0; j < 4; ++j) {
        int c = tid + j * 256;
        x[j] = fcout[(size_t)row * DM_ + c] + fcb[c] + resid[(size_t)row * DM_ + c];
    }
    float s = x[0] + x[1] + x[2] + x[3];
    red[tid] = s;
    __syncthreads();
    for (int st = 128; st; st >>= 1) {
        if (tid < st) red[tid] += red[tid + st];
        __syncthreads();
    }
    float mu = red[0] * (1.f / (float)DM_);
    __syncthreads();
    float vs = 0.f;
#pragma unroll
    for (int j = 0; j < 4; ++j) { float d = x[j] - mu; vs += d * d; }
    red[tid] = vs;
    __syncthreads();
    for (int st = 128; st; st >>= 1) {
        if (tid < st) red[tid] += red[tid + st];
        __syncthreads();
    }
    float rstd = rsqrtf(red[0] * (1.f / (float)DM_) + 1e-6f);
#pragma unroll
    for (int j = 0; j < 4; ++j) {
        int c = tid + j * 256;
        out[(size_t)row * DM_ + c] = (x[j] - mu) * rstd * lnw[c] + lnb[c];
    }
}

// ================= launch =================

extern "C" void kernel_launch(void* const* d_in, const int* in_sizes, int n_in,
                              void* d_out, int out_size, void* d_ws, size_t ws_size,
                              hipStream_t stream) {
    if (n_in < 9 || d_ws == nullptr || d_out == nullptr) return;
    if (ws_size < 34ull * 1024 * 1024) return;

    const float* hs  = (const float*)d_in[0];
    const float* wq  = (const float*)d_in[1];
    const float* wk  = (const float*)d_in[2];
    const float* wv  = (const float*)d_in[3];
    const float* fcw = (const float*)d_in[4];
    const float* fcb = (const float*)d_in[5];
    const float* lnw = (const float*)d_in[6];
    const float* lnb = (const float*)d_in[7];
    const int* idxs  = (const int*)d_in[8];

    const size_t MD = (size_t)B_ * S_ * DM_;  // 4194304
    const int M = B_ * S_;                    // 4096
    float* ws = (float*)d_ws;
    float* out = (float*)d_out;

    // Layout: q [0,MD) fp32 -> (after gather_qsel) Opart/Mpart/Lpart -> ctx
    //         k [MD,2MD) fp32 -> (after attn_chunk) fcout
    //         smalls [2MD,+~1MB): mbuf, vmean, upd, mtop, qsel
    //         v -> d_out, dead before ln writes
    float* q = ws;
    float* k = ws + MD;
    float* mbuf = ws + 2 * MD;                             // B*H*S
    float* vmean = mbuf + (size_t)B_ * H_ * S_;            // 2048
    float* upd = vmean + B_ * H_ * DK_;                    // 81920
    int* mtop = (int*)(upd + (size_t)B_ * H_ * U_ * DK_);  // 1280
    float* qsel = (float*)(mtop + B_ * H_ * U_);           // 98304
    float* v = out;
    float* Opart = q;                                 // 512*48*64 = 1572864 f
    float* Mpart = Opart + (size_t)512 * 48 * 64;     // 24576 f
    float* Lpart = Mpart + (size_t)512 * 48;          // 24576 f
    float* ctx = q;    // after Opart dead (post-combine)
    float* fcout = k;  // after k dead (post-attn_chunk)

    sgemm_v2<<<256, 256, 0, stream>>>(hs, wq, q, M, DM_, DM_, 0.125f);  // 1/sqrt(64)
    sgemm_v2<<<256, 256, 0, stream>>>(hs, wk, k, M, DM_, DM_, 1.0f);
    mfma_gemm<<<256, 256, 0, stream>>>(hs, wv, v, M, DM_, DM_, 1.0f);

    m_score_kernel<<<(B_ * H_ * S_) / 4, 256, 0, stream>>>(q, k, idxs, mbuf);
    topk_kernel<<<B_ * H_, 256, 0, stream>>>(mbuf, mtop);
    vmean_kernel<<<B_ * H_, 256, 0, stream>>>(v, vmean);
    gather_qsel<<<B_ * H_, 256, 0, stream>>>(q, mtop, qsel);

    attn_chunk<<<B_ * H_ * NCH_, 256, 0, stream>>>(qsel, k, v, Opart, Mpart, Lpart);
    attn_combine<<<B_ * H_, 256, 0, stream>>>(Opart, Mpart, Lpart, upd);

    ctx_fill<<<(int)(MD / 256), 256, 0, stream>>>(vmean, ctx);
    ctx_scatter<<<B_ * H_ * U_, 64, 0, stream>>>(upd, mtop, ctx);

    mfma_gemm<<<256, 256, 0, stream>>>(ctx, fcw, fcout, M, DM_, DM_, 1.0f);
    ln_kernel<<<M, 256, 0, stream>>>(fcout, fcb, hs, lnw, lnb, out);
}

// Round 8
// 745.949 us; speedup vs baseline: 2.1177x; 1.1904x over previous
//
#include <hip/hip_runtime.h>
#include <hip/hip_bf16.h>

#define B_  2
#define S_  2048
#define DM_ 1024
#define H_  16
#define DK_ 64
#define SK_ 40   // SAMPLE_K
#define U_  40   // top-k u
#define CH_ 128  // attn chunk columns
#define NCH_ (S_ / CH_)  // 16

typedef __attribute__((ext_vector_type(8))) short short8;
typedef __attribute__((ext_vector_type(4))) float f32x4;

union BF16S { __hip_bfloat16 h; short s; };
static __device__ __forceinline__ short f2bs(float x) {
    BF16S u; u.h = __float2bfloat16(x); return u.s;
}

// ================= split-bf16 MFMA GEMM for q/k (fp32-fidelity ~1e-5).
// C = A@B * scale via Ah·Bh + Ah·Bl + Al·Bh. Tile 64x128, BK=32, 4 waves.
__global__ __launch_bounds__(256) void gemm_qk_split(const float* __restrict__ A,
                                                     const float* __restrict__ Bm,
                                                     float* __restrict__ C,
                                                     int M, int N, int K, float scale) {
    __shared__ __hip_bfloat16 Ah[64][40], Al[64][40];    // [m][k]
    __shared__ __hip_bfloat16 Bh[128][40], Bl[128][40];  // [n][k] transposed
    int nbx = N >> 7;
    int by = blockIdx.x / nbx, bx = blockIdx.x % nbx;
    int tid = threadIdx.x, lane = tid & 63, w = tid >> 6;
    int ml = lane & 15, kq = lane >> 4;

    f32x4 acc[4][2];
#pragma unroll
    for (int i = 0; i < 4; ++i)
#pragma unroll
        for (int j = 0; j < 2; ++j) acc[i][j] = (f32x4){0.f, 0.f, 0.f, 0.f};

    const float* Ab = A + (size_t)(by * 64) * K;
    const float* Bb = Bm + bx * 128;
    int ar = tid >> 2, akq = (tid & 3) * 8;    // A stage: row, k-offset
    int bkr = tid >> 3, bcq = (tid & 7) * 16;  // B stage: k-row, col-offset

    for (int k0 = 0; k0 < K; k0 += 32) {
        // stage A hi/lo
        {
            float av[8];
            *(float4*)&av[0] = *(const float4*)(Ab + (size_t)ar * K + k0 + akq);
            *(float4*)&av[4] = *(const float4*)(Ab + (size_t)ar * K + k0 + akq + 4);
#pragma unroll
            for (int e = 0; e < 8; ++e) {
                __hip_bfloat16 hi = __float2bfloat16(av[e]);
                Ah[ar][akq + e] = hi;
                Al[ar][akq + e] = __float2bfloat16(av[e] - __bfloat162float(hi));
            }
        }
        // stage B hi/lo (transposed)
#pragma unroll
        for (int j = 0; j < 4; ++j) {
            float4 bv = *(const float4*)(Bb + (size_t)(k0 + bkr) * N + bcq + j * 4);
            float be[4] = {bv.x, bv.y, bv.z, bv.w};
#pragma unroll
            for (int e = 0; e < 4; ++e) {
                int col = bcq + j * 4 + e;
                __hip_bfloat16 hi = __float2bfloat16(be[e]);
                Bh[col][bkr] = hi;
                Bl[col][bkr] = __float2bfloat16(be[e] - __bfloat162float(hi));
            }
        }
        __syncthreads();
        short8 ah[4], al[4], bh[2], bl[2];
#pragma unroll
        for (int mt = 0; mt < 4; ++mt) {
            ah[mt] = *(const short8*)&Ah[mt * 16 + ml][kq * 8];
            al[mt] = *(const short8*)&Al[mt * 16 + ml][kq * 8];
        }
#pragma unroll
        for (int nt = 0; nt < 2; ++nt) {
            bh[nt] = *(const short8*)&Bh[w * 32 + nt * 16 + ml][kq * 8];
            bl[nt] = *(const short8*)&Bl[w * 32 + nt * 16 + ml][kq * 8];
        }
#pragma unroll
        for (int mt = 0; mt < 4; ++mt)
#pragma unroll
            for (int nt = 0; nt < 2; ++nt) {
                acc[mt][nt] = __builtin_amdgcn_mfma_f32_16x16x32_bf16(ah[mt], bh[nt], acc[mt][nt], 0, 0, 0);
                acc[mt][nt] = __builtin_amdgcn_mfma_f32_16x16x32_bf16(ah[mt], bl[nt], acc[mt][nt], 0, 0, 0);
                acc[mt][nt] = __builtin_amdgcn_mfma_f32_16x16x32_bf16(al[mt], bh[nt], acc[mt][nt], 0, 0, 0);
            }
        __syncthreads();
    }
#pragma unroll
    for (int mt = 0; mt < 4; ++mt)
#pragma unroll
        for (int nt = 0; nt < 2; ++nt)
#pragma unroll
            for (int r = 0; r < 4; ++r) {
                int row = by * 64 + mt * 16 + kq * 4 + r;
                int col = bx * 128 + w * 32 + nt * 16 + ml;
                C[(size_t)row * N + col] = acc[mt][nt][r] * scale;
            }
}

// ================= plain bf16 MFMA GEMM (v, fc). Tile 64x128, BK=32.
__global__ __launch_bounds__(256) void mfma_gemm_v2(const float* __restrict__ A,
                                                    const float* __restrict__ Bm,
                                                    float* __restrict__ C,
                                                    int M, int N, int K, float scale) {
    __shared__ __hip_bfloat16 Asb[64][40];   // [m][k]
    __shared__ __hip_bfloat16 Bsb[128][40];  // [n][k] transposed
    int nbx = N >> 7;
    int by = blockIdx.x / nbx, bx = blockIdx.x % nbx;
    int tid = threadIdx.x, lane = tid & 63, w = tid >> 6;
    int ml = lane & 15, kq = lane >> 4;

    f32x4 acc[4][2];
#pragma unroll
    for (int i = 0; i < 4; ++i)
#pragma unroll
        for (int j = 0; j < 2; ++j) acc[i][j] = (f32x4){0.f, 0.f, 0.f, 0.f};

    const float* Ab = A + (size_t)(by * 64) * K;
    const float* Bb = Bm + bx * 128;
    int ar = tid >> 2, akq = (tid & 3) * 8;
    int bkr = tid >> 3, bcq = (tid & 7) * 16;

    for (int k0 = 0; k0 < K; k0 += 32) {
        {
            float av[8];
            *(float4*)&av[0] = *(const float4*)(Ab + (size_t)ar * K + k0 + akq);
            *(float4*)&av[4] = *(const float4*)(Ab + (size_t)ar * K + k0 + akq + 4);
#pragma unroll
            for (int e = 0; e < 8; ++e) Asb[ar][akq + e] = __float2bfloat16(av[e]);
        }
#pragma unroll
        for (int j = 0; j < 4; ++j) {
            float4 bv = *(const float4*)(Bb + (size_t)(k0 + bkr) * N + bcq + j * 4);
            Bsb[bcq + j * 4 + 0][bkr] = __float2bfloat16(bv.x);
            Bsb[bcq + j * 4 + 1][bkr] = __float2bfloat16(bv.y);
            Bsb[bcq + j * 4 + 2][bkr] = __float2bfloat16(bv.z);
            Bsb[bcq + j * 4 + 3][bkr] = __float2bfloat16(bv.w);
        }
        __syncthreads();
        short8 af[4], bf[2];
#pragma unroll
        for (int mt = 0; mt < 4; ++mt) af[mt] = *(const short8*)&Asb[mt * 16 + ml][kq * 8];
#pragma unroll
        for (int nt = 0; nt < 2; ++nt) bf[nt] = *(const short8*)&Bsb[w * 32 + nt * 16 + ml][kq * 8];
#pragma unroll
        for (int mt = 0; mt < 4; ++mt)
#pragma unroll
            for (int nt = 0; nt < 2; ++nt)
                acc[mt][nt] = __builtin_amdgcn_mfma_f32_16x16x32_bf16(af[mt], bf[nt], acc[mt][nt], 0, 0, 0);
        __syncthreads();
    }
#pragma unroll
    for (int mt = 0; mt < 4; ++mt)
#pragma unroll
        for (int nt = 0; nt < 2; ++nt)
#pragma unroll
            for (int r = 0; r < 4; ++r) {
                int row = by * 64 + mt * 16 + kq * 4 + r;
                int col = bx * 128 + w * 32 + nt * 16 + ml;
                C[(size_t)row * N + col] = acc[mt][nt][r] * scale;
            }
}

// ================= m-score: one wave per (b,h,l); lane = sample index.
__global__ void m_score_v2(const float* __restrict__ q, const float* __restrict__ k,
                           const int* __restrict__ idxs, float* __restrict__ m_out) {
    int gwave = blockIdx.x * 4 + (threadIdx.x >> 6);
    int lane = threadIdx.x & 63;
    if (gwave >= B_ * H_ * S_) return;
    int l = gwave % S_;
    int bh = gwave / S_;
    int h = bh & 15, b = bh >> 4;

    const float* qr = q + ((size_t)(b * S_ + l)) * DM_ + h * DK_;
    const float* kb = k + (size_t)b * S_ * DM_ + h * DK_;
    int idx = 0;
    if (lane < SK_) {
        idx = idxs[l * SK_ + lane];
        idx = (idx < 0) ? 0 : (idx >= S_ ? S_ - 1 : idx);
    }
    const float* kr = kb + (size_t)idx * DM_;
    float dot = 0.f;
#pragma unroll
    for (int d = 0; d < DK_; d += 4) {
        float4 q4 = *(const float4*)(qr + d);
        float4 k4 = *(const float4*)(kr + d);
        dot += q4.x * k4.x + q4.y * k4.y + q4.z * k4.z + q4.w * k4.w;
    }
    float mx = (lane < SK_) ? dot : -INFINITY;
    float sm = (lane < SK_) ? dot : 0.f;
#pragma unroll
    for (int off = 32; off; off >>= 1) {
        mx = fmaxf(mx, __shfl_xor(mx, off, 64));
        sm += __shfl_xor(sm, off, 64);
    }
    if (lane == 0) m_out[(size_t)bh * S_ + l] = mx - sm * (1.f / (float)S_);
}

// ================= top-40 per block: iterative masked argmax
__global__ void topk_kernel(const float* __restrict__ m, int* __restrict__ mtop) {
    __shared__ float vals[S_];
    __shared__ float rv[256];
    __shared__ int ri[256];
    int bh = blockIdx.x, tid = threadIdx.x;
    for (int i = tid; i < S_; i += 256) vals[i] = m[(size_t)bh * S_ + i];
    __syncthreads();
    for (int it = 0; it < U_; ++it) {
        float best = -INFINITY;
        int bi = -1;
        for (int i = tid; i < S_; i += 256) {
            float v = vals[i];
            if (v > best) { best = v; bi = i; }
        }
        rv[tid] = best; ri[tid] = bi;
        __syncthreads();
        for (int s = 128; s; s >>= 1) {
            if (tid < s) {
                if ((ri[tid] < 0 && ri[tid + s] >= 0) ||
                    (ri[tid + s] >= 0 &&
                     (rv[tid + s] > rv[tid] ||
                      (rv[tid + s] == rv[tid] && ri[tid + s] < ri[tid])))) {
                    rv[tid] = rv[tid + s]; ri[tid] = ri[tid + s];
                }
            }
            __syncthreads();
        }
        if (tid == 0) {
            int r0 = (ri[0] >= 0 && ri[0] < S_) ? ri[0] : 0;
            mtop[bh * U_ + it] = r0;
            vals[r0] = -INFINITY;
        }
        __syncthreads();
    }
}

// ================= v mean over S per (b,h)
__global__ void vmean_kernel(const float* __restrict__ v, float* __restrict__ vm) {
    __shared__ float part[4][DK_];
    int bh = blockIdx.x, tid = threadIdx.x;
    int wave = tid >> 6, lane = tid & 63;
    int b = bh / H_, h = bh % H_;
    const float* vb = v + (size_t)b * S_ * DM_ + h * DK_;
    float s = 0.f;
    for (int l = wave; l < S_; l += 4) s += vb[(size_t)l * DM_ + lane];
    part[wave][lane] = s;
    __syncthreads();
    if (tid < DK_)
        vm[bh * DK_ + tid] =
            (part[0][tid] + part[1][tid] + part[2][tid] + part[3][tid]) * (1.f / (float)S_);
}

// ================= gather selected q rows -> qsel[bh][48][64] (rows 40..47 zero)
__global__ void gather_qsel(const float* __restrict__ q, const int* __restrict__ mtop,
                            float* __restrict__ qsel) {
    int bh = blockIdx.x;
    int b = bh >> 4, h = bh & 15;
    int tid = threadIdx.x;
    int u = tid >> 2, dq = (tid & 3) * 16;
    if (u >= 48) return;
    float* dst = qsel + ((size_t)bh * 48 + u) * 64 + dq;
    if (u < U_) {
        int row = mtop[bh * U_ + u];
        row = (row < 0) ? 0 : (row >= S_ ? S_ - 1 : row);
        const float* src = q + ((size_t)(b * S_ + row)) * DM_ + h * DK_ + dq;
#pragma unroll
        for (int j = 0; j < 16; j += 4) *(float4*)(dst + j) = *(const float4*)(src + j);
    } else {
        float4 z = {0.f, 0.f, 0.f, 0.f};
#pragma unroll
        for (int j = 0; j < 16; j += 4) *(float4*)(dst + j) = z;
    }
}

// ================= split-K flash attention, block per (b,h,chunk). 512 blocks.
__global__ __launch_bounds__(256) void attn_chunk(const float* __restrict__ qsel,
                                                  const float* __restrict__ k,
                                                  const float* __restrict__ v,
                                                  float* __restrict__ Opart,
                                                  float* __restrict__ Mpart,
                                                  float* __restrict__ Lpart) {
    __shared__ alignas(16) __hip_bfloat16 Qs[48][72];    // [u][d]
    __shared__ alignas(16) __hip_bfloat16 Vt[64][136];   // [d][k-in-chunk]
    __shared__ alignas(16) __hip_bfloat16 Ps[48][136];   // [u][k-in-chunk]
    __shared__ float mpart[4][48], lpart[4][48];
    __shared__ float mrow[48];
    int blk = blockIdx.x;
    int bh = blk / NCH_, ch = blk % NCH_;
    int b = bh >> 4, h = bh & 15;
    int c0 = ch * CH_;
    int tid = threadIdx.x, lane = tid & 63, w = tid >> 6;
    int ml = lane & 15, kq = lane >> 4;

    {
        int u = tid >> 2, dq = (tid & 3) * 16;
        if (u < 48) {
            const float* src = qsel + ((size_t)bh * 48 + u) * 64 + dq;
#pragma unroll
            for (int j = 0; j < 16; j += 4) {
                float4 v4 = *(const float4*)(src + j);
                Qs[u][dq + j + 0] = __float2bfloat16(v4.x);
                Qs[u][dq + j + 1] = __float2bfloat16(v4.y);
                Qs[u][dq + j + 2] = __float2bfloat16(v4.z);
                Qs[u][dq + j + 3] = __float2bfloat16(v4.w);
            }
        }
    }
    {
        int klocal = tid >> 1, dq = (tid & 1) * 32;
        const float* vr = v + (size_t)(b * S_ + c0 + klocal) * DM_ + h * DK_ + dq;
#pragma unroll
        for (int jj = 0; jj < 32; jj += 4) {
            float4 v4 = *(const float4*)(vr + jj);
            Vt[dq + jj + 0][klocal] = __float2bfloat16(v4.x);
            Vt[dq + jj + 1][klocal] = __float2bfloat16(v4.y);
            Vt[dq + jj + 2][klocal] = __float2bfloat16(v4.z);
            Vt[dq + jj + 3][klocal] = __float2bfloat16(v4.w);
        }
    }
    __syncthreads();

    const float* Kb = k + (size_t)b * S_ * DM_ + h * DK_;
    f32x4 sreg[3][2];
#pragma unroll
    for (int i = 0; i < 3; ++i)
#pragma unroll
        for (int j = 0; j < 2; ++j) sreg[i][j] = (f32x4){0.f, 0.f, 0.f, 0.f};
#pragma unroll
    for (int ntl = 0; ntl < 2; ++ntl) {
        int krow = c0 + (w * 2 + ntl) * 16 + ml;
        const float* kr = Kb + (size_t)krow * DM_;
        float4 x0 = *(const float4*)(kr + kq * 8);
        float4 x1 = *(const float4*)(kr + kq * 8 + 4);
        float4 y0 = *(const float4*)(kr + 32 + kq * 8);
        float4 y1 = *(const float4*)(kr + 32 + kq * 8 + 4);
        short8 b0, b1;
        b0[0] = f2bs(x0.x); b0[1] = f2bs(x0.y); b0[2] = f2bs(x0.z); b0[3] = f2bs(x0.w);
        b0[4] = f2bs(x1.x); b0[5] = f2bs(x1.y); b0[6] = f2bs(x1.z); b0[7] = f2bs(x1.w);
        b1[0] = f2bs(y0.x); b1[1] = f2bs(y0.y); b1[2] = f2bs(y0.z); b1[3] = f2bs(y0.w);
        b1[4] = f2bs(y1.x); b1[5] = f2bs(y1.y); b1[6] = f2bs(y1.z); b1[7] = f2bs(y1.w);
#pragma unroll
        for (int mt = 0; mt < 3; ++mt) {
            short8 a0 = *(const short8*)&Qs[mt * 16 + ml][kq * 8];
            short8 a1 = *(const short8*)&Qs[mt * 16 + ml][32 + kq * 8];
            sreg[mt][ntl] = __builtin_amdgcn_mfma_f32_16x16x32_bf16(a0, b0, sreg[mt][ntl], 0, 0, 0);
            sreg[mt][ntl] = __builtin_amdgcn_mfma_f32_16x16x32_bf16(a1, b1, sreg[mt][ntl], 0, 0, 0);
        }
    }

    {
        float vmx[3][4];
#pragma unroll
        for (int mt = 0; mt < 3; ++mt)
#pragma unroll
            for (int r = 0; r < 4; ++r)
                vmx[mt][r] = fmaxf(sreg[mt][0][r], sreg[mt][1][r]);
#pragma unroll
        for (int mask = 1; mask <= 8; mask <<= 1)
#pragma unroll
            for (int mt = 0; mt < 3; ++mt)
#pragma unroll
                for (int r = 0; r < 4; ++r)
                    vmx[mt][r] = fmaxf(vmx[mt][r], __shfl_xor(vmx[mt][r], mask, 64));
        if (ml == 0)
#pragma unroll
            for (int mt = 0; mt < 3; ++mt)
#pragma unroll
                for (int r = 0; r < 4; ++r)
                    mpart[w][mt * 16 + kq * 4 + r] = vmx[mt][r];
    }
    __syncthreads();
    if (tid < 48)
        mrow[tid] = fmaxf(fmaxf(mpart[0][tid], mpart[1][tid]),
                          fmaxf(mpart[2][tid], mpart[3][tid]));
    __syncthreads();

    {
        float vsum[3][4] = {{0.f}};
#pragma unroll
        for (int mt = 0; mt < 3; ++mt)
#pragma unroll
            for (int ntl = 0; ntl < 2; ++ntl) {
                int col = (w * 2 + ntl) * 16 + ml;
#pragma unroll
                for (int r = 0; r < 4; ++r) {
                    int row = mt * 16 + kq * 4 + r;
                    float p = __expf(sreg[mt][ntl][r] - mrow[row]);
                    Ps[row][col] = __float2bfloat16(p);
                    vsum[mt][r] += p;
                }
            }
#pragma unroll
        for (int mask = 1; mask <= 8; mask <<= 1)
#pragma unroll
            for (int mt = 0; mt < 3; ++mt)
#pragma unroll
                for (int r = 0; r < 4; ++r)
                    vsum[mt][r] += __shfl_xor(vsum[mt][r], mask, 64);
        if (ml == 0)
#pragma unroll
            for (int mt = 0; mt < 3; ++mt)
#pragma unroll
                for (int r = 0; r < 4; ++r)
                    lpart[w][mt * 16 + kq * 4 + r] = vsum[mt][r];
    }
    __syncthreads();

    f32x4 oreg[3];
#pragma unroll
    for (int i = 0; i < 3; ++i) oreg[i] = (f32x4){0.f, 0.f, 0.f, 0.f};
#pragma unroll
    for (int kt = 0; kt < 4; ++kt) {
        short8 bfq = *(const short8*)&Vt[w * 16 + ml][kt * 32 + kq * 8];
#pragma unroll
        for (int mt = 0; mt < 3; ++mt) {
            short8 af = *(const short8*)&Ps[mt * 16 + ml][kt * 32 + kq * 8];
            oreg[mt] = __builtin_amdgcn_mfma_f32_16x16x32_bf16(af, bfq, oreg[mt], 0, 0, 0);
        }
    }
#pragma unroll
    for (int mt = 0; mt < 3; ++mt)
#pragma unroll
        for (int r = 0; r < 4; ++r) {
            int row = mt * 16 + kq * 4 + r;
            Opart[((size_t)blk * 48 + row) * 64 + w * 16 + ml] = oreg[mt][r];
        }
    if (tid < 48) {
        Mpart[(size_t)blk * 48 + tid] = mrow[tid];
        Lpart[(size_t)blk * 48 + tid] =
            lpart[0][tid] + lpart[1][tid] + lpart[2][tid] + lpart[3][tid];
    }
}

// ================= combine chunk partials -> upd (block per bh)
__global__ void attn_combine(const float* __restrict__ Opart, const float* __restrict__ Mpart,
                             const float* __restrict__ Lpart, float* __restrict__ upd) {
    __shared__ float wfac[NCH_][48];
    __shared__ float lfin[48];
    int bh = blockIdx.x, tid = threadIdx.x;
    if (tid < 48) {
        float m = -1e30f;
        for (int c = 0; c < NCH_; ++c)
            m = fmaxf(m, Mpart[(size_t)(bh * NCH_ + c) * 48 + tid]);
        float l = 0.f;
        for (int c = 0; c < NCH_; ++c) {
            float wf = __expf(Mpart[(size_t)(bh * NCH_ + c) * 48 + tid] - m);
            wfac[c][tid] = wf;
            l += wf * Lpart[(size_t)(bh * NCH_ + c) * 48 + tid];
        }
        lfin[tid] = l;
    }
    __syncthreads();
    for (int e = tid; e < U_ * DK_; e += 256) {
        int row = e >> 6, col = e & 63;
        float o = 0.f;
        for (int c = 0; c < NCH_; ++c)
            o += wfac[c][row] * Opart[((size_t)(bh * NCH_ + c) * 48 + row) * 64 + col];
        upd[((size_t)bh * U_ + row) * DK_ + col] = o / lfin[row];
    }
}

// ================= ctx = broadcast v_mean (fp32)
__global__ void ctx_fill(const float* __restrict__ vm, float* __restrict__ ctx) {
    size_t i = (size_t)blockIdx.x * 256 + threadIdx.x;
    int c = (int)(i & (DM_ - 1));
    size_t bl = i >> 10;
    int b = (int)(bl >> 11);
    int h = c >> 6, d = c & (DK_ - 1);
    ctx[i] = vm[(b * H_ + h) * DK_ + d];
}

// ================= scatter upd rows into ctx
__global__ void ctx_scatter(const float* __restrict__ upd, const int* __restrict__ mtop,
                            float* __restrict__ ctx) {
    int blk = blockIdx.x;
    int bh = blk / U_;
    int b = bh / H_, h = bh % H_;
    int lane = threadIdx.x;
    int row = mtop[blk];
    row = (row < 0) ? 0 : (row >= S_ ? S_ - 1 : row);
    ctx[((size_t)(b * S_ + row)) * DM_ + h * DK_ + lane] = upd[(size_t)blk * DK_ + lane];
}

// ================= bias + residual + LayerNorm
__global__ void ln_kernel(const float* __restrict__ fcout, const float* __restrict__ fcb,
                          const float* __restrict__ resid,
                          const float* __restrict__ lnw, const float* __restrict__ lnb,
                          float* __restrict__ out) {
    __shared__ float red[256];
    int row = blockIdx.x, tid = threadIdx.x;
    float x[4];
#pragma unroll
    for (int j = 0; j < 4; ++j) {
        int c = tid + j * 256;
        x[j] = fcout[(size_t)row * DM_ + c] + fcb[c] + resid[(size_t)row * DM_ + c];
    }
    float s = x[0] + x[1] + x[2] + x[3];
    red[tid] = s;
    __syncthreads();
    for (int st = 128; st; st >>= 1) {
        if (tid < st) red[tid] += red[tid + st];
        __syncthreads();
    }
    float mu = red[0] * (1.f / (float)DM_);
    __syncthreads();
    float vs = 0.f;
#pragma unroll
    for (int j = 0; j < 4; ++j) { float d = x[j] - mu; vs += d * d; }
    red[tid] = vs;
    __syncthreads();
    for (int st = 128; st; st >>= 1) {
        if (tid < st) red[tid] += red[tid + st];
        __syncthreads();
    }
    float rstd = rsqrtf(red[0] * (1.f / (float)DM_) + 1e-6f);
#pragma unroll
    for (int j = 0; j < 4; ++j) {
        int c = tid + j * 256;
        out[(size_t)row * DM_ + c] = (x[j] - mu) * rstd * lnw[c] + lnb[c];
    }
}

// ================= launch =================

extern "C" void kernel_launch(void* const* d_in, const int* in_sizes, int n_in,
                              void* d_out, int out_size, void* d_ws, size_t ws_size,
                              hipStream_t stream) {
    if (n_in < 9 || d_ws == nullptr || d_out == nullptr) return;
    if (ws_size < 34ull * 1024 * 1024) return;

    const float* hs  = (const float*)d_in[0];
    const float* wq  = (const float*)d_in[1];
    const float* wk  = (const float*)d_in[2];
    const float* wv  = (const float*)d_in[3];
    const float* fcw = (const float*)d_in[4];
    const float* fcb = (const float*)d_in[5];
    const float* lnw = (const float*)d_in[6];
    const float* lnb = (const float*)d_in[7];
    const int* idxs  = (const int*)d_in[8];

    const size_t MD = (size_t)B_ * S_ * DM_;  // 4194304
    const int M = B_ * S_;                    // 4096
    float* ws = (float*)d_ws;
    float* out = (float*)d_out;

    float* q = ws;
    float* k = ws + MD;
    float* mbuf = ws + 2 * MD;                             // B*H*S
    float* vmean = mbuf + (size_t)B_ * H_ * S_;            // 2048
    float* upd = vmean + B_ * H_ * DK_;                    // 81920
    int* mtop = (int*)(upd + (size_t)B_ * H_ * U_ * DK_);  // 1280
    float* qsel = (float*)(mtop + B_ * H_ * U_);           // 98304
    float* v = out;
    float* Opart = q;                                 // 512*48*64 f (q dead post-gather)
    float* Mpart = Opart + (size_t)512 * 48 * 64;
    float* Lpart = Mpart + (size_t)512 * 48;
    float* ctx = q;    // after Opart dead (post-combine)
    float* fcout = k;  // after k dead (post-attn_chunk)

    // grids: (M/64)*(N/128) = 64*8 = 512 blocks
    gemm_qk_split<<<512, 256, 0, stream>>>(hs, wq, q, M, DM_, DM_, 0.125f);  // 1/sqrt(64)
    gemm_qk_split<<<512, 256, 0, stream>>>(hs, wk, k, M, DM_, DM_, 1.0f);
    mfma_gemm_v2<<<512, 256, 0, stream>>>(hs, wv, v, M, DM_, DM_, 1.0f);

    m_score_v2<<<(B_ * H_ * S_) / 4, 256, 0, stream>>>(q, k, idxs, mbuf);
    topk_kernel<<<B_ * H_, 256, 0, stream>>>(mbuf, mtop);
    vmean_kernel<<<B_ * H_, 256, 0, stream>>>(v, vmean);
    gather_qsel<<<B_ * H_, 256, 0, stream>>>(q, mtop, qsel);

    attn_chunk<<<B_ * H_ * NCH_, 256, 0, stream>>>(qsel, k, v, Opart, Mpart, Lpart);
    attn_combine<<<B_ * H_, 256, 0, stream>>>(Opart, Mpart, Lpart, upd);

    ctx_fill<<<(int)(MD / 256), 256, 0, stream>>>(vmean, ctx);
    ctx_scatter<<<B_ * H_ * U_, 64, 0, stream>>>(upd, mtop, ctx);

    mfma_gemm_v2<<<512, 256, 0, stream>>>(ctx, fcw, fcout, M, DM_, DM_, 1.0f);
    ln_kernel<<<M, 256, 0, stream>>>(fcout, fcb, hs, lnw, lnb, out);
}

// Round 9
// 599.723 us; speedup vs baseline: 2.6341x; 1.2438x over previous
//
#include <hip/hip_runtime.h>
#include <hip/hip_bf16.h>

#define B_  2
#define S_  2048
#define DM_ 1024
#define H_  16
#define DK_ 64
#define SK_ 40   // SAMPLE_K
#define U_  40   // top-k u
#define CH_ 128  // attn chunk columns
#define NCH_ (S_ / CH_)  // 16
#define VCH_ 64  // vmean chunks per (b,h)

typedef __attribute__((ext_vector_type(8))) short short8;
typedef __attribute__((ext_vector_type(4))) float f32x4;

union BF16S { __hip_bfloat16 h; short s; };
static __device__ __forceinline__ short f2bs(float x) {
    BF16S u; u.h = __float2bfloat16(x); return u.s;
}

// ================= split-bf16 MFMA GEMM for q/k (fp32-fidelity ~1e-5).
__global__ __launch_bounds__(256) void gemm_qk_split(const float* __restrict__ A,
                                                     const float* __restrict__ Bm,
                                                     float* __restrict__ C,
                                                     int M, int N, int K, float scale) {
    __shared__ __hip_bfloat16 Ah[64][40], Al[64][40];    // [m][k]
    __shared__ __hip_bfloat16 Bh[128][40], Bl[128][40];  // [n][k] transposed
    int nbx = N >> 7;
    int by = blockIdx.x / nbx, bx = blockIdx.x % nbx;
    int tid = threadIdx.x, lane = tid & 63, w = tid >> 6;
    int ml = lane & 15, kq = lane >> 4;

    f32x4 acc[4][2];
#pragma unroll
    for (int i = 0; i < 4; ++i)
#pragma unroll
        for (int j = 0; j < 2; ++j) acc[i][j] = (f32x4){0.f, 0.f, 0.f, 0.f};

    const float* Ab = A + (size_t)(by * 64) * K;
    const float* Bb = Bm + bx * 128;
    int ar = tid >> 2, akq = (tid & 3) * 8;
    int bkr = tid >> 3, bcq = (tid & 7) * 16;

    for (int k0 = 0; k0 < K; k0 += 32) {
        {
            float av[8];
            *(float4*)&av[0] = *(const float4*)(Ab + (size_t)ar * K + k0 + akq);
            *(float4*)&av[4] = *(const float4*)(Ab + (size_t)ar * K + k0 + akq + 4);
#pragma unroll
            for (int e = 0; e < 8; ++e) {
                __hip_bfloat16 hi = __float2bfloat16(av[e]);
                Ah[ar][akq + e] = hi;
                Al[ar][akq + e] = __float2bfloat16(av[e] - __bfloat162float(hi));
            }
        }
#pragma unroll
        for (int j = 0; j < 4; ++j) {
            float4 bv = *(const float4*)(Bb + (size_t)(k0 + bkr) * N + bcq + j * 4);
            float be[4] = {bv.x, bv.y, bv.z, bv.w};
#pragma unroll
            for (int e = 0; e < 4; ++e) {
                int col = bcq + j * 4 + e;
                __hip_bfloat16 hi = __float2bfloat16(be[e]);
                Bh[col][bkr] = hi;
                Bl[col][bkr] = __float2bfloat16(be[e] - __bfloat162float(hi));
            }
        }
        __syncthreads();
        short8 ah[4], al[4], bh[2], bl[2];
#pragma unroll
        for (int mt = 0; mt < 4; ++mt) {
            ah[mt] = *(const short8*)&Ah[mt * 16 + ml][kq * 8];
            al[mt] = *(const short8*)&Al[mt * 16 + ml][kq * 8];
        }
#pragma unroll
        for (int nt = 0; nt < 2; ++nt) {
            bh[nt] = *(const short8*)&Bh[w * 32 + nt * 16 + ml][kq * 8];
            bl[nt] = *(const short8*)&Bl[w * 32 + nt * 16 + ml][kq * 8];
        }
#pragma unroll
        for (int mt = 0; mt < 4; ++mt)
#pragma unroll
            for (int nt = 0; nt < 2; ++nt) {
                acc[mt][nt] = __builtin_amdgcn_mfma_f32_16x16x32_bf16(ah[mt], bh[nt], acc[mt][nt], 0, 0, 0);
                acc[mt][nt] = __builtin_amdgcn_mfma_f32_16x16x32_bf16(ah[mt], bl[nt], acc[mt][nt], 0, 0, 0);
                acc[mt][nt] = __builtin_amdgcn_mfma_f32_16x16x32_bf16(al[mt], bh[nt], acc[mt][nt], 0, 0, 0);
            }
        __syncthreads();
    }
#pragma unroll
    for (int mt = 0; mt < 4; ++mt)
#pragma unroll
        for (int nt = 0; nt < 2; ++nt)
#pragma unroll
            for (int r = 0; r < 4; ++r) {
                int row = by * 64 + mt * 16 + kq * 4 + r;
                int col = bx * 128 + w * 32 + nt * 16 + ml;
                C[(size_t)row * N + col] = acc[mt][nt][r] * scale;
            }
}

// ================= plain bf16 MFMA GEMM (v, fc). Tile 64x128, BK=32.
__global__ __launch_bounds__(256) void mfma_gemm_v2(const float* __restrict__ A,
                                                    const float* __restrict__ Bm,
                                                    float* __restrict__ C,
                                                    int M, int N, int K, float scale) {
    __shared__ __hip_bfloat16 Asb[64][40];   // [m][k]
    __shared__ __hip_bfloat16 Bsb[128][40];  // [n][k] transposed
    int nbx = N >> 7;
    int by = blockIdx.x / nbx, bx = blockIdx.x % nbx;
    int tid = threadIdx.x, lane = tid & 63, w = tid >> 6;
    int ml = lane & 15, kq = lane >> 4;

    f32x4 acc[4][2];
#pragma unroll
    for (int i = 0; i < 4; ++i)
#pragma unroll
        for (int j = 0; j < 2; ++j) acc[i][j] = (f32x4){0.f, 0.f, 0.f, 0.f};

    const float* Ab = A + (size_t)(by * 64) * K;
    const float* Bb = Bm + bx * 128;
    int ar = tid >> 2, akq = (tid & 3) * 8;
    int bkr = tid >> 3, bcq = (tid & 7) * 16;

    for (int k0 = 0; k0 < K; k0 += 32) {
        {
            float av[8];
            *(float4*)&av[0] = *(const float4*)(Ab + (size_t)ar * K + k0 + akq);
            *(float4*)&av[4] = *(const float4*)(Ab + (size_t)ar * K + k0 + akq + 4);
#pragma unroll
            for (int e = 0; e < 8; ++e) Asb[ar][akq + e] = __float2bfloat16(av[e]);
        }
#pragma unroll
        for (int j = 0; j < 4; ++j) {
            float4 bv = *(const float4*)(Bb + (size_t)(k0 + bkr) * N + bcq + j * 4);
            Bsb[bcq + j * 4 + 0][bkr] = __float2bfloat16(bv.x);
            Bsb[bcq + j * 4 + 1][bkr] = __float2bfloat16(bv.y);
            Bsb[bcq + j * 4 + 2][bkr] = __float2bfloat16(bv.z);
            Bsb[bcq + j * 4 + 3][bkr] = __float2bfloat16(bv.w);
        }
        __syncthreads();
        short8 af[4], bf[2];
#pragma unroll
        for (int mt = 0; mt < 4; ++mt) af[mt] = *(const short8*)&Asb[mt * 16 + ml][kq * 8];
#pragma unroll
        for (int nt = 0; nt < 2; ++nt) bf[nt] = *(const short8*)&Bsb[w * 32 + nt * 16 + ml][kq * 8];
#pragma unroll
        for (int mt = 0; mt < 4; ++mt)
#pragma unroll
            for (int nt = 0; nt < 2; ++nt)
                acc[mt][nt] = __builtin_amdgcn_mfma_f32_16x16x32_bf16(af[mt], bf[nt], acc[mt][nt], 0, 0, 0);
        __syncthreads();
    }
#pragma unroll
    for (int mt = 0; mt < 4; ++mt)
#pragma unroll
        for (int nt = 0; nt < 2; ++nt)
#pragma unroll
            for (int r = 0; r < 4; ++r) {
                int row = by * 64 + mt * 16 + kq * 4 + r;
                int col = bx * 128 + w * 32 + nt * 16 + ml;
                C[(size_t)row * N + col] = acc[mt][nt][r] * scale;
            }
}

// ================= m-score: one wave per (b,h,l); lane = sample index.
__global__ void m_score_v2(const float* __restrict__ q, const float* __restrict__ k,
                           const int* __restrict__ idxs, float* __restrict__ m_out) {
    int gwave = blockIdx.x * 4 + (threadIdx.x >> 6);
    int lane = threadIdx.x & 63;
    if (gwave >= B_ * H_ * S_) return;
    int l = gwave % S_;
    int bh = gwave / S_;
    int h = bh & 15, b = bh >> 4;

    const float* qr = q + ((size_t)(b * S_ + l)) * DM_ + h * DK_;
    const float* kb = k + (size_t)b * S_ * DM_ + h * DK_;
    int idx = 0;
    if (lane < SK_) {
        idx = idxs[l * SK_ + lane];
        idx = (idx < 0) ? 0 : (idx >= S_ ? S_ - 1 : idx);
    }
    const float* kr = kb + (size_t)idx * DM_;
    float dot = 0.f;
#pragma unroll
    for (int d = 0; d < DK_; d += 4) {
        float4 q4 = *(const float4*)(qr + d);
        float4 k4 = *(const float4*)(kr + d);
        dot += q4.x * k4.x + q4.y * k4.y + q4.z * k4.z + q4.w * k4.w;
    }
    float mx = (lane < SK_) ? dot : -INFINITY;
    float sm = (lane < SK_) ? dot : 0.f;
#pragma unroll
    for (int off = 32; off; off >>= 1) {
        mx = fmaxf(mx, __shfl_xor(mx, off, 64));
        sm += __shfl_xor(sm, off, 64);
    }
    if (lane == 0) m_out[(size_t)bh * S_ + l] = mx - sm * (1.f / (float)S_);
}

// ================= top-40 per block: iterative masked argmax
__global__ void topk_kernel(const float* __restrict__ m, int* __restrict__ mtop) {
    __shared__ float vals[S_];
    __shared__ float rv[256];
    __shared__ int ri[256];
    int bh = blockIdx.x, tid = threadIdx.x;
    for (int i = tid; i < S_; i += 256) vals[i] = m[(size_t)bh * S_ + i];
    __syncthreads();
    for (int it = 0; it < U_; ++it) {
        float best = -INFINITY;
        int bi = -1;
        for (int i = tid; i < S_; i += 256) {
            float v = vals[i];
            if (v > best) { best = v; bi = i; }
        }
        rv[tid] = best; ri[tid] = bi;
        __syncthreads();
        for (int s = 128; s; s >>= 1) {
            if (tid < s) {
                if ((ri[tid] < 0 && ri[tid + s] >= 0) ||
                    (ri[tid + s] >= 0 &&
                     (rv[tid + s] > rv[tid] ||
                      (rv[tid + s] == rv[tid] && ri[tid + s] < ri[tid])))) {
                    rv[tid] = rv[tid + s]; ri[tid] = ri[tid + s];
                }
            }
            __syncthreads();
        }
        if (tid == 0) {
            int r0 = (ri[0] >= 0 && ri[0] < S_) ? ri[0] : 0;
            mtop[bh * U_ + it] = r0;
            vals[r0] = -INFINITY;
        }
        __syncthreads();
    }
}

// ================= v mean, stage 1: block per (bh, 32-row chunk) -> partial sums
__global__ void vmean_part(const float* __restrict__ v, float* __restrict__ vpart) {
    __shared__ float part[4][DK_];
    int blk = blockIdx.x;               // bh*VCH_ + ch
    int bh = blk >> 6, ch = blk & (VCH_ - 1);
    int b = bh >> 4, h = bh & 15;
    int tid = threadIdx.x, wave = tid >> 6, lane = tid & 63;
    const float* vb = v + (size_t)(b * S_ + ch * 32) * DM_ + h * DK_;
    float s = 0.f;
#pragma unroll
    for (int i = 0; i < 8; ++i)
        s += vb[(size_t)(i * 4 + wave) * DM_ + lane];
    part[wave][lane] = s;
    __syncthreads();
    if (tid < DK_)
        vpart[(size_t)blk * DK_ + tid] =
            part[0][tid] + part[1][tid] + part[2][tid] + part[3][tid];
}

// ================= v mean, stage 2: 32 blocks x 64 threads
__global__ void vmean_comb(const float* __restrict__ vpart, float* __restrict__ vm) {
    int bh = blockIdx.x, lane = threadIdx.x;
    float s = 0.f;
    for (int c = 0; c < VCH_; ++c)
        s += vpart[(size_t)(bh * VCH_ + c) * DK_ + lane];
    vm[bh * DK_ + lane] = s * (1.f / (float)S_);
}

// ================= gather selected q rows -> qsel[bh][48][64] (rows 40..47 zero)
__global__ void gather_qsel(const float* __restrict__ q, const int* __restrict__ mtop,
                            float* __restrict__ qsel) {
    int bh = blockIdx.x;
    int b = bh >> 4, h = bh & 15;
    int tid = threadIdx.x;
    int u = tid >> 2, dq = (tid & 3) * 16;
    if (u >= 48) return;
    float* dst = qsel + ((size_t)bh * 48 + u) * 64 + dq;
    if (u < U_) {
        int row = mtop[bh * U_ + u];
        row = (row < 0) ? 0 : (row >= S_ ? S_ - 1 : row);
        const float* src = q + ((size_t)(b * S_ + row)) * DM_ + h * DK_ + dq;
#pragma unroll
        for (int j = 0; j < 16; j += 4) *(float4*)(dst + j) = *(const float4*)(src + j);
    } else {
        float4 z = {0.f, 0.f, 0.f, 0.f};
#pragma unroll
        for (int j = 0; j < 16; j += 4) *(float4*)(dst + j) = z;
    }
}

// ================= split-K flash attention, block per (b,h,chunk). 512 blocks.
__global__ __launch_bounds__(256) void attn_chunk(const float* __restrict__ qsel,
                                                  const float* __restrict__ k,
                                                  const float* __restrict__ v,
                                                  float* __restrict__ Opart,
                                                  float* __restrict__ Mpart,
                                                  float* __restrict__ Lpart) {
    __shared__ alignas(16) __hip_bfloat16 Qs[48][72];    // [u][d]
    __shared__ alignas(16) __hip_bfloat16 Vt[64][136];   // [d][k-in-chunk]
    __shared__ alignas(16) __hip_bfloat16 Ps[48][136];   // [u][k-in-chunk]
    __shared__ float mpart[4][48], lpart[4][48];
    __shared__ float mrow[48];
    int blk = blockIdx.x;
    int bh = blk / NCH_, ch = blk % NCH_;
    int b = bh >> 4, h = bh & 15;
    int c0 = ch * CH_;
    int tid = threadIdx.x, lane = tid & 63, w = tid >> 6;
    int ml = lane & 15, kq = lane >> 4;

    {
        int u = tid >> 2, dq = (tid & 3) * 16;
        if (u < 48) {
            const float* src = qsel + ((size_t)bh * 48 + u) * 64 + dq;
#pragma unroll
            for (int j = 0; j < 16; j += 4) {
                float4 v4 = *(const float4*)(src + j);
                Qs[u][dq + j + 0] = __float2bfloat16(v4.x);
                Qs[u][dq + j + 1] = __float2bfloat16(v4.y);
                Qs[u][dq + j + 2] = __float2bfloat16(v4.z);
                Qs[u][dq + j + 3] = __float2bfloat16(v4.w);
            }
        }
    }
    {
        int klocal = tid >> 1, dq = (tid & 1) * 32;
        const float* vr = v + (size_t)(b * S_ + c0 + klocal) * DM_ + h * DK_ + dq;
#pragma unroll
        for (int jj = 0; jj < 32; jj += 4) {
            float4 v4 = *(const float4*)(vr + jj);
            Vt[dq + jj + 0][klocal] = __float2bfloat16(v4.x);
            Vt[dq + jj + 1][klocal] = __float2bfloat16(v4.y);
            Vt[dq + jj + 2][klocal] = __float2bfloat16(v4.z);
            Vt[dq + jj + 3][klocal] = __float2bfloat16(v4.w);
        }
    }
    __syncthreads();

    const float* Kb = k + (size_t)b * S_ * DM_ + h * DK_;
    f32x4 sreg[3][2];
#pragma unroll
    for (int i = 0; i < 3; ++i)
#pragma unroll
        for (int j = 0; j < 2; ++j) sreg[i][j] = (f32x4){0.f, 0.f, 0.f, 0.f};
#pragma unroll
    for (int ntl = 0; ntl < 2; ++ntl) {
        int krow = c0 + (w * 2 + ntl) * 16 + ml;
        const float* kr = Kb + (size_t)krow * DM_;
        float4 x0 = *(const float4*)(kr + kq * 8);
        float4 x1 = *(const float4*)(kr + kq * 8 + 4);
        float4 y0 = *(const float4*)(kr + 32 + kq * 8);
        float4 y1 = *(const float4*)(kr + 32 + kq * 8 + 4);
        short8 b0, b1;
        b0[0] = f2bs(x0.x); b0[1] = f2bs(x0.y); b0[2] = f2bs(x0.z); b0[3] = f2bs(x0.w);
        b0[4] = f2bs(x1.x); b0[5] = f2bs(x1.y); b0[6] = f2bs(x1.z); b0[7] = f2bs(x1.w);
        b1[0] = f2bs(y0.x); b1[1] = f2bs(y0.y); b1[2] = f2bs(y0.z); b1[3] = f2bs(y0.w);
        b1[4] = f2bs(y1.x); b1[5] = f2bs(y1.y); b1[6] = f2bs(y1.z); b1[7] = f2bs(y1.w);
#pragma unroll
        for (int mt = 0; mt < 3; ++mt) {
            short8 a0 = *(const short8*)&Qs[mt * 16 + ml][kq * 8];
            short8 a1 = *(const short8*)&Qs[mt * 16 + ml][32 + kq * 8];
            sreg[mt][ntl] = __builtin_amdgcn_mfma_f32_16x16x32_bf16(a0, b0, sreg[mt][ntl], 0, 0, 0);
            sreg[mt][ntl] = __builtin_amdgcn_mfma_f32_16x16x32_bf16(a1, b1, sreg[mt][ntl], 0, 0, 0);
        }
    }

    {
        float vmx[3][4];
#pragma unroll
        for (int mt = 0; mt < 3; ++mt)
#pragma unroll
            for (int r = 0; r < 4; ++r)
                vmx[mt][r] = fmaxf(sreg[mt][0][r], sreg[mt][1][r]);
#pragma unroll
        for (int mask = 1; mask <= 8; mask <<= 1)
#pragma unroll
            for (int mt = 0; mt < 3; ++mt)
#pragma unroll
                for (int r = 0; r < 4; ++r)
                    vmx[mt][r] = fmaxf(vmx[mt][r], __shfl_xor(vmx[mt][r], mask, 64));
        if (ml == 0)
#pragma unroll
            for (int mt = 0; mt < 3; ++mt)
#pragma unroll
                for (int r = 0; r < 4; ++r)
                    mpart[w][mt * 16 + kq * 4 + r] = vmx[mt][r];
    }
    __syncthreads();
    if (tid < 48)
        mrow[tid] = fmaxf(fmaxf(mpart[0][tid], mpart[1][tid]),
                          fmaxf(mpart[2][tid], mpart[3][tid]));
    __syncthreads();

    {
        float vsum[3][4] = {{0.f}};
#pragma unroll
        for (int mt = 0; mt < 3; ++mt)
#pragma unroll
            for (int ntl = 0; ntl < 2; ++ntl) {
                int col = (w * 2 + ntl) * 16 + ml;
#pragma unroll
                for (int r = 0; r < 4; ++r) {
                    int row = mt * 16 + kq * 4 + r;
                    float p = __expf(sreg[mt][ntl][r] - mrow[row]);
                    Ps[row][col] = __float2bfloat16(p);
                    vsum[mt][r] += p;
                }
            }
#pragma unroll
        for (int mask = 1; mask <= 8; mask <<= 1)
#pragma unroll
            for (int mt = 0; mt < 3; ++mt)
#pragma unroll
                for (int r = 0; r < 4; ++r)
                    vsum[mt][r] += __shfl_xor(vsum[mt][r], mask, 64);
        if (ml == 0)
#pragma unroll
            for (int mt = 0; mt < 3; ++mt)
#pragma unroll
                for (int r = 0; r < 4; ++r)
                    lpart[w][mt * 16 + kq * 4 + r] = vsum[mt][r];
    }
    __syncthreads();

    f32x4 oreg[3];
#pragma unroll
    for (int i = 0; i < 3; ++i) oreg[i] = (f32x4){0.f, 0.f, 0.f, 0.f};
#pragma unroll
    for (int kt = 0; kt < 4; ++kt) {
        short8 bfq = *(const short8*)&Vt[w * 16 + ml][kt * 32 + kq * 8];
#pragma unroll
        for (int mt = 0; mt < 3; ++mt) {
            short8 af = *(const short8*)&Ps[mt * 16 + ml][kt * 32 + kq * 8];
            oreg[mt] = __builtin_amdgcn_mfma_f32_16x16x32_bf16(af, bfq, oreg[mt], 0, 0, 0);
        }
    }
#pragma unroll
    for (int mt = 0; mt < 3; ++mt)
#pragma unroll
        for (int r = 0; r < 4; ++r) {
            int row = mt * 16 + kq * 4 + r;
            Opart[((size_t)blk * 48 + row) * 64 + w * 16 + ml] = oreg[mt][r];
        }
    if (tid < 48) {
        Mpart[(size_t)blk * 48 + tid] = mrow[tid];
        Lpart[(size_t)blk * 48 + tid] =
            lpart[0][tid] + lpart[1][tid] + lpart[2][tid] + lpart[3][tid];
    }
}

// ================= combine chunk partials -> upd (block per bh)
__global__ void attn_combine(const float* __restrict__ Opart, const float* __restrict__ Mpart,
                             const float* __restrict__ Lpart, float* __restrict__ upd) {
    __shared__ float wfac[NCH_][48];
    __shared__ float lfin[48];
    int bh = blockIdx.x, tid = threadIdx.x;
    if (tid < 48) {
        float m = -1e30f;
        for (int c = 0; c < NCH_; ++c)
            m = fmaxf(m, Mpart[(size_t)(bh * NCH_ + c) * 48 + tid]);
        float l = 0.f;
        for (int c = 0; c < NCH_; ++c) {
            float wf = __expf(Mpart[(size_t)(bh * NCH_ + c) * 48 + tid] - m);
            wfac[c][tid] = wf;
            l += wf * Lpart[(size_t)(bh * NCH_ + c) * 48 + tid];
        }
        lfin[tid] = l;
    }
    __syncthreads();
    for (int e = tid; e < U_ * DK_; e += 256) {
        int row = e >> 6, col = e & 63;
        float o = 0.f;
        for (int c = 0; c < NCH_; ++c)
            o += wfac[c][row] * Opart[((size_t)(bh * NCH_ + c) * 48 + row) * 64 + col];
        upd[((size_t)bh * U_ + row) * DK_ + col] = o / lfin[row];
    }
}

// ================= ctx = broadcast v_mean (fp32, float4)
__global__ void ctx_fill(const float* __restrict__ vm, float* __restrict__ ctx) {
    size_t i = ((size_t)blockIdx.x * 256 + threadIdx.x) * 4;  // over B*S*DM
    int c = (int)(i & (DM_ - 1));
    size_t bl = i >> 10;
    int b = (int)(bl >> 11);
    int h = c >> 6, d = c & (DK_ - 1);
    *(float4*)(ctx + i) = *(const float4*)(vm + (b * H_ + h) * DK_ + d);
}

// ================= scatter upd rows into ctx
__global__ void ctx_scatter(const float* __restrict__ upd, const int* __restrict__ mtop,
                            float* __restrict__ ctx) {
    int blk = blockIdx.x;
    int bh = blk / U_;
    int b = bh / H_, h = bh % H_;
    int lane = threadIdx.x;
    int row = mtop[blk];
    row = (row < 0) ? 0 : (row >= S_ ? S_ - 1 : row);
    ctx[((size_t)(b * S_ + row)) * DM_ + h * DK_ + lane] = upd[(size_t)blk * DK_ + lane];
}

// ================= bias + residual + LayerNorm
__global__ void ln_kernel(const float* __restrict__ fcout, const float* __restrict__ fcb,
                          const float* __restrict__ resid,
                          const float* __restrict__ lnw, const float* __restrict__ lnb,
                          float* __restrict__ out) {
    __shared__ float red[256];
    int row = blockIdx.x, tid = threadIdx.x;
    float x[4];
#pragma unroll
    for (int j = 0; j < 4; ++j) {
        int c = tid + j * 256;
        x[j] = fcout[(size_t)row * DM_ + c] + fcb[c] + resid[(size_t)row * DM_ + c];
    }
    float s = x[0] + x[1] + x[2] + x[3];
    red[tid] = s;
    __syncthreads();
    for (int st = 128; st; st >>= 1) {
        if (tid < st) red[tid] += red[tid + st];
        __syncthreads();
    }
    float mu = red[0] * (1.f / (float)DM_);
    __syncthreads();
    float vs = 0.f;
#pragma unroll
    for (int j = 0; j < 4; ++j) { float d = x[j] - mu; vs += d * d; }
    red[tid] = vs;
    __syncthreads();
    for (int st = 128; st; st >>= 1) {
        if (tid < st) red[tid] += red[tid + st];
        __syncthreads();
    }
    float rstd = rsqrtf(red[0] * (1.f / (float)DM_) + 1e-6f);
#pragma unroll
    for (int j = 0; j < 4; ++j) {
        int c = tid + j * 256;
        out[(size_t)row * DM_ + c] = (x[j] - mu) * rstd * lnw[c] + lnb[c];
    }
}

// ================= launch =================

extern "C" void kernel_launch(void* const* d_in, const int* in_sizes, int n_in,
                              void* d_out, int out_size, void* d_ws, size_t ws_size,
                              hipStream_t stream) {
    if (n_in < 9 || d_ws == nullptr || d_out == nullptr) return;
    if (ws_size < 34ull * 1024 * 1024) return;

    const float* hs  = (const float*)d_in[0];
    const float* wq  = (const float*)d_in[1];
    const float* wk  = (const float*)d_in[2];
    const float* wv  = (const float*)d_in[3];
    const float* fcw = (const float*)d_in[4];
    const float* fcb = (const float*)d_in[5];
    const float* lnw = (const float*)d_in[6];
    const float* lnb = (const float*)d_in[7];
    const int* idxs  = (const int*)d_in[8];

    const size_t MD = (size_t)B_ * S_ * DM_;  // 4194304
    const int M = B_ * S_;                    // 4096
    float* ws = (float*)d_ws;
    float* out = (float*)d_out;

    float* q = ws;
    float* k = ws + MD;
    float* mbuf = ws + 2 * MD;                             // B*H*S = 65536 f
    float* vmean = mbuf + (size_t)B_ * H_ * S_;            // 2048 f
    float* upd = vmean + B_ * H_ * DK_;                    // 81920 f
    int* mtop = (int*)(upd + (size_t)B_ * H_ * U_ * DK_);  // 1280 i
    float* qsel = (float*)(mtop + B_ * H_ * U_);           // 98304 f
    float* vpart = qsel + (size_t)B_ * H_ * 48 * 64;       // 32*64*64 = 131072 f
    float* v = out;
    float* Opart = q;                                 // q dead post-gather
    float* Mpart = Opart + (size_t)512 * 48 * 64;
    float* Lpart = Mpart + (size_t)512 * 48;
    float* ctx = q;    // after Opart dead (post-combine)
    float* fcout = k;  // after k dead (post-attn_chunk)

    gemm_qk_split<<<512, 256, 0, stream>>>(hs, wq, q, M, DM_, DM_, 0.125f);  // 1/sqrt(64)
    gemm_qk_split<<<512, 256, 0, stream>>>(hs, wk, k, M, DM_, DM_, 1.0f);
    mfma_gemm_v2<<<512, 256, 0, stream>>>(hs, wv, v, M, DM_, DM_, 1.0f);

    m_score_v2<<<(B_ * H_ * S_) / 4, 256, 0, stream>>>(q, k, idxs, mbuf);
    topk_kernel<<<B_ * H_, 256, 0, stream>>>(mbuf, mtop);
    vmean_part<<<B_ * H_ * VCH_, 256, 0, stream>>>(v, vpart);
    vmean_comb<<<B_ * H_, 64, 0, stream>>>(vpart, vmean);
    gather_qsel<<<B_ * H_, 256, 0, stream>>>(q, mtop, qsel);

    attn_chunk<<<B_ * H_ * NCH_, 256, 0, stream>>>(qsel, k, v, Opart, Mpart, Lpart);
    attn_combine<<<B_ * H_, 256, 0, stream>>>(Opart, Mpart, Lpart, upd);

    ctx_fill<<<(int)(MD / 1024), 256, 0, stream>>>(vmean, ctx);
    ctx_scatter<<<B_ * H_ * U_, 64, 0, stream>>>(upd, mtop, ctx);

    mfma_gemm_v2<<<512, 256, 0, stream>>>(ctx, fcw, fcout, M, DM_, DM_, 1.0f);
    ln_kernel<<<M, 256, 0, stream>>>(fcout, fcb, hs, lnw, lnb, out);
}

// Round 10
// 520.922 us; speedup vs baseline: 3.0326x; 1.1513x over previous
//
#include <hip/hip_runtime.h>
#include <hip/hip_bf16.h>

#define B_  2
#define S_  2048
#define DM_ 1024
#define H_  16
#define DK_ 64
#define SK_ 40   // SAMPLE_K
#define U_  40   // top-k u
#define CH_ 128  // attn chunk columns
#define NCH_ (S_ / CH_)  // 16
#define VCH_ 64  // vmean chunks per (b,h)

typedef __attribute__((ext_vector_type(8))) short short8;
typedef __attribute__((ext_vector_type(4))) float f32x4;

union BF16S { __hip_bfloat16 h; short s; };
static __device__ __forceinline__ short f2bs(float x) {
    BF16S u; u.h = __float2bfloat16(x); return u.s;
}

// ================= split-bf16 MFMA GEMM for q/k (fp32-fidelity ~1e-5).
__global__ __launch_bounds__(256) void gemm_qk_split(const float* __restrict__ A,
                                                     const float* __restrict__ Bm,
                                                     float* __restrict__ C,
                                                     int M, int N, int K, float scale) {
    __shared__ __hip_bfloat16 Ah[64][40], Al[64][40];    // [m][k]
    __shared__ __hip_bfloat16 Bh[128][40], Bl[128][40];  // [n][k] transposed
    int nbx = N >> 7;
    int by = blockIdx.x / nbx, bx = blockIdx.x % nbx;
    int tid = threadIdx.x, lane = tid & 63, w = tid >> 6;
    int ml = lane & 15, kq = lane >> 4;

    f32x4 acc[4][2];
#pragma unroll
    for (int i = 0; i < 4; ++i)
#pragma unroll
        for (int j = 0; j < 2; ++j) acc[i][j] = (f32x4){0.f, 0.f, 0.f, 0.f};

    const float* Ab = A + (size_t)(by * 64) * K;
    const float* Bb = Bm + bx * 128;
    int ar = tid >> 2, akq = (tid & 3) * 8;
    int bkr = tid >> 3, bcq = (tid & 7) * 16;

    for (int k0 = 0; k0 < K; k0 += 32) {
        {
            float av[8];
            *(float4*)&av[0] = *(const float4*)(Ab + (size_t)ar * K + k0 + akq);
            *(float4*)&av[4] = *(const float4*)(Ab + (size_t)ar * K + k0 + akq + 4);
#pragma unroll
            for (int e = 0; e < 8; ++e) {
                __hip_bfloat16 hi = __float2bfloat16(av[e]);
                Ah[ar][akq + e] = hi;
                Al[ar][akq + e] = __float2bfloat16(av[e] - __bfloat162float(hi));
            }
        }
#pragma unroll
        for (int j = 0; j < 4; ++j) {
            float4 bv = *(const float4*)(Bb + (size_t)(k0 + bkr) * N + bcq + j * 4);
            float be[4] = {bv.x, bv.y, bv.z, bv.w};
#pragma unroll
            for (int e = 0; e < 4; ++e) {
                int col = bcq + j * 4 + e;
                __hip_bfloat16 hi = __float2bfloat16(be[e]);
                Bh[col][bkr] = hi;
                Bl[col][bkr] = __float2bfloat16(be[e] - __bfloat162float(hi));
            }
        }
        __syncthreads();
        short8 ah[4], al[4], bh[2], bl[2];
#pragma unroll
        for (int mt = 0; mt < 4; ++mt) {
            ah[mt] = *(const short8*)&Ah[mt * 16 + ml][kq * 8];
            al[mt] = *(const short8*)&Al[mt * 16 + ml][kq * 8];
        }
#pragma unroll
        for (int nt = 0; nt < 2; ++nt) {
            bh[nt] = *(const short8*)&Bh[w * 32 + nt * 16 + ml][kq * 8];
            bl[nt] = *(const short8*)&Bl[w * 32 + nt * 16 + ml][kq * 8];
        }
#pragma unroll
        for (int mt = 0; mt < 4; ++mt)
#pragma unroll
            for (int nt = 0; nt < 2; ++nt) {
                acc[mt][nt] = __builtin_amdgcn_mfma_f32_16x16x32_bf16(ah[mt], bh[nt], acc[mt][nt], 0, 0, 0);
                acc[mt][nt] = __builtin_amdgcn_mfma_f32_16x16x32_bf16(ah[mt], bl[nt], acc[mt][nt], 0, 0, 0);
                acc[mt][nt] = __builtin_amdgcn_mfma_f32_16x16x32_bf16(al[mt], bh[nt], acc[mt][nt], 0, 0, 0);
            }
        __syncthreads();
    }
#pragma unroll
    for (int mt = 0; mt < 4; ++mt)
#pragma unroll
        for (int nt = 0; nt < 2; ++nt)
#pragma unroll
            for (int r = 0; r < 4; ++r) {
                int row = by * 64 + mt * 16 + kq * 4 + r;
                int col = bx * 128 + w * 32 + nt * 16 + ml;
                C[(size_t)row * N + col] = acc[mt][nt][r] * scale;
            }
}

// ================= plain bf16 MFMA GEMM (v, fc). Tile 64x128, BK=32.
__global__ __launch_bounds__(256) void mfma_gemm_v2(const float* __restrict__ A,
                                                    const float* __restrict__ Bm,
                                                    float* __restrict__ C,
                                                    int M, int N, int K, float scale) {
    __shared__ __hip_bfloat16 Asb[64][40];   // [m][k]
    __shared__ __hip_bfloat16 Bsb[128][40];  // [n][k] transposed
    int nbx = N >> 7;
    int by = blockIdx.x / nbx, bx = blockIdx.x % nbx;
    int tid = threadIdx.x, lane = tid & 63, w = tid >> 6;
    int ml = lane & 15, kq = lane >> 4;

    f32x4 acc[4][2];
#pragma unroll
    for (int i = 0; i < 4; ++i)
#pragma unroll
        for (int j = 0; j < 2; ++j) acc[i][j] = (f32x4){0.f, 0.f, 0.f, 0.f};

    const float* Ab = A + (size_t)(by * 64) * K;
    const float* Bb = Bm + bx * 128;
    int ar = tid >> 2, akq = (tid & 3) * 8;
    int bkr = tid >> 3, bcq = (tid & 7) * 16;

    for (int k0 = 0; k0 < K; k0 += 32) {
        {
            float av[8];
            *(float4*)&av[0] = *(const float4*)(Ab + (size_t)ar * K + k0 + akq);
            *(float4*)&av[4] = *(const float4*)(Ab + (size_t)ar * K + k0 + akq + 4);
#pragma unroll
            for (int e = 0; e < 8; ++e) Asb[ar][akq + e] = __float2bfloat16(av[e]);
        }
#pragma unroll
        for (int j = 0; j < 4; ++j) {
            float4 bv = *(const float4*)(Bb + (size_t)(k0 + bkr) * N + bcq + j * 4);
            Bsb[bcq + j * 4 + 0][bkr] = __float2bfloat16(bv.x);
            Bsb[bcq + j * 4 + 1][bkr] = __float2bfloat16(bv.y);
            Bsb[bcq + j * 4 + 2][bkr] = __float2bfloat16(bv.z);
            Bsb[bcq + j * 4 + 3][bkr] = __float2bfloat16(bv.w);
        }
        __syncthreads();
        short8 af[4], bf[2];
#pragma unroll
        for (int mt = 0; mt < 4; ++mt) af[mt] = *(const short8*)&Asb[mt * 16 + ml][kq * 8];
#pragma unroll
        for (int nt = 0; nt < 2; ++nt) bf[nt] = *(const short8*)&Bsb[w * 32 + nt * 16 + ml][kq * 8];
#pragma unroll
        for (int mt = 0; mt < 4; ++mt)
#pragma unroll
            for (int nt = 0; nt < 2; ++nt)
                acc[mt][nt] = __builtin_amdgcn_mfma_f32_16x16x32_bf16(af[mt], bf[nt], acc[mt][nt], 0, 0, 0);
        __syncthreads();
    }
#pragma unroll
    for (int mt = 0; mt < 4; ++mt)
#pragma unroll
        for (int nt = 0; nt < 2; ++nt)
#pragma unroll
            for (int r = 0; r < 4; ++r) {
                int row = by * 64 + mt * 16 + kq * 4 + r;
                int col = bx * 128 + w * 32 + nt * 16 + ml;
                C[(size_t)row * N + col] = acc[mt][nt][r] * scale;
            }
}

// ================= m-score v3: one wave per (b,h,l); lane = (sample slot, d-chunk).
// 8 samples x 8 d-chunks per wave-instruction -> 8 distinct rows/load (vs 40).
__global__ void m_score_v3(const float* __restrict__ q, const float* __restrict__ k,
                           const int* __restrict__ idxs, float* __restrict__ m_out) {
    int gwave = blockIdx.x * 4 + (threadIdx.x >> 6);
    int lane = threadIdx.x & 63;
    if (gwave >= B_ * H_ * S_) return;
    int l = gwave % S_;
    int bh = gwave / S_;
    int h = bh & 15, b = bh >> 4;
    int sl = lane >> 3;   // sample slot 0..7
    int dc = lane & 7;    // d-chunk 0..7 (8 floats each)

    const float* qr = q + ((size_t)(b * S_ + l)) * DM_ + h * DK_ + dc * 8;
    float4 q0 = *(const float4*)qr;
    float4 q1 = *(const float4*)(qr + 4);
    const float* kb = k + (size_t)b * S_ * DM_ + h * DK_ + dc * 8;

    float mx = -INFINITY, sm = 0.f;
#pragma unroll
    for (int c = 0; c < 5; ++c) {
        int s = c * 8 + sl;
        int idx = idxs[l * SK_ + s];
        idx = (idx < 0) ? 0 : (idx >= S_ ? S_ - 1 : idx);
        const float* kr = kb + (size_t)idx * DM_;
        float4 k0 = *(const float4*)kr;
        float4 k1 = *(const float4*)(kr + 4);
        float d = q0.x * k0.x + q0.y * k0.y + q0.z * k0.z + q0.w * k0.w +
                  q1.x * k1.x + q1.y * k1.y + q1.z * k1.z + q1.w * k1.w;
        // reduce over the 8 d-chunk lanes (low 3 bits)
        d += __shfl_xor(d, 1, 64);
        d += __shfl_xor(d, 2, 64);
        d += __shfl_xor(d, 4, 64);
        mx = fmaxf(mx, d);
        sm += d;
    }
    // combine the 8 sample-groups (each holds stats over its 5 samples)
#pragma unroll
    for (int off = 8; off <= 32; off <<= 1) {
        mx = fmaxf(mx, __shfl_xor(mx, off, 64));
        sm += __shfl_xor(sm, off, 64);
    }
    if (lane == 0) m_out[(size_t)bh * S_ + l] = mx - sm * (1.f / (float)S_);
}

// ================= top-40 per block: iterative masked argmax
__global__ void topk_kernel(const float* __restrict__ m, int* __restrict__ mtop) {
    __shared__ float vals[S_];
    __shared__ float rv[256];
    __shared__ int ri[256];
    int bh = blockIdx.x, tid = threadIdx.x;
    for (int i = tid; i < S_; i += 256) vals[i] = m[(size_t)bh * S_ + i];
    __syncthreads();
    for (int it = 0; it < U_; ++it) {
        float best = -INFINITY;
        int bi = -1;
        for (int i = tid; i < S_; i += 256) {
            float v = vals[i];
            if (v > best) { best = v; bi = i; }
        }
        rv[tid] = best; ri[tid] = bi;
        __syncthreads();
        for (int s = 128; s; s >>= 1) {
            if (tid < s) {
                if ((ri[tid] < 0 && ri[tid + s] >= 0) ||
                    (ri[tid + s] >= 0 &&
                     (rv[tid + s] > rv[tid] ||
                      (rv[tid + s] == rv[tid] && ri[tid + s] < ri[tid])))) {
                    rv[tid] = rv[tid + s]; ri[tid] = ri[tid + s];
                }
            }
            __syncthreads();
        }
        if (tid == 0) {
            int r0 = (ri[0] >= 0 && ri[0] < S_) ? ri[0] : 0;
            mtop[bh * U_ + it] = r0;
            vals[r0] = -INFINITY;
        }
        __syncthreads();
    }
}

// ================= v mean, stage 1: block per (bh, 32-row chunk) -> partial sums
__global__ void vmean_part(const float* __restrict__ v, float* __restrict__ vpart) {
    __shared__ float part[4][DK_];
    int blk = blockIdx.x;               // bh*VCH_ + ch
    int bh = blk >> 6, ch = blk & (VCH_ - 1);
    int b = bh >> 4, h = bh & 15;
    int tid = threadIdx.x, wave = tid >> 6, lane = tid & 63;
    const float* vb = v + (size_t)(b * S_ + ch * 32) * DM_ + h * DK_;
    float s = 0.f;
#pragma unroll
    for (int i = 0; i < 8; ++i)
        s += vb[(size_t)(i * 4 + wave) * DM_ + lane];
    part[wave][lane] = s;
    __syncthreads();
    if (tid < DK_)
        vpart[(size_t)blk * DK_ + tid] =
            part[0][tid] + part[1][tid] + part[2][tid] + part[3][tid];
}

// ================= v mean, stage 2: 32 blocks x 64 threads
__global__ void vmean_comb(const float* __restrict__ vpart, float* __restrict__ vm) {
    int bh = blockIdx.x, lane = threadIdx.x;
    float s = 0.f;
    for (int c = 0; c < VCH_; ++c)
        s += vpart[(size_t)(bh * VCH_ + c) * DK_ + lane];
    vm[bh * DK_ + lane] = s * (1.f / (float)S_);
}

// ================= gather selected q rows -> qsel[bh][48][64] (rows 40..47 zero)
__global__ void gather_qsel(const float* __restrict__ q, const int* __restrict__ mtop,
                            float* __restrict__ qsel) {
    int bh = blockIdx.x;
    int b = bh >> 4, h = bh & 15;
    int tid = threadIdx.x;
    int u = tid >> 2, dq = (tid & 3) * 16;
    if (u >= 48) return;
    float* dst = qsel + ((size_t)bh * 48 + u) * 64 + dq;
    if (u < U_) {
        int row = mtop[bh * U_ + u];
        row = (row < 0) ? 0 : (row >= S_ ? S_ - 1 : row);
        const float* src = q + ((size_t)(b * S_ + row)) * DM_ + h * DK_ + dq;
#pragma unroll
        for (int j = 0; j < 16; j += 4) *(float4*)(dst + j) = *(const float4*)(src + j);
    } else {
        float4 z = {0.f, 0.f, 0.f, 0.f};
#pragma unroll
        for (int j = 0; j < 16; j += 4) *(float4*)(dst + j) = z;
    }
}

// ================= split-K flash attention, block per (b,h,chunk). 512 blocks.
__global__ __launch_bounds__(256) void attn_chunk(const float* __restrict__ qsel,
                                                  const float* __restrict__ k,
                                                  const float* __restrict__ v,
                                                  float* __restrict__ Opart,
                                                  float* __restrict__ Mpart,
                                                  float* __restrict__ Lpart) {
    __shared__ alignas(16) __hip_bfloat16 Qs[48][72];    // [u][d]
    __shared__ alignas(16) __hip_bfloat16 Vt[64][136];   // [d][k-in-chunk]
    __shared__ alignas(16) __hip_bfloat16 Ps[48][136];   // [u][k-in-chunk]
    __shared__ float mpart[4][48], lpart[4][48];
    __shared__ float mrow[48];
    int blk = blockIdx.x;
    int bh = blk / NCH_, ch = blk % NCH_;
    int b = bh >> 4, h = bh & 15;
    int c0 = ch * CH_;
    int tid = threadIdx.x, lane = tid & 63, w = tid >> 6;
    int ml = lane & 15, kq = lane >> 4;

    {
        int u = tid >> 2, dq = (tid & 3) * 16;
        if (u < 48) {
            const float* src = qsel + ((size_t)bh * 48 + u) * 64 + dq;
#pragma unroll
            for (int j = 0; j < 16; j += 4) {
                float4 v4 = *(const float4*)(src + j);
                Qs[u][dq + j + 0] = __float2bfloat16(v4.x);
                Qs[u][dq + j + 1] = __float2bfloat16(v4.y);
                Qs[u][dq + j + 2] = __float2bfloat16(v4.z);
                Qs[u][dq + j + 3] = __float2bfloat16(v4.w);
            }
        }
    }
    {
        int klocal = tid >> 1, dq = (tid & 1) * 32;
        const float* vr = v + (size_t)(b * S_ + c0 + klocal) * DM_ + h * DK_ + dq;
#pragma unroll
        for (int jj = 0; jj < 32; jj += 4) {
            float4 v4 = *(const float4*)(vr + jj);
            Vt[dq + jj + 0][klocal] = __float2bfloat16(v4.x);
            Vt[dq + jj + 1][klocal] = __float2bfloat16(v4.y);
            Vt[dq + jj + 2][klocal] = __float2bfloat16(v4.z);
            Vt[dq + jj + 3][klocal] = __float2bfloat16(v4.w);
        }
    }
    __syncthreads();

    const float* Kb = k + (size_t)b * S_ * DM_ + h * DK_;
    f32x4 sreg[3][2];
#pragma unroll
    for (int i = 0; i < 3; ++i)
#pragma unroll
        for (int j = 0; j < 2; ++j) sreg[i][j] = (f32x4){0.f, 0.f, 0.f, 0.f};
#pragma unroll
    for (int ntl = 0; ntl < 2; ++ntl) {
        int krow = c0 + (w * 2 + ntl) * 16 + ml;
        const float* kr = Kb + (size_t)krow * DM_;
        float4 x0 = *(const float4*)(kr + kq * 8);
        float4 x1 = *(const float4*)(kr + kq * 8 + 4);
        float4 y0 = *(const float4*)(kr + 32 + kq * 8);
        float4 y1 = *(const float4*)(kr + 32 + kq * 8 + 4);
        short8 b0, b1;
        b0[0] = f2bs(x0.x); b0[1] = f2bs(x0.y); b0[2] = f2bs(x0.z); b0[3] = f2bs(x0.w);
        b0[4] = f2bs(x1.x); b0[5] = f2bs(x1.y); b0[6] = f2bs(x1.z); b0[7] = f2bs(x1.w);
        b1[0] = f2bs(y0.x); b1[1] = f2bs(y0.y); b1[2] = f2bs(y0.z); b1[3] = f2bs(y0.w);
        b1[4] = f2bs(y1.x); b1[5] = f2bs(y1.y); b1[6] = f2bs(y1.z); b1[7] = f2bs(y1.w);
#pragma unroll
        for (int mt = 0; mt < 3; ++mt) {
            short8 a0 = *(const short8*)&Qs[mt * 16 + ml][kq * 8];
            short8 a1 = *(const short8*)&Qs[mt * 16 + ml][32 + kq * 8];
            sreg[mt][ntl] = __builtin_amdgcn_mfma_f32_16x16x32_bf16(a0, b0, sreg[mt][ntl], 0, 0, 0);
            sreg[mt][ntl] = __builtin_amdgcn_mfma_f32_16x16x32_bf16(a1, b1, sreg[mt][ntl], 0, 0, 0);
        }
    }

    {
        float vmx[3][4];
#pragma unroll
        for (int mt = 0; mt < 3; ++mt)
#pragma unroll
            for (int r = 0; r < 4; ++r)
                vmx[mt][r] = fmaxf(sreg[mt][0][r], sreg[mt][1][r]);
#pragma unroll
        for (int mask = 1; mask <= 8; mask <<= 1)
#pragma unroll
            for (int mt = 0; mt < 3; ++mt)
#pragma unroll
                for (int r = 0; r < 4; ++r)
                    vmx[mt][r] = fmaxf(vmx[mt][r], __shfl_xor(vmx[mt][r], mask, 64));
        if (ml == 0)
#pragma unroll
            for (int mt = 0; mt < 3; ++mt)
#pragma unroll
                for (int r = 0; r < 4; ++r)
                    mpart[w][mt * 16 + kq * 4 + r] = vmx[mt][r];
    }
    __syncthreads();
    if (tid < 48)
        mrow[tid] = fmaxf(fmaxf(mpart[0][tid], mpart[1][tid]),
                          fmaxf(mpart[2][tid], mpart[3][tid]));
    __syncthreads();

    {
        float vsum[3][4] = {{0.f}};
#pragma unroll
        for (int mt = 0; mt < 3; ++mt)
#pragma unroll
            for (int ntl = 0; ntl < 2; ++ntl) {
                int col = (w * 2 + ntl) * 16 + ml;
#pragma unroll
                for (int r = 0; r < 4; ++r) {
                    int row = mt * 16 + kq * 4 + r;
                    float p = __expf(sreg[mt][ntl][r] - mrow[row]);
                    Ps[row][col] = __float2bfloat16(p);
                    vsum[mt][r] += p;
                }
            }
#pragma unroll
        for (int mask = 1; mask <= 8; mask <<= 1)
#pragma unroll
            for (int mt = 0; mt < 3; ++mt)
#pragma unroll
                for (int r = 0; r < 4; ++r)
                    vsum[mt][r] += __shfl_xor(vsum[mt][r], mask, 64);
        if (ml == 0)
#pragma unroll
            for (int mt = 0; mt < 3; ++mt)
#pragma unroll
                for (int r = 0; r < 4; ++r)
                    lpart[w][mt * 16 + kq * 4 + r] = vsum[mt][r];
    }
    __syncthreads();

    f32x4 oreg[3];
#pragma unroll
    for (int i = 0; i < 3; ++i) oreg[i] = (f32x4){0.f, 0.f, 0.f, 0.f};
#pragma unroll
    for (int kt = 0; kt < 4; ++kt) {
        short8 bfq = *(const short8*)&Vt[w * 16 + ml][kt * 32 + kq * 8];
#pragma unroll
        for (int mt = 0; mt < 3; ++mt) {
            short8 af = *(const short8*)&Ps[mt * 16 + ml][kt * 32 + kq * 8];
            oreg[mt] = __builtin_amdgcn_mfma_f32_16x16x32_bf16(af, bfq, oreg[mt], 0, 0, 0);
        }
    }
#pragma unroll
    for (int mt = 0; mt < 3; ++mt)
#pragma unroll
        for (int r = 0; r < 4; ++r) {
            int row = mt * 16 + kq * 4 + r;
            Opart[((size_t)blk * 48 + row) * 64 + w * 16 + ml] = oreg[mt][r];
        }
    if (tid < 48) {
        Mpart[(size_t)blk * 48 + tid] = mrow[tid];
        Lpart[(size_t)blk * 48 + tid] =
            lpart[0][tid] + lpart[1][tid] + lpart[2][tid] + lpart[3][tid];
    }
}

// ================= combine chunk partials -> upd (block per bh)
__global__ void attn_combine(const float* __restrict__ Opart, const float* __restrict__ Mpart,
                             const float* __restrict__ Lpart, float* __restrict__ upd) {
    __shared__ float wfac[NCH_][48];
    __shared__ float lfin[48];
    int bh = blockIdx.x, tid = threadIdx.x;
    if (tid < 48) {
        float m = -1e30f;
        for (int c = 0; c < NCH_; ++c)
            m = fmaxf(m, Mpart[(size_t)(bh * NCH_ + c) * 48 + tid]);
        float l = 0.f;
        for (int c = 0; c < NCH_; ++c) {
            float wf = __expf(Mpart[(size_t)(bh * NCH_ + c) * 48 + tid] - m);
            wfac[c][tid] = wf;
            l += wf * Lpart[(size_t)(bh * NCH_ + c) * 48 + tid];
        }
        lfin[tid] = l;
    }
    __syncthreads();
    for (int e = tid; e < U_ * DK_; e += 256) {
        int row = e >> 6, col = e & 63;
        float o = 0.f;
        for (int c = 0; c < NCH_; ++c)
            o += wfac[c][row] * Opart[((size_t)(bh * NCH_ + c) * 48 + row) * 64 + col];
        upd[((size_t)bh * U_ + row) * DK_ + col] = o / lfin[row];
    }
}

// ================= ctx = broadcast v_mean (fp32, float4)
__global__ void ctx_fill(const float* __restrict__ vm, float* __restrict__ ctx) {
    size_t i = ((size_t)blockIdx.x * 256 + threadIdx.x) * 4;  // over B*S*DM
    int c = (int)(i & (DM_ - 1));
    size_t bl = i >> 10;
    int b = (int)(bl >> 11);
    int h = c >> 6, d = c & (DK_ - 1);
    *(float4*)(ctx + i) = *(const float4*)(vm + (b * H_ + h) * DK_ + d);
}

// ================= scatter upd rows into ctx
__global__ void ctx_scatter(const float* __restrict__ upd, const int* __restrict__ mtop,
                            float* __restrict__ ctx) {
    int blk = blockIdx.x;
    int bh = blk / U_;
    int b = bh / H_, h = bh % H_;
    int lane = threadIdx.x;
    int row = mtop[blk];
    row = (row < 0) ? 0 : (row >= S_ ? S_ - 1 : row);
    ctx[((size_t)(b * S_ + row)) * DM_ + h * DK_ + lane] = upd[(size_t)blk * DK_ + lane];
}

// ================= bias + residual + LayerNorm
__global__ void ln_kernel(const float* __restrict__ fcout, const float* __restrict__ fcb,
                          const float* __restrict__ resid,
                          const float* __restrict__ lnw, const float* __restrict__ lnb,
                          float* __restrict__ out) {
    __shared__ float red[256];
    int row = blockIdx.x, tid = threadIdx.x;
    float x[4];
#pragma unroll
    for (int j = 0; j < 4; ++j) {
        int c = tid + j * 256;
        x[j] = fcout[(size_t)row * DM_ + c] + fcb[c] + resid[(size_t)row * DM_ + c];
    }
    float s = x[0] + x[1] + x[2] + x[3];
    red[tid] = s;
    __syncthreads();
    for (int st = 128; st; st >>= 1) {
        if (tid < st) red[tid] += red[tid + st];
        __syncthreads();
    }
    float mu = red[0] * (1.f / (float)DM_);
    __syncthreads();
    float vs = 0.f;
#pragma unroll
    for (int j = 0; j < 4; ++j) { float d = x[j] - mu; vs += d * d; }
    red[tid] = vs;
    __syncthreads();
    for (int st = 128; st; st >>= 1) {
        if (tid < st) red[tid] += red[tid + st];
        __syncthreads();
    }
    float rstd = rsqrtf(red[0] * (1.f / (float)DM_) + 1e-6f);
#pragma unroll
    for (int j = 0; j < 4; ++j) {
        int c = tid + j * 256;
        out[(size_t)row * DM_ + c] = (x[j] - mu) * rstd * lnw[c] + lnb[c];
    }
}

// ================= launch =================

extern "C" void kernel_launch(void* const* d_in, const int* in_sizes, int n_in,
                              void* d_out, int out_size, void* d_ws, size_t ws_size,
                              hipStream_t stream) {
    if (n_in < 9 || d_ws == nullptr || d_out == nullptr) return;
    if (ws_size < 34ull * 1024 * 1024) return;

    const float* hs  = (const float*)d_in[0];
    const float* wq  = (const float*)d_in[1];
    const float* wk  = (const float*)d_in[2];
    const float* wv  = (const float*)d_in[3];
    const float* fcw = (const float*)d_in[4];
    const float* fcb = (const float*)d_in[5];
    const float* lnw = (const float*)d_in[6];
    const float* lnb = (const float*)d_in[7];
    const int* idxs  = (const int*)d_in[8];

    const size_t MD = (size_t)B_ * S_ * DM_;  // 4194304
    const int M = B_ * S_;                    // 4096
    float* ws = (float*)d_ws;
    float* out = (float*)d_out;

    float* q = ws;
    float* k = ws + MD;
    float* mbuf = ws + 2 * MD;                             // B*H*S = 65536 f
    float* vmean = mbuf + (size_t)B_ * H_ * S_;            // 2048 f
    float* upd = vmean + B_ * H_ * DK_;                    // 81920 f
    int* mtop = (int*)(upd + (size_t)B_ * H_ * U_ * DK_);  // 1280 i
    float* qsel = (float*)(mtop + B_ * H_ * U_);           // 98304 f
    float* vpart = qsel + (size_t)B_ * H_ * 48 * 64;       // 131072 f
    float* v = out;
    float* Opart = q;                                 // q dead post-gather
    float* Mpart = Opart + (size_t)512 * 48 * 64;
    float* Lpart = Mpart + (size_t)512 * 48;
    float* ctx = q;    // after Opart dead (post-combine)
    float* fcout = k;  // after k dead (post-attn_chunk)

    gemm_qk_split<<<512, 256, 0, stream>>>(hs, wq, q, M, DM_, DM_, 0.125f);  // 1/sqrt(64)
    gemm_qk_split<<<512, 256, 0, stream>>>(hs, wk, k, M, DM_, DM_, 1.0f);
    mfma_gemm_v2<<<512, 256, 0, stream>>>(hs, wv, v, M, DM_, DM_, 1.0f);

    m_score_v3<<<(B_ * H_ * S_) / 4, 256, 0, stream>>>(q, k, idxs, mbuf);
    topk_kernel<<<B_ * H_, 256, 0, stream>>>(mbuf, mtop);
    vmean_part<<<B_ * H_ * VCH_, 256, 0, stream>>>(v, vpart);
    vmean_comb<<<B_ * H_, 64, 0, stream>>>(vpart, vmean);
    gather_qsel<<<B_ * H_, 256, 0, stream>>>(q, mtop, qsel);

    attn_chunk<<<B_ * H_ * NCH_, 256, 0, stream>>>(qsel, k, v, Opart, Mpart, Lpart);
    attn_combine<<<B_ * H_, 256, 0, stream>>>(Opart, Mpart, Lpart, upd);

    ctx_fill<<<(int)(MD / 1024), 256, 0, stream>>>(vmean, ctx);
    ctx_scatter<<<B_ * H_ * U_, 64, 0, stream>>>(upd, mtop, ctx);

    mfma_gemm_v2<<<512, 256, 0, stream>>>(ctx, fcw, fcout, M, DM_, DM_, 1.0f);
    ln_kernel<<<M, 256, 0, stream>>>(fcout, fcb, hs, lnw, lnb, out);
}

// Round 11
// 397.394 us; speedup vs baseline: 3.9752x; 1.3108x over previous
//
#include <hip/hip_runtime.h>
#include <hip/hip_bf16.h>

#define B_  2
#define S_  2048
#define DM_ 1024
#define H_  16
#define DK_ 64
#define SK_ 40   // SAMPLE_K
#define U_  40   // top-k u
#define CH_ 128  // attn chunk columns
#define NCH_ (S_ / CH_)  // 16
#define VCH_ 64  // vmean chunks per (b,h)

typedef __attribute__((ext_vector_type(8))) short short8;
typedef __attribute__((ext_vector_type(4))) float f32x4;

union BF16S { __hip_bfloat16 h; short s; };
static __device__ __forceinline__ short f2bs(float x) {
    BF16S u; u.h = __float2bfloat16(x); return u.s;
}

// ================= split-bf16 MFMA GEMM for q/k (fp32-fidelity ~1e-5).
// Tile 64x128, BK=32. All LDS writes are ds_write_b128 on a conflict-free
// 40-elem (20-word) stride: col*20 mod 32 cycles 8 disjoint quads per phase.
__global__ __launch_bounds__(256) void gemm_qk_split(const float* __restrict__ A,
                                                     const float* __restrict__ Bm,
                                                     float* __restrict__ C,
                                                     int M, int N, int K, float scale) {
    __shared__ alignas(16) __hip_bfloat16 Ah[64][40], Al[64][40];    // [m][k]
    __shared__ alignas(16) __hip_bfloat16 Bh[128][40], Bl[128][40];  // [n][k] transposed
    int nbx = N >> 7;
    int by = blockIdx.x / nbx, bx = blockIdx.x % nbx;
    int tid = threadIdx.x, lane = tid & 63, w = tid >> 6;
    int ml = lane & 15, kq = lane >> 4;

    f32x4 acc[4][2];
#pragma unroll
    for (int i = 0; i < 4; ++i)
#pragma unroll
        for (int j = 0; j < 2; ++j) acc[i][j] = (f32x4){0.f, 0.f, 0.f, 0.f};

    const float* Ab = A + (size_t)(by * 64) * K;
    const float* Bb = Bm + bx * 128;
    int ar = tid >> 2, akq = (tid & 3) * 8;   // A stage: row, 8-k chunk
    int bcol = tid & 127, bkh = tid >> 7;     // B stage: col, 16-k half

    for (int k0 = 0; k0 < K; k0 += 32) {
        // ---- stage A hi/lo: k-contiguous read, 2x b128 write
        {
            float av[8];
            *(float4*)&av[0] = *(const float4*)(Ab + (size_t)ar * K + k0 + akq);
            *(float4*)&av[4] = *(const float4*)(Ab + (size_t)ar * K + k0 + akq + 4);
            short8 hv, lv;
#pragma unroll
            for (int e = 0; e < 8; ++e) {
                __hip_bfloat16 hb = __float2bfloat16(av[e]);
                hv[e] = ((BF16S){hb}).s;
                lv[e] = f2bs(av[e] - __bfloat162float(hb));
            }
            *(short8*)&Ah[ar][akq] = hv;
            *(short8*)&Al[ar][akq] = lv;
        }
        // ---- stage B hi/lo: 16 k-strided coalesced loads, 4x b128 writes
        {
            float be[16];
            const float* bp = Bb + (size_t)(k0 + bkh * 16) * N + bcol;
#pragma unroll
            for (int j = 0; j < 16; ++j) be[j] = bp[(size_t)j * N];
            short8 h0, h1, l0, l1;
#pragma unroll
            for (int e = 0; e < 8; ++e) {
                __hip_bfloat16 hb = __float2bfloat16(be[e]);
                h0[e] = ((BF16S){hb}).s;
                l0[e] = f2bs(be[e] - __bfloat162float(hb));
                __hip_bfloat16 hb2 = __float2bfloat16(be[e + 8]);
                h1[e] = ((BF16S){hb2}).s;
                l1[e] = f2bs(be[e + 8] - __bfloat162float(hb2));
            }
            *(short8*)&Bh[bcol][bkh * 16] = h0;
            *(short8*)&Bh[bcol][bkh * 16 + 8] = h1;
            *(short8*)&Bl[bcol][bkh * 16] = l0;
            *(short8*)&Bl[bcol][bkh * 16 + 8] = l1;
        }
        __syncthreads();
        short8 ah[4], al[4], bh[2], bl[2];
#pragma unroll
        for (int mt = 0; mt < 4; ++mt) {
            ah[mt] = *(const short8*)&Ah[mt * 16 + ml][kq * 8];
            al[mt] = *(const short8*)&Al[mt * 16 + ml][kq * 8];
        }
#pragma unroll
        for (int nt = 0; nt < 2; ++nt) {
            bh[nt] = *(const short8*)&Bh[w * 32 + nt * 16 + ml][kq * 8];
            bl[nt] = *(const short8*)&Bl[w * 32 + nt * 16 + ml][kq * 8];
        }
#pragma unroll
        for (int mt = 0; mt < 4; ++mt)
#pragma unroll
            for (int nt = 0; nt < 2; ++nt) {
                acc[mt][nt] = __builtin_amdgcn_mfma_f32_16x16x32_bf16(ah[mt], bh[nt], acc[mt][nt], 0, 0, 0);
                acc[mt][nt] = __builtin_amdgcn_mfma_f32_16x16x32_bf16(ah[mt], bl[nt], acc[mt][nt], 0, 0, 0);
                acc[mt][nt] = __builtin_amdgcn_mfma_f32_16x16x32_bf16(al[mt], bh[nt], acc[mt][nt], 0, 0, 0);
            }
        __syncthreads();
    }
#pragma unroll
    for (int mt = 0; mt < 4; ++mt)
#pragma unroll
        for (int nt = 0; nt < 2; ++nt)
#pragma unroll
            for (int r = 0; r < 4; ++r) {
                int row = by * 64 + mt * 16 + kq * 4 + r;
                int col = bx * 128 + w * 32 + nt * 16 + ml;
                C[(size_t)row * N + col] = acc[mt][nt][r] * scale;
            }
}

// ================= plain bf16 MFMA GEMM (v, fc). Tile 64x128, BK=32.
// Same conflict-free vector staging as gemm_qk_split.
__global__ __launch_bounds__(256) void mfma_gemm_v2(const float* __restrict__ A,
                                                    const float* __restrict__ Bm,
                                                    float* __restrict__ C,
                                                    int M, int N, int K, float scale) {
    __shared__ alignas(16) __hip_bfloat16 Asb[64][40];   // [m][k]
    __shared__ alignas(16) __hip_bfloat16 Bsb[128][40];  // [n][k] transposed
    int nbx = N >> 7;
    int by = blockIdx.x / nbx, bx = blockIdx.x % nbx;
    int tid = threadIdx.x, lane = tid & 63, w = tid >> 6;
    int ml = lane & 15, kq = lane >> 4;

    f32x4 acc[4][2];
#pragma unroll
    for (int i = 0; i < 4; ++i)
#pragma unroll
        for (int j = 0; j < 2; ++j) acc[i][j] = (f32x4){0.f, 0.f, 0.f, 0.f};

    const float* Ab = A + (size_t)(by * 64) * K;
    const float* Bb = Bm + bx * 128;
    int ar = tid >> 2, akq = (tid & 3) * 8;
    int bcol = tid & 127, bkh = tid >> 7;

    for (int k0 = 0; k0 < K; k0 += 32) {
        {
            float av[8];
            *(float4*)&av[0] = *(const float4*)(Ab + (size_t)ar * K + k0 + akq);
            *(float4*)&av[4] = *(const float4*)(Ab + (size_t)ar * K + k0 + akq + 4);
            short8 hv;
#pragma unroll
            for (int e = 0; e < 8; ++e) hv[e] = f2bs(av[e]);
            *(short8*)&Asb[ar][akq] = hv;
        }
        {
            float be[16];
            const float* bp = Bb + (size_t)(k0 + bkh * 16) * N + bcol;
#pragma unroll
            for (int j = 0; j < 16; ++j) be[j] = bp[(size_t)j * N];
            short8 h0, h1;
#pragma unroll
            for (int e = 0; e < 8; ++e) {
                h0[e] = f2bs(be[e]);
                h1[e] = f2bs(be[e + 8]);
            }
            *(short8*)&Bsb[bcol][bkh * 16] = h0;
            *(short8*)&Bsb[bcol][bkh * 16 + 8] = h1;
        }
        __syncthreads();
        short8 af[4], bf[2];
#pragma unroll
        for (int mt = 0; mt < 4; ++mt) af[mt] = *(const short8*)&Asb[mt * 16 + ml][kq * 8];
#pragma unroll
        for (int nt = 0; nt < 2; ++nt) bf[nt] = *(const short8*)&Bsb[w * 32 + nt * 16 + ml][kq * 8];
#pragma unroll
        for (int mt = 0; mt < 4; ++mt)
#pragma unroll
            for (int nt = 0; nt < 2; ++nt)
                acc[mt][nt] = __builtin_amdgcn_mfma_f32_16x16x32_bf16(af[mt], bf[nt], acc[mt][nt], 0, 0, 0);
        __syncthreads();
    }
#pragma unroll
    for (int mt = 0; mt < 4; ++mt)
#pragma unroll
        for (int nt = 0; nt < 2; ++nt)
#pragma unroll
            for (int r = 0; r < 4; ++r) {
                int row = by * 64 + mt * 16 + kq * 4 + r;
                int col = bx * 128 + w * 32 + nt * 16 + ml;
                C[(size_t)row * N + col] = acc[mt][nt][r] * scale;
            }
}

// ================= m-score v3: one wave per (b,h,l); lane = (sample slot, d-chunk).
__global__ void m_score_v3(const float* __restrict__ q, const float* __restrict__ k,
                           const int* __restrict__ idxs, float* __restrict__ m_out) {
    int gwave = blockIdx.x * 4 + (threadIdx.x >> 6);
    int lane = threadIdx.x & 63;
    if (gwave >= B_ * H_ * S_) return;
    int l = gwave % S_;
    int bh = gwave / S_;
    int h = bh & 15, b = bh >> 4;
    int sl = lane >> 3;   // sample slot 0..7
    int dc = lane & 7;    // d-chunk 0..7 (8 floats each)

    const float* qr = q + ((size_t)(b * S_ + l)) * DM_ + h * DK_ + dc * 8;
    float4 q0 = *(const float4*)qr;
    float4 q1 = *(const float4*)(qr + 4);
    const float* kb = k + (size_t)b * S_ * DM_ + h * DK_ + dc * 8;

    float mx = -INFINITY, sm = 0.f;
#pragma unroll
    for (int c = 0; c < 5; ++c) {
        int s = c * 8 + sl;
        int idx = idxs[l * SK_ + s];
        idx = (idx < 0) ? 0 : (idx >= S_ ? S_ - 1 : idx);
        const float* kr = kb + (size_t)idx * DM_;
        float4 k0 = *(const float4*)kr;
        float4 k1 = *(const float4*)(kr + 4);
        float d = q0.x * k0.x + q0.y * k0.y + q0.z * k0.z + q0.w * k0.w +
                  q1.x * k1.x + q1.y * k1.y + q1.z * k1.z + q1.w * k1.w;
        d += __shfl_xor(d, 1, 64);
        d += __shfl_xor(d, 2, 64);
        d += __shfl_xor(d, 4, 64);
        mx = fmaxf(mx, d);
        sm += d;
    }
#pragma unroll
    for (int off = 8; off <= 32; off <<= 1) {
        mx = fmaxf(mx, __shfl_xor(mx, off, 64));
        sm += __shfl_xor(sm, off, 64);
    }
    if (lane == 0) m_out[(size_t)bh * S_ + l] = mx - sm * (1.f / (float)S_);
}

// ================= top-40 per block: iterative masked argmax
__global__ void topk_kernel(const float* __restrict__ m, int* __restrict__ mtop) {
    __shared__ float vals[S_];
    __shared__ float rv[256];
    __shared__ int ri[256];
    int bh = blockIdx.x, tid = threadIdx.x;
    for (int i = tid; i < S_; i += 256) vals[i] = m[(size_t)bh * S_ + i];
    __syncthreads();
    for (int it = 0; it < U_; ++it) {
        float best = -INFINITY;
        int bi = -1;
        for (int i = tid; i < S_; i += 256) {
            float v = vals[i];
            if (v > best) { best = v; bi = i; }
        }
        rv[tid] = best; ri[tid] = bi;
        __syncthreads();
        for (int s = 128; s; s >>= 1) {
            if (tid < s) {
                if ((ri[tid] < 0 && ri[tid + s] >= 0) ||
                    (ri[tid + s] >= 0 &&
                     (rv[tid + s] > rv[tid] ||
                      (rv[tid + s] == rv[tid] && ri[tid + s] < ri[tid])))) {
                    rv[tid] = rv[tid + s]; ri[tid] = ri[tid + s];
                }
            }
            __syncthreads();
        }
        if (tid == 0) {
            int r0 = (ri[0] >= 0 && ri[0] < S_) ? ri[0] : 0;
            mtop[bh * U_ + it] = r0;
            vals[r0] = -INFINITY;
        }
        __syncthreads();
    }
}

// ================= v mean, stage 1: block per (bh, 32-row chunk) -> partial sums
__global__ void vmean_part(const float* __restrict__ v, float* __restrict__ vpart) {
    __shared__ float part[4][DK_];
    int blk = blockIdx.x;               // bh*VCH_ + ch
    int bh = blk >> 6, ch = blk & (VCH_ - 1);
    int b = bh >> 4, h = bh & 15;
    int tid = threadIdx.x, wave = tid >> 6, lane = tid & 63;
    const float* vb = v + (size_t)(b * S_ + ch * 32) * DM_ + h * DK_;
    float s = 0.f;
#pragma unroll
    for (int i = 0; i < 8; ++i)
        s += vb[(size_t)(i * 4 + wave) * DM_ + lane];
    part[wave][lane] = s;
    __syncthreads();
    if (tid < DK_)
        vpart[(size_t)blk * DK_ + tid] =
            part[0][tid] + part[1][tid] + part[2][tid] + part[3][tid];
}

// ================= v mean, stage 2: 32 blocks x 64 threads
__global__ void vmean_comb(const float* __restrict__ vpart, float* __restrict__ vm) {
    int bh = blockIdx.x, lane = threadIdx.x;
    float s = 0.f;
    for (int c = 0; c < VCH_; ++c)
        s += vpart[(size_t)(bh * VCH_ + c) * DK_ + lane];
    vm[bh * DK_ + lane] = s * (1.f / (float)S_);
}

// ================= gather selected q rows -> qsel[bh][48][64] (rows 40..47 zero)
__global__ void gather_qsel(const float* __restrict__ q, const int* __restrict__ mtop,
                            float* __restrict__ qsel) {
    int bh = blockIdx.x;
    int b = bh >> 4, h = bh & 15;
    int tid = threadIdx.x;
    int u = tid >> 2, dq = (tid & 3) * 16;
    if (u >= 48) return;
    float* dst = qsel + ((size_t)bh * 48 + u) * 64 + dq;
    if (u < U_) {
        int row = mtop[bh * U_ + u];
        row = (row < 0) ? 0 : (row >= S_ ? S_ - 1 : row);
        const float* src = q + ((size_t)(b * S_ + row)) * DM_ + h * DK_ + dq;
#pragma unroll
        for (int j = 0; j < 16; j += 4) *(float4*)(dst + j) = *(const float4*)(src + j);
    } else {
        float4 z = {0.f, 0.f, 0.f, 0.f};
#pragma unroll
        for (int j = 0; j < 16; j += 4) *(float4*)(dst + j) = z;
    }
}

// ================= split-K flash attention, block per (b,h,chunk). 512 blocks.
__global__ __launch_bounds__(256) void attn_chunk(const float* __restrict__ qsel,
                                                  const float* __restrict__ k,
                                                  const float* __restrict__ v,
                                                  float* __restrict__ Opart,
                                                  float* __restrict__ Mpart,
                                                  float* __restrict__ Lpart) {
    __shared__ alignas(16) __hip_bfloat16 Qs[48][72];    // [u][d]
    __shared__ alignas(16) __hip_bfloat16 Vt[64][136];   // [d][k-in-chunk]
    __shared__ alignas(16) __hip_bfloat16 Ps[48][136];   // [u][k-in-chunk]
    __shared__ float mpart[4][48], lpart[4][48];
    __shared__ float mrow[48];
    int blk = blockIdx.x;
    int bh = blk / NCH_, ch = blk % NCH_;
    int b = bh >> 4, h = bh & 15;
    int c0 = ch * CH_;
    int tid = threadIdx.x, lane = tid & 63, w = tid >> 6;
    int ml = lane & 15, kq = lane >> 4;

    {
        int u = tid >> 2, dq = (tid & 3) * 16;
        if (u < 48) {
            const float* src = qsel + ((size_t)bh * 48 + u) * 64 + dq;
#pragma unroll
            for (int j = 0; j < 16; j += 4) {
                float4 v4 = *(const float4*)(src + j);
                Qs[u][dq + j + 0] = __float2bfloat16(v4.x);
                Qs[u][dq + j + 1] = __float2bfloat16(v4.y);
                Qs[u][dq + j + 2] = __float2bfloat16(v4.z);
                Qs[u][dq + j + 3] = __float2bfloat16(v4.w);
            }
        }
    }
    {
        int klocal = tid >> 1, dq = (tid & 1) * 32;
        const float* vr = v + (size_t)(b * S_ + c0 + klocal) * DM_ + h * DK_ + dq;
#pragma unroll
        for (int jj = 0; jj < 32; jj += 4) {
            float4 v4 = *(const float4*)(vr + jj);
            Vt[dq + jj + 0][klocal] = __float2bfloat16(v4.x);
            Vt[dq + jj + 1][klocal] = __float2bfloat16(v4.y);
            Vt[dq + jj + 2][klocal] = __float2bfloat16(v4.z);
            Vt[dq + jj + 3][klocal] = __float2bfloat16(v4.w);
        }
    }
    __syncthreads();

    const float* Kb = k + (size_t)b * S_ * DM_ + h * DK_;
    f32x4 sreg[3][2];
#pragma unroll
    for (int i = 0; i < 3; ++i)
#pragma unroll
        for (int j = 0; j < 2; ++j) sreg[i][j] = (f32x4){0.f, 0.f, 0.f, 0.f};
#pragma unroll
    for (int ntl = 0; ntl < 2; ++ntl) {
        int krow = c0 + (w * 2 + ntl) * 16 + ml;
        const float* kr = Kb + (size_t)krow * DM_;
        float4 x0 = *(const float4*)(kr + kq * 8);
        float4 x1 = *(const float4*)(kr + kq * 8 + 4);
        float4 y0 = *(const float4*)(kr + 32 + kq * 8);
        float4 y1 = *(const float4*)(kr + 32 + kq * 8 + 4);
        short8 b0, b1;
        b0[0] = f2bs(x0.x); b0[1] = f2bs(x0.y); b0[2] = f2bs(x0.z); b0[3] = f2bs(x0.w);
        b0[4] = f2bs(x1.x); b0[5] = f2bs(x1.y); b0[6] = f2bs(x1.z); b0[7] = f2bs(x1.w);
        b1[0] = f2bs(y0.x); b1[1] = f2bs(y0.y); b1[2] = f2bs(y0.z); b1[3] = f2bs(y0.w);
        b1[4] = f2bs(y1.x); b1[5] = f2bs(y1.y); b1[6] = f2bs(y1.z); b1[7] = f2bs(y1.w);
#pragma unroll
        for (int mt = 0; mt < 3; ++mt) {
            short8 a0 = *(const short8*)&Qs[mt * 16 + ml][kq * 8];
            short8 a1 = *(const short8*)&Qs[mt * 16 + ml][32 + kq * 8];
            sreg[mt][ntl] = __builtin_amdgcn_mfma_f32_16x16x32_bf16(a0, b0, sreg[mt][ntl], 0, 0, 0);
            sreg[mt][ntl] = __builtin_amdgcn_mfma_f32_16x16x32_bf16(a1, b1, sreg[mt][ntl], 0, 0, 0);
        }
    }

    {
        float vmx[3][4];
#pragma unroll
        for (int mt = 0; mt < 3; ++mt)
#pragma unroll
            for (int r = 0; r < 4; ++r)
                vmx[mt][r] = fmaxf(sreg[mt][0][r], sreg[mt][1][r]);
#pragma unroll
        for (int mask = 1; mask <= 8; mask <<= 1)
#pragma unroll
            for (int mt = 0; mt < 3; ++mt)
#pragma unroll
                for (int r = 0; r < 4; ++r)
                    vmx[mt][r] = fmaxf(vmx[mt][r], __shfl_xor(vmx[mt][r], mask, 64));
        if (ml == 0)
#pragma unroll
            for (int mt = 0; mt < 3; ++mt)
#pragma unroll
                for (int r = 0; r < 4; ++r)
                    mpart[w][mt * 16 + kq * 4 + r] = vmx[mt][r];
    }
    __syncthreads();
    if (tid < 48)
        mrow[tid] = fmaxf(fmaxf(mpart[0][tid], mpart[1][tid]),
                          fmaxf(mpart[2][tid], mpart[3][tid]));
    __syncthreads();

    {
        float vsum[3][4] = {{0.f}};
#pragma unroll
        for (int mt = 0; mt < 3; ++mt)
#pragma unroll
            for (int ntl = 0; ntl < 2; ++ntl) {
                int col = (w * 2 + ntl) * 16 + ml;
#pragma unroll
                for (int r = 0; r < 4; ++r) {
                    int row = mt * 16 + kq * 4 + r;
                    float p = __expf(sreg[mt][ntl][r] - mrow[row]);
                    Ps[row][col] = __float2bfloat16(p);
                    vsum[mt][r] += p;
                }
            }
#pragma unroll
        for (int mask = 1; mask <= 8; mask <<= 1)
#pragma unroll
            for (int mt = 0; mt < 3; ++mt)
#pragma unroll
                for (int r = 0; r < 4; ++r)
                    vsum[mt][r] += __shfl_xor(vsum[mt][r], mask, 64);
        if (ml == 0)
#pragma unroll
            for (int mt = 0; mt < 3; ++mt)
#pragma unroll
                for (int r = 0; r < 4; ++r)
                    lpart[w][mt * 16 + kq * 4 + r] = vsum[mt][r];
    }
    __syncthreads();

    f32x4 oreg[3];
#pragma unroll
    for (int i = 0; i < 3; ++i) oreg[i] = (f32x4){0.f, 0.f, 0.f, 0.f};
#pragma unroll
    for (int kt = 0; kt < 4; ++kt) {
        short8 bfq = *(const short8*)&Vt[w * 16 + ml][kt * 32 + kq * 8];
#pragma unroll
        for (int mt = 0; mt < 3; ++mt) {
            short8 af = *(const short8*)&Ps[mt * 16 + ml][kt * 32 + kq * 8];
            oreg[mt] = __builtin_amdgcn_mfma_f32_16x16x32_bf16(af, bfq, oreg[mt], 0, 0, 0);
        }
    }
#pragma unroll
    for (int mt = 0; mt < 3; ++mt)
#pragma unroll
        for (int r = 0; r < 4; ++r) {
            int row = mt * 16 + kq * 4 + r;
            Opart[((size_t)blk * 48 + row) * 64 + w * 16 + ml] = oreg[mt][r];
        }
    if (tid < 48) {
        Mpart[(size_t)blk * 48 + tid] = mrow[tid];
        Lpart[(size_t)blk * 48 + tid] =
            lpart[0][tid] + lpart[1][tid] + lpart[2][tid] + lpart[3][tid];
    }
}

// ================= combine chunk partials -> upd (block per bh)
__global__ void attn_combine(const float* __restrict__ Opart, const float* __restrict__ Mpart,
                             const float* __restrict__ Lpart, float* __restrict__ upd) {
    __shared__ float wfac[NCH_][48];
    __shared__ float lfin[48];
    int bh = blockIdx.x, tid = threadIdx.x;
    if (tid < 48) {
        float m = -1e30f;
        for (int c = 0; c < NCH_; ++c)
            m = fmaxf(m, Mpart[(size_t)(bh * NCH_ + c) * 48 + tid]);
        float l = 0.f;
        for (int c = 0; c < NCH_; ++c) {
            float wf = __expf(Mpart[(size_t)(bh * NCH_ + c) * 48 + tid] - m);
            wfac[c][tid] = wf;
            l += wf * Lpart[(size_t)(bh * NCH_ + c) * 48 + tid];
        }
        lfin[tid] = l;
    }
    __syncthreads();
    for (int e = tid; e < U_ * DK_; e += 256) {
        int row = e >> 6, col = e & 63;
        float o = 0.f;
        for (int c = 0; c < NCH_; ++c)
            o += wfac[c][row] * Opart[((size_t)(bh * NCH_ + c) * 48 + row) * 64 + col];
        upd[((size_t)bh * U_ + row) * DK_ + col] = o / lfin[row];
    }
}

// ================= ctx = broadcast v_mean (fp32, float4)
__global__ void ctx_fill(const float* __restrict__ vm, float* __restrict__ ctx) {
    size_t i = ((size_t)blockIdx.x * 256 + threadIdx.x) * 4;  // over B*S*DM
    int c = (int)(i & (DM_ - 1));
    size_t bl = i >> 10;
    int b = (int)(bl >> 11);
    int h = c >> 6, d = c & (DK_ - 1);
    *(float4*)(ctx + i) = *(const float4*)(vm + (b * H_ + h) * DK_ + d);
}

// ================= scatter upd rows into ctx
__global__ void ctx_scatter(const float* __restrict__ upd, const int* __restrict__ mtop,
                            float* __restrict__ ctx) {
    int blk = blockIdx.x;
    int bh = blk / U_;
    int b = bh / H_, h = bh % H_;
    int lane = threadIdx.x;
    int row = mtop[blk];
    row = (row < 0) ? 0 : (row >= S_ ? S_ - 1 : row);
    ctx[((size_t)(b * S_ + row)) * DM_ + h * DK_ + lane] = upd[(size_t)blk * DK_ + lane];
}

// ================= bias + residual + LayerNorm
__global__ void ln_kernel(const float* __restrict__ fcout, const float* __restrict__ fcb,
                          const float* __restrict__ resid,
                          const float* __restrict__ lnw, const float* __restrict__ lnb,
                          float* __restrict__ out) {
    __shared__ float red[256];
    int row = blockIdx.x, tid = threadIdx.x;
    float x[4];
#pragma unroll
    for (int j = 0; j < 4; ++j) {
        int c = tid + j * 256;
        x[j] = fcout[(size_t)row * DM_ + c] + fcb[c] + resid[(size_t)row * DM_ + c];
    }
    float s = x[0] + x[1] + x[2] + x[3];
    red[tid] = s;
    __syncthreads();
    for (int st = 128; st; st >>= 1) {
        if (tid < st) red[tid] += red[tid + st];
        __syncthreads();
    }
    float mu = red[0] * (1.f / (float)DM_);
    __syncthreads();
    float vs = 0.f;
#pragma unroll
    for (int j = 0; j < 4; ++j) { float d = x[j] - mu; vs += d * d; }
    red[tid] = vs;
    __syncthreads();
    for (int st = 128; st; st >>= 1) {
        if (tid < st) red[tid] += red[tid + st];
        __syncthreads();
    }
    float rstd = rsqrtf(red[0] * (1.f / (float)DM_) + 1e-6f);
#pragma unroll
    for (int j = 0; j < 4; ++j) {
        int c = tid + j * 256;
        out[(size_t)row * DM_ + c] = (x[j] - mu) * rstd * lnw[c] + lnb[c];
    }
}

// ================= launch =================

extern "C" void kernel_launch(void* const* d_in, const int* in_sizes, int n_in,
                              void* d_out, int out_size, void* d_ws, size_t ws_size,
                              hipStream_t stream) {
    if (n_in < 9 || d_ws == nullptr || d_out == nullptr) return;
    if (ws_size < 34ull * 1024 * 1024) return;

    const float* hs  = (const float*)d_in[0];
    const float* wq  = (const float*)d_in[1];
    const float* wk  = (const float*)d_in[2];
    const float* wv  = (const float*)d_in[3];
    const float* fcw = (const float*)d_in[4];
    const float* fcb = (const float*)d_in[5];
    const float* lnw = (const float*)d_in[6];
    const float* lnb = (const float*)d_in[7];
    const int* idxs  = (const int*)d_in[8];

    const size_t MD = (size_t)B_ * S_ * DM_;  // 4194304
    const int M = B_ * S_;                    // 4096
    float* ws = (float*)d_ws;
    float* out = (float*)d_out;

    float* q = ws;
    float* k = ws + MD;
    float* mbuf = ws + 2 * MD;                             // B*H*S = 65536 f
    float* vmean = mbuf + (size_t)B_ * H_ * S_;            // 2048 f
    float* upd = vmean + B_ * H_ * DK_;                    // 81920 f
    int* mtop = (int*)(upd + (size_t)B_ * H_ * U_ * DK_);  // 1280 i
    float* qsel = (float*)(mtop + B_ * H_ * U_);           // 98304 f
    float* vpart = qsel + (size_t)B_ * H_ * 48 * 64;       // 131072 f
    float* v = out;
    float* Opart = q;                                 // q dead post-gather
    float* Mpart = Opart + (size_t)512 * 48 * 64;
    float* Lpart = Mpart + (size_t)512 * 48;
    float* ctx = q;    // after Opart dead (post-combine)
    float* fcout = k;  // after k dead (post-attn_chunk)

    gemm_qk_split<<<512, 256, 0, stream>>>(hs, wq, q, M, DM_, DM_, 0.125f);  // 1/sqrt(64)
    gemm_qk_split<<<512, 256, 0, stream>>>(hs, wk, k, M, DM_, DM_, 1.0f);
    mfma_gemm_v2<<<512, 256, 0, stream>>>(hs, wv, v, M, DM_, DM_, 1.0f);

    m_score_v3<<<(B_ * H_ * S_) / 4, 256, 0, stream>>>(q, k, idxs, mbuf);
    topk_kernel<<<B_ * H_, 256, 0, stream>>>(mbuf, mtop);
    vmean_part<<<B_ * H_ * VCH_, 256, 0, stream>>>(v, vpart);
    vmean_comb<<<B_ * H_, 64, 0, stream>>>(vpart, vmean);
    gather_qsel<<<B_ * H_, 256, 0, stream>>>(q, mtop, qsel);

    attn_chunk<<<B_ * H_ * NCH_, 256, 0, stream>>>(qsel, k, v, Opart, Mpart, Lpart);
    attn_combine<<<B_ * H_, 256, 0, stream>>>(Opart, Mpart, Lpart, upd);

    ctx_fill<<<(int)(MD / 1024), 256, 0, stream>>>(vmean, ctx);
    ctx_scatter<<<B_ * H_ * U_, 64, 0, stream>>>(upd, mtop, ctx);

    mfma_gemm_v2<<<512, 256, 0, stream>>>(ctx, fcw, fcout, M, DM_, DM_, 1.0f);
    ln_kernel<<<M, 256, 0, stream>>>(fcout, fcb, hs, lnw, lnb, out);
}

// Round 12
// 357.345 us; speedup vs baseline: 4.4207x; 1.1121x over previous
//
#include <hip/hip_runtime.h>
#include <hip/hip_bf16.h>

#define B_  2
#define S_  2048
#define DM_ 1024
#define H_  16
#define DK_ 64
#define SK_ 40   // SAMPLE_K
#define U_  40   // top-k u
#define CH_ 128  // attn chunk columns
#define NCH_ (S_ / CH_)  // 16
#define VCH_ 64  // vmean chunks per (b,h)

typedef __attribute__((ext_vector_type(8))) short short8;
typedef __attribute__((ext_vector_type(4))) float f32x4;

union BF16S { __hip_bfloat16 h; short s; };
static __device__ __forceinline__ short f2bs(float x) {
    BF16S u; u.h = __float2bfloat16(x); return u.s;
}

// ================= split-bf16 MFMA GEMM for q/k (fp32-fidelity ~1e-5).
__global__ __launch_bounds__(256) void gemm_qk_split(const float* __restrict__ A,
                                                     const float* __restrict__ Bm,
                                                     float* __restrict__ C,
                                                     int M, int N, int K, float scale) {
    __shared__ alignas(16) __hip_bfloat16 Ah[64][40], Al[64][40];    // [m][k]
    __shared__ alignas(16) __hip_bfloat16 Bh[128][40], Bl[128][40];  // [n][k] transposed
    int nbx = N >> 7;
    int by = blockIdx.x / nbx, bx = blockIdx.x % nbx;
    int tid = threadIdx.x, lane = tid & 63, w = tid >> 6;
    int ml = lane & 15, kq = lane >> 4;

    f32x4 acc[4][2];
#pragma unroll
    for (int i = 0; i < 4; ++i)
#pragma unroll
        for (int j = 0; j < 2; ++j) acc[i][j] = (f32x4){0.f, 0.f, 0.f, 0.f};

    const float* Ab = A + (size_t)(by * 64) * K;
    const float* Bb = Bm + bx * 128;
    int ar = tid >> 2, akq = (tid & 3) * 8;   // A stage: row, 8-k chunk
    int bcol = tid & 127, bkh = tid >> 7;     // B stage: col, 16-k half

    for (int k0 = 0; k0 < K; k0 += 32) {
        {
            float av[8];
            *(float4*)&av[0] = *(const float4*)(Ab + (size_t)ar * K + k0 + akq);
            *(float4*)&av[4] = *(const float4*)(Ab + (size_t)ar * K + k0 + akq + 4);
            short8 hv, lv;
#pragma unroll
            for (int e = 0; e < 8; ++e) {
                __hip_bfloat16 hb = __float2bfloat16(av[e]);
                hv[e] = ((BF16S){hb}).s;
                lv[e] = f2bs(av[e] - __bfloat162float(hb));
            }
            *(short8*)&Ah[ar][akq] = hv;
            *(short8*)&Al[ar][akq] = lv;
        }
        {
            float be[16];
            const float* bp = Bb + (size_t)(k0 + bkh * 16) * N + bcol;
#pragma unroll
            for (int j = 0; j < 16; ++j) be[j] = bp[(size_t)j * N];
            short8 h0, h1, l0, l1;
#pragma unroll
            for (int e = 0; e < 8; ++e) {
                __hip_bfloat16 hb = __float2bfloat16(be[e]);
                h0[e] = ((BF16S){hb}).s;
                l0[e] = f2bs(be[e] - __bfloat162float(hb));
                __hip_bfloat16 hb2 = __float2bfloat16(be[e + 8]);
                h1[e] = ((BF16S){hb2}).s;
                l1[e] = f2bs(be[e + 8] - __bfloat162float(hb2));
            }
            *(short8*)&Bh[bcol][bkh * 16] = h0;
            *(short8*)&Bh[bcol][bkh * 16 + 8] = h1;
            *(short8*)&Bl[bcol][bkh * 16] = l0;
            *(short8*)&Bl[bcol][bkh * 16 + 8] = l1;
        }
        __syncthreads();
        short8 ah[4], al[4], bh[2], bl[2];
#pragma unroll
        for (int mt = 0; mt < 4; ++mt) {
            ah[mt] = *(const short8*)&Ah[mt * 16 + ml][kq * 8];
            al[mt] = *(const short8*)&Al[mt * 16 + ml][kq * 8];
        }
#pragma unroll
        for (int nt = 0; nt < 2; ++nt) {
            bh[nt] = *(const short8*)&Bh[w * 32 + nt * 16 + ml][kq * 8];
            bl[nt] = *(const short8*)&Bl[w * 32 + nt * 16 + ml][kq * 8];
        }
#pragma unroll
        for (int mt = 0; mt < 4; ++mt)
#pragma unroll
            for (int nt = 0; nt < 2; ++nt) {
                acc[mt][nt] = __builtin_amdgcn_mfma_f32_16x16x32_bf16(ah[mt], bh[nt], acc[mt][nt], 0, 0, 0);
                acc[mt][nt] = __builtin_amdgcn_mfma_f32_16x16x32_bf16(ah[mt], bl[nt], acc[mt][nt], 0, 0, 0);
                acc[mt][nt] = __builtin_amdgcn_mfma_f32_16x16x32_bf16(al[mt], bh[nt], acc[mt][nt], 0, 0, 0);
            }
        __syncthreads();
    }
#pragma unroll
    for (int mt = 0; mt < 4; ++mt)
#pragma unroll
        for (int nt = 0; nt < 2; ++nt)
#pragma unroll
            for (int r = 0; r < 4; ++r) {
                int row = by * 64 + mt * 16 + kq * 4 + r;
                int col = bx * 128 + w * 32 + nt * 16 + ml;
                C[(size_t)row * N + col] = acc[mt][nt][r] * scale;
            }
}

// ================= plain bf16 MFMA GEMM (v, fc). Tile 64x128, BK=32.
__global__ __launch_bounds__(256) void mfma_gemm_v2(const float* __restrict__ A,
                                                    const float* __restrict__ Bm,
                                                    float* __restrict__ C,
                                                    int M, int N, int K, float scale) {
    __shared__ alignas(16) __hip_bfloat16 Asb[64][40];   // [m][k]
    __shared__ alignas(16) __hip_bfloat16 Bsb[128][40];  // [n][k] transposed
    int nbx = N >> 7;
    int by = blockIdx.x / nbx, bx = blockIdx.x % nbx;
    int tid = threadIdx.x, lane = tid & 63, w = tid >> 6;
    int ml = lane & 15, kq = lane >> 4;

    f32x4 acc[4][2];
#pragma unroll
    for (int i = 0; i < 4; ++i)
#pragma unroll
        for (int j = 0; j < 2; ++j) acc[i][j] = (f32x4){0.f, 0.f, 0.f, 0.f};

    const float* Ab = A + (size_t)(by * 64) * K;
    const float* Bb = Bm + bx * 128;
    int ar = tid >> 2, akq = (tid & 3) * 8;
    int bcol = tid & 127, bkh = tid >> 7;

    for (int k0 = 0; k0 < K; k0 += 32) {
        {
            float av[8];
            *(float4*)&av[0] = *(const float4*)(Ab + (size_t)ar * K + k0 + akq);
            *(float4*)&av[4] = *(const float4*)(Ab + (size_t)ar * K + k0 + akq + 4);
            short8 hv;
#pragma unroll
            for (int e = 0; e < 8; ++e) hv[e] = f2bs(av[e]);
            *(short8*)&Asb[ar][akq] = hv;
        }
        {
            float be[16];
            const float* bp = Bb + (size_t)(k0 + bkh * 16) * N + bcol;
#pragma unroll
            for (int j = 0; j < 16; ++j) be[j] = bp[(size_t)j * N];
            short8 h0, h1;
#pragma unroll
            for (int e = 0; e < 8; ++e) {
                h0[e] = f2bs(be[e]);
                h1[e] = f2bs(be[e + 8]);
            }
            *(short8*)&Bsb[bcol][bkh * 16] = h0;
            *(short8*)&Bsb[bcol][bkh * 16 + 8] = h1;
        }
        __syncthreads();
        short8 af[4], bf[2];
#pragma unroll
        for (int mt = 0; mt < 4; ++mt) af[mt] = *(const short8*)&Asb[mt * 16 + ml][kq * 8];
#pragma unroll
        for (int nt = 0; nt < 2; ++nt) bf[nt] = *(const short8*)&Bsb[w * 32 + nt * 16 + ml][kq * 8];
#pragma unroll
        for (int mt = 0; mt < 4; ++mt)
#pragma unroll
            for (int nt = 0; nt < 2; ++nt)
                acc[mt][nt] = __builtin_amdgcn_mfma_f32_16x16x32_bf16(af[mt], bf[nt], acc[mt][nt], 0, 0, 0);
        __syncthreads();
    }
#pragma unroll
    for (int mt = 0; mt < 4; ++mt)
#pragma unroll
        for (int nt = 0; nt < 2; ++nt)
#pragma unroll
            for (int r = 0; r < 4; ++r) {
                int row = by * 64 + mt * 16 + kq * 4 + r;
                int col = bx * 128 + w * 32 + nt * 16 + ml;
                C[(size_t)row * N + col] = acc[mt][nt][r] * scale;
            }
}

// ================= m-score v3: one wave per (b,h,l); lane = (sample slot, d-chunk).
__global__ void m_score_v3(const float* __restrict__ q, const float* __restrict__ k,
                           const int* __restrict__ idxs, float* __restrict__ m_out) {
    int gwave = blockIdx.x * 4 + (threadIdx.x >> 6);
    int lane = threadIdx.x & 63;
    if (gwave >= B_ * H_ * S_) return;
    int l = gwave % S_;
    int bh = gwave / S_;
    int h = bh & 15, b = bh >> 4;
    int sl = lane >> 3;   // sample slot 0..7
    int dc = lane & 7;    // d-chunk 0..7 (8 floats each)

    const float* qr = q + ((size_t)(b * S_ + l)) * DM_ + h * DK_ + dc * 8;
    float4 q0 = *(const float4*)qr;
    float4 q1 = *(const float4*)(qr + 4);
    const float* kb = k + (size_t)b * S_ * DM_ + h * DK_ + dc * 8;

    float mx = -INFINITY, sm = 0.f;
#pragma unroll
    for (int c = 0; c < 5; ++c) {
        int s = c * 8 + sl;
        int idx = idxs[l * SK_ + s];
        idx = (idx < 0) ? 0 : (idx >= S_ ? S_ - 1 : idx);
        const float* kr = kb + (size_t)idx * DM_;
        float4 k0 = *(const float4*)kr;
        float4 k1 = *(const float4*)(kr + 4);
        float d = q0.x * k0.x + q0.y * k0.y + q0.z * k0.z + q0.w * k0.w +
                  q1.x * k1.x + q1.y * k1.y + q1.z * k1.z + q1.w * k1.w;
        d += __shfl_xor(d, 1, 64);
        d += __shfl_xor(d, 2, 64);
        d += __shfl_xor(d, 4, 64);
        mx = fmaxf(mx, d);
        sm += d;
    }
#pragma unroll
    for (int off = 8; off <= 32; off <<= 1) {
        mx = fmaxf(mx, __shfl_xor(mx, off, 64));
        sm += __shfl_xor(sm, off, 64);
    }
    if (lane == 0) m_out[(size_t)bh * S_ + l] = mx - sm * (1.f / (float)S_);
}

// ================= top-40, single wave per (b,h), register-resident, barrier-free.
// Lane i owns m[j*64+i], j=0..31, in registers. 40 x (shuffle argmax + winner fixup).
// Tie-break: higher value wins; equal value -> lower global index (matches lax.top_k).
__global__ void topk_wave(const float* __restrict__ m, int* __restrict__ mtop) {
    int bh = blockIdx.x;
    int lane = threadIdx.x;  // 64 threads
    const float* mb = m + (size_t)bh * S_;
    float vals[32];
#pragma unroll
    for (int j = 0; j < 32; ++j) vals[j] = mb[j * 64 + lane];
    float lmax = -INFINITY;
    int lj = 0;
#pragma unroll
    for (int j = 0; j < 32; ++j)
        if (vals[j] > lmax) { lmax = vals[j]; lj = j; }

    for (int it = 0; it < U_; ++it) {
        float wv = lmax;
        int wi = lj * 64 + lane;  // global index
#pragma unroll
        for (int off = 1; off < 64; off <<= 1) {
            float ov = __shfl_xor(wv, off, 64);
            int oi = __shfl_xor(wi, off, 64);
            if (ov > wv || (ov == wv && oi < wi)) { wv = ov; wi = oi; }
        }
        if (lane == 0) mtop[bh * U_ + it] = wi;
        if ((wi & 63) == lane) {
            int jw = wi >> 6;
#pragma unroll
            for (int t = 0; t < 32; ++t)
                if (t == jw) vals[t] = -INFINITY;
            lmax = -INFINITY;
            lj = 0;
#pragma unroll
            for (int t = 0; t < 32; ++t)
                if (vals[t] > lmax) { lmax = vals[t]; lj = t; }
        }
    }
}

// ================= v mean, stage 1: block per (bh, 32-row chunk) -> partial sums
__global__ void vmean_part(const float* __restrict__ v, float* __restrict__ vpart) {
    __shared__ float part[4][DK_];
    int blk = blockIdx.x;               // bh*VCH_ + ch
    int bh = blk >> 6, ch = blk & (VCH_ - 1);
    int b = bh >> 4, h = bh & 15;
    int tid = threadIdx.x, wave = tid >> 6, lane = tid & 63;
    const float* vb = v + (size_t)(b * S_ + ch * 32) * DM_ + h * DK_;
    float s = 0.f;
#pragma unroll
    for (int i = 0; i < 8; ++i)
        s += vb[(size_t)(i * 4 + wave) * DM_ + lane];
    part[wave][lane] = s;
    __syncthreads();
    if (tid < DK_)
        vpart[(size_t)blk * DK_ + tid] =
            part[0][tid] + part[1][tid] + part[2][tid] + part[3][tid];
}

// ================= v mean, stage 2: 32 blocks x 64 threads
__global__ void vmean_comb(const float* __restrict__ vpart, float* __restrict__ vm) {
    int bh = blockIdx.x, lane = threadIdx.x;
    float s = 0.f;
    for (int c = 0; c < VCH_; ++c)
        s += vpart[(size_t)(bh * VCH_ + c) * DK_ + lane];
    vm[bh * DK_ + lane] = s * (1.f / (float)S_);
}

// ================= gather selected q rows -> qsel[bh][48][64] (rows 40..47 zero)
__global__ void gather_qsel(const float* __restrict__ q, const int* __restrict__ mtop,
                            float* __restrict__ qsel) {
    int bh = blockIdx.x;
    int b = bh >> 4, h = bh & 15;
    int tid = threadIdx.x;
    int u = tid >> 2, dq = (tid & 3) * 16;
    if (u >= 48) return;
    float* dst = qsel + ((size_t)bh * 48 + u) * 64 + dq;
    if (u < U_) {
        int row = mtop[bh * U_ + u];
        row = (row < 0) ? 0 : (row >= S_ ? S_ - 1 : row);
        const float* src = q + ((size_t)(b * S_ + row)) * DM_ + h * DK_ + dq;
#pragma unroll
        for (int j = 0; j < 16; j += 4) *(float4*)(dst + j) = *(const float4*)(src + j);
    } else {
        float4 z = {0.f, 0.f, 0.f, 0.f};
#pragma unroll
        for (int j = 0; j < 16; j += 4) *(float4*)(dst + j) = z;
    }
}

// ================= split-K flash attention, block per (b,h,chunk). 512 blocks.
__global__ __launch_bounds__(256) void attn_chunk(const float* __restrict__ qsel,
                                                  const float* __restrict__ k,
                                                  const float* __restrict__ v,
                                                  float* __restrict__ Opart,
                                                  float* __restrict__ Mpart,
                                                  float* __restrict__ Lpart) {
    __shared__ alignas(16) __hip_bfloat16 Qs[48][72];    // [u][d]
    __shared__ alignas(16) __hip_bfloat16 Vt[64][136];   // [d][k-in-chunk]
    __shared__ alignas(16) __hip_bfloat16 Ps[48][136];   // [u][k-in-chunk]
    __shared__ float mpart[4][48], lpart[4][48];
    __shared__ float mrow[48];
    int blk = blockIdx.x;
    int bh = blk / NCH_, ch = blk % NCH_;
    int b = bh >> 4, h = bh & 15;
    int c0 = ch * CH_;
    int tid = threadIdx.x, lane = tid & 63, w = tid >> 6;
    int ml = lane & 15, kq = lane >> 4;

    {
        int u = tid >> 2, dq = (tid & 3) * 16;
        if (u < 48) {
            const float* src = qsel + ((size_t)bh * 48 + u) * 64 + dq;
#pragma unroll
            for (int j = 0; j < 16; j += 4) {
                float4 v4 = *(const float4*)(src + j);
                Qs[u][dq + j + 0] = __float2bfloat16(v4.x);
                Qs[u][dq + j + 1] = __float2bfloat16(v4.y);
                Qs[u][dq + j + 2] = __float2bfloat16(v4.z);
                Qs[u][dq + j + 3] = __float2bfloat16(v4.w);
            }
        }
    }
    {
        int klocal = tid >> 1, dq = (tid & 1) * 32;
        const float* vr = v + (size_t)(b * S_ + c0 + klocal) * DM_ + h * DK_ + dq;
#pragma unroll
        for (int jj = 0; jj < 32; jj += 4) {
            float4 v4 = *(const float4*)(vr + jj);
            Vt[dq + jj + 0][klocal] = __float2bfloat16(v4.x);
            Vt[dq + jj + 1][klocal] = __float2bfloat16(v4.y);
            Vt[dq + jj + 2][klocal] = __float2bfloat16(v4.z);
            Vt[dq + jj + 3][klocal] = __float2bfloat16(v4.w);
        }
    }
    __syncthreads();

    const float* Kb = k + (size_t)b * S_ * DM_ + h * DK_;
    f32x4 sreg[3][2];
#pragma unroll
    for (int i = 0; i < 3; ++i)
#pragma unroll
        for (int j = 0; j < 2; ++j) sreg[i][j] = (f32x4){0.f, 0.f, 0.f, 0.f};
#pragma unroll
    for (int ntl = 0; ntl < 2; ++ntl) {
        int krow = c0 + (w * 2 + ntl) * 16 + ml;
        const float* kr = Kb + (size_t)krow * DM_;
        float4 x0 = *(const float4*)(kr + kq * 8);
        float4 x1 = *(const float4*)(kr + kq * 8 + 4);
        float4 y0 = *(const float4*)(kr + 32 + kq * 8);
        float4 y1 = *(const float4*)(kr + 32 + kq * 8 + 4);
        short8 b0, b1;
        b0[0] = f2bs(x0.x); b0[1] = f2bs(x0.y); b0[2] = f2bs(x0.z); b0[3] = f2bs(x0.w);
        b0[4] = f2bs(x1.x); b0[5] = f2bs(x1.y); b0[6] = f2bs(x1.z); b0[7] = f2bs(x1.w);
        b1[0] = f2bs(y0.x); b1[1] = f2bs(y0.y); b1[2] = f2bs(y0.z); b1[3] = f2bs(y0.w);
        b1[4] = f2bs(y1.x); b1[5] = f2bs(y1.y); b1[6] = f2bs(y1.z); b1[7] = f2bs(y1.w);
#pragma unroll
        for (int mt = 0; mt < 3; ++mt) {
            short8 a0 = *(const short8*)&Qs[mt * 16 + ml][kq * 8];
            short8 a1 = *(const short8*)&Qs[mt * 16 + ml][32 + kq * 8];
            sreg[mt][ntl] = __builtin_amdgcn_mfma_f32_16x16x32_bf16(a0, b0, sreg[mt][ntl], 0, 0, 0);
            sreg[mt][ntl] = __builtin_amdgcn_mfma_f32_16x16x32_bf16(a1, b1, sreg[mt][ntl], 0, 0, 0);
        }
    }

    {
        float vmx[3][4];
#pragma unroll
        for (int mt = 0; mt < 3; ++mt)
#pragma unroll
            for (int r = 0; r < 4; ++r)
                vmx[mt][r] = fmaxf(sreg[mt][0][r], sreg[mt][1][r]);
#pragma unroll
        for (int mask = 1; mask <= 8; mask <<= 1)
#pragma unroll
            for (int mt = 0; mt < 3; ++mt)
#pragma unroll
                for (int r = 0; r < 4; ++r)
                    vmx[mt][r] = fmaxf(vmx[mt][r], __shfl_xor(vmx[mt][r], mask, 64));
        if (ml == 0)
#pragma unroll
            for (int mt = 0; mt < 3; ++mt)
#pragma unroll
                for (int r = 0; r < 4; ++r)
                    mpart[w][mt * 16 + kq * 4 + r] = vmx[mt][r];
    }
    __syncthreads();
    if (tid < 48)
        mrow[tid] = fmaxf(fmaxf(mpart[0][tid], mpart[1][tid]),
                          fmaxf(mpart[2][tid], mpart[3][tid]));
    __syncthreads();

    {
        float vsum[3][4] = {{0.f}};
#pragma unroll
        for (int mt = 0; mt < 3; ++mt)
#pragma unroll
            for (int ntl = 0; ntl < 2; ++ntl) {
                int col = (w * 2 + ntl) * 16 + ml;
#pragma unroll
                for (int r = 0; r < 4; ++r) {
                    int row = mt * 16 + kq * 4 + r;
                    float p = __expf(sreg[mt][ntl][r] - mrow[row]);
                    Ps[row][col] = __float2bfloat16(p);
                    vsum[mt][r] += p;
                }
            }
#pragma unroll
        for (int mask = 1; mask <= 8; mask <<= 1)
#pragma unroll
            for (int mt = 0; mt < 3; ++mt)
#pragma unroll
                for (int r = 0; r < 4; ++r)
                    vsum[mt][r] += __shfl_xor(vsum[mt][r], mask, 64);
        if (ml == 0)
#pragma unroll
            for (int mt = 0; mt < 3; ++mt)
#pragma unroll
                for (int r = 0; r < 4; ++r)
                    lpart[w][mt * 16 + kq * 4 + r] = vsum[mt][r];
    }
    __syncthreads();

    f32x4 oreg[3];
#pragma unroll
    for (int i = 0; i < 3; ++i) oreg[i] = (f32x4){0.f, 0.f, 0.f, 0.f};
#pragma unroll
    for (int kt = 0; kt < 4; ++kt) {
        short8 bfq = *(const short8*)&Vt[w * 16 + ml][kt * 32 + kq * 8];
#pragma unroll
        for (int mt = 0; mt < 3; ++mt) {
            short8 af = *(const short8*)&Ps[mt * 16 + ml][kt * 32 + kq * 8];
            oreg[mt] = __builtin_amdgcn_mfma_f32_16x16x32_bf16(af, bfq, oreg[mt], 0, 0, 0);
        }
    }
#pragma unroll
    for (int mt = 0; mt < 3; ++mt)
#pragma unroll
        for (int r = 0; r < 4; ++r) {
            int row = mt * 16 + kq * 4 + r;
            Opart[((size_t)blk * 48 + row) * 64 + w * 16 + ml] = oreg[mt][r];
        }
    if (tid < 48) {
        Mpart[(size_t)blk * 48 + tid] = mrow[tid];
        Lpart[(size_t)blk * 48 + tid] =
            lpart[0][tid] + lpart[1][tid] + lpart[2][tid] + lpart[3][tid];
    }
}

// ================= combine chunk partials -> upd (block per bh)
__global__ void attn_combine(const float* __restrict__ Opart, const float* __restrict__ Mpart,
                             const float* __restrict__ Lpart, float* __restrict__ upd) {
    __shared__ float wfac[NCH_][48];
    __shared__ float lfin[48];
    int bh = blockIdx.x, tid = threadIdx.x;
    if (tid < 48) {
        float m = -1e30f;
        for (int c = 0; c < NCH_; ++c)
            m = fmaxf(m, Mpart[(size_t)(bh * NCH_ + c) * 48 + tid]);
        float l = 0.f;
        for (int c = 0; c < NCH_; ++c) {
            float wf = __expf(Mpart[(size_t)(bh * NCH_ + c) * 48 + tid] - m);
            wfac[c][tid] = wf;
            l += wf * Lpart[(size_t)(bh * NCH_ + c) * 48 + tid];
        }
        lfin[tid] = l;
    }
    __syncthreads();
    for (int e = tid; e < U_ * DK_; e += 256) {
        int row = e >> 6, col = e & 63;
        float o = 0.f;
        for (int c = 0; c < NCH_; ++c)
            o += wfac[c][row] * Opart[((size_t)(bh * NCH_ + c) * 48 + row) * 64 + col];
        upd[((size_t)bh * U_ + row) * DK_ + col] = o / lfin[row];
    }
}

// ================= ctx = broadcast v_mean (fp32, float4)
__global__ void ctx_fill(const float* __restrict__ vm, float* __restrict__ ctx) {
    size_t i = ((size_t)blockIdx.x * 256 + threadIdx.x) * 4;  // over B*S*DM
    int c = (int)(i & (DM_ - 1));
    size_t bl = i >> 10;
    int b = (int)(bl >> 11);
    int h = c >> 6, d = c & (DK_ - 1);
    *(float4*)(ctx + i) = *(const float4*)(vm + (b * H_ + h) * DK_ + d);
}

// ================= scatter upd rows into ctx
__global__ void ctx_scatter(const float* __restrict__ upd, const int* __restrict__ mtop,
                            float* __restrict__ ctx) {
    int blk = blockIdx.x;
    int bh = blk / U_;
    int b = bh / H_, h = bh % H_;
    int lane = threadIdx.x;
    int row = mtop[blk];
    row = (row < 0) ? 0 : (row >= S_ ? S_ - 1 : row);
    ctx[((size_t)(b * S_ + row)) * DM_ + h * DK_ + lane] = upd[(size_t)blk * DK_ + lane];
}

// ================= bias + residual + LayerNorm
__global__ void ln_kernel(const float* __restrict__ fcout, const float* __restrict__ fcb,
                          const float* __restrict__ resid,
                          const float* __restrict__ lnw, const float* __restrict__ lnb,
                          float* __restrict__ out) {
    __shared__ float red[256];
    int row = blockIdx.x, tid = threadIdx.x;
    float x[4];
#pragma unroll
    for (int j = 0; j < 4; ++j) {
        int c = tid + j * 256;
        x[j] = fcout[(size_t)row * DM_ + c] + fcb[c] + resid[(size_t)row * DM_ + c];
    }
    float s = x[0] + x[1] + x[2] + x[3];
    red[tid] = s;
    __syncthreads();
    for (int st = 128; st; st >>= 1) {
        if (tid < st) red[tid] += red[tid + st];
        __syncthreads();
    }
    float mu = red[0] * (1.f / (float)DM_);
    __syncthreads();
    float vs = 0.f;
#pragma unroll
    for (int j = 0; j < 4; ++j) { float d = x[j] - mu; vs += d * d; }
    red[tid] = vs;
    __syncthreads();
    for (int st = 128; st; st >>= 1) {
        if (tid < st) red[tid] += red[tid + st];
        __syncthreads();
    }
    float rstd = rsqrtf(red[0] * (1.f / (float)DM_) + 1e-6f);
#pragma unroll
    for (int j = 0; j < 4; ++j) {
        int c = tid + j * 256;
        out[(size_t)row * DM_ + c] = (x[j] - mu) * rstd * lnw[c] + lnb[c];
    }
}

// ================= launch =================

extern "C" void kernel_launch(void* const* d_in, const int* in_sizes, int n_in,
                              void* d_out, int out_size, void* d_ws, size_t ws_size,
                              hipStream_t stream) {
    if (n_in < 9 || d_ws == nullptr || d_out == nullptr) return;
    if (ws_size < 34ull * 1024 * 1024) return;

    const float* hs  = (const float*)d_in[0];
    const float* wq  = (const float*)d_in[1];
    const float* wk  = (const float*)d_in[2];
    const float* wv  = (const float*)d_in[3];
    const float* fcw = (const float*)d_in[4];
    const float* fcb = (const float*)d_in[5];
    const float* lnw = (const float*)d_in[6];
    const float* lnb = (const float*)d_in[7];
    const int* idxs  = (const int*)d_in[8];

    const size_t MD = (size_t)B_ * S_ * DM_;  // 4194304
    const int M = B_ * S_;                    // 4096
    float* ws = (float*)d_ws;
    float* out = (float*)d_out;

    float* q = ws;
    float* k = ws + MD;
    float* mbuf = ws + 2 * MD;                             // B*H*S = 65536 f
    float* vmean = mbuf + (size_t)B_ * H_ * S_;            // 2048 f
    float* upd = vmean + B_ * H_ * DK_;                    // 81920 f
    int* mtop = (int*)(upd + (size_t)B_ * H_ * U_ * DK_);  // 1280 i
    float* qsel = (float*)(mtop + B_ * H_ * U_);           // 98304 f
    float* vpart = qsel + (size_t)B_ * H_ * 48 * 64;       // 131072 f
    float* v = out;
    float* Opart = q;                                 // q dead post-gather
    float* Mpart = Opart + (size_t)512 * 48 * 64;
    float* Lpart = Mpart + (size_t)512 * 48;
    float* ctx = q;    // after Opart dead (post-combine)
    float* fcout = k;  // after k dead (post-attn_chunk)

    gemm_qk_split<<<512, 256, 0, stream>>>(hs, wq, q, M, DM_, DM_, 0.125f);  // 1/sqrt(64)
    gemm_qk_split<<<512, 256, 0, stream>>>(hs, wk, k, M, DM_, DM_, 1.0f);
    mfma_gemm_v2<<<512, 256, 0, stream>>>(hs, wv, v, M, DM_, DM_, 1.0f);

    m_score_v3<<<(B_ * H_ * S_) / 4, 256, 0, stream>>>(q, k, idxs, mbuf);
    topk_wave<<<B_ * H_, 64, 0, stream>>>(mbuf, mtop);
    vmean_part<<<B_ * H_ * VCH_, 256, 0, stream>>>(v, vpart);
    vmean_comb<<<B_ * H_, 64, 0, stream>>>(vpart, vmean);
    gather_qsel<<<B_ * H_, 256, 0, stream>>>(q, mtop, qsel);

    attn_chunk<<<B_ * H_ * NCH_, 256, 0, stream>>>(qsel, k, v, Opart, Mpart, Lpart);
    attn_combine<<<B_ * H_, 256, 0, stream>>>(Opart, Mpart, Lpart, upd);

    ctx_fill<<<(int)(MD / 1024), 256, 0, stream>>>(vmean, ctx);
    ctx_scatter<<<B_ * H_ * U_, 64, 0, stream>>>(upd, mtop, ctx);

    mfma_gemm_v2<<<512, 256, 0, stream>>>(ctx, fcw, fcout, M, DM_, DM_, 1.0f);
    ln_kernel<<<M, 256, 0, stream>>>(fcout, fcb, hs, lnw, lnb, out);
}

// Round 13
// 353.539 us; speedup vs baseline: 4.4683x; 1.0108x over previous
//
#include <hip/hip_runtime.h>
#include <hip/hip_bf16.h>

#define B_  2
#define S_  2048
#define DM_ 1024
#define H_  16
#define DK_ 64
#define SK_ 40   // SAMPLE_K
#define U_  40   // top-k u
#define CH_ 128  // attn chunk columns
#define NCH_ (S_ / CH_)  // 16
#define VCH_ 64  // vmean chunks per (b,h)

typedef __attribute__((ext_vector_type(8))) short short8;
typedef __attribute__((ext_vector_type(4))) float f32x4;

union BF16S { __hip_bfloat16 h; short s; };
static __device__ __forceinline__ short f2bs(float x) {
    BF16S u; u.h = __float2bfloat16(x); return u.s;
}

// ================= fused q/k/v projection GEMM, one dispatch.
// grid = 64 row-tiles x {q,k,v} x 8 col-tiles (adjacent blocks share A rows
// for L2 reuse). q/k use split-bf16 3-MFMA (fp32 fidelity ~1e-5 for the
// top-k decision boundary); v uses plain bf16.
__global__ __launch_bounds__(256) void gemm_qkv(const float* __restrict__ hs,
                                                const float* __restrict__ wq,
                                                const float* __restrict__ wk,
                                                const float* __restrict__ wv,
                                                float* __restrict__ q,
                                                float* __restrict__ k,
                                                float* __restrict__ v) {
    __shared__ alignas(16) __hip_bfloat16 Ah[64][40], Al[64][40];    // [m][k]
    __shared__ alignas(16) __hip_bfloat16 Bh[128][40], Bl[128][40];  // [n][k] transposed
    int idx = blockIdx.x;
    int by = idx / 24;
    int r = idx % 24;
    int mode = r >> 3, bx = r & 7;
    const float* Bm = (mode == 0) ? wq : (mode == 1) ? wk : wv;
    float* C = (mode == 0) ? q : (mode == 1) ? k : v;
    float scale = (mode == 0) ? 0.125f : 1.0f;  // 1/sqrt(64) for q
    bool split = (mode < 2);

    int tid = threadIdx.x, lane = tid & 63, w = tid >> 6;
    int ml = lane & 15, kq = lane >> 4;

    f32x4 acc[4][2];
#pragma unroll
    for (int i = 0; i < 4; ++i)
#pragma unroll
        for (int j = 0; j < 2; ++j) acc[i][j] = (f32x4){0.f, 0.f, 0.f, 0.f};

    const float* Ab = hs + (size_t)(by * 64) * DM_;
    const float* Bb = Bm + bx * 128;
    int ar = tid >> 2, akq = (tid & 3) * 8;   // A stage: row, 8-k chunk
    int bcol = tid & 127, bkh = tid >> 7;     // B stage: col, 16-k half

    for (int k0 = 0; k0 < DM_; k0 += 32) {
        // ---- stage A: k-contiguous read, b128 writes
        {
            float av[8];
            *(float4*)&av[0] = *(const float4*)(Ab + (size_t)ar * DM_ + k0 + akq);
            *(float4*)&av[4] = *(const float4*)(Ab + (size_t)ar * DM_ + k0 + akq + 4);
            short8 hv, lv;
#pragma unroll
            for (int e = 0; e < 8; ++e) {
                __hip_bfloat16 hb = __float2bfloat16(av[e]);
                hv[e] = ((BF16S){hb}).s;
                lv[e] = f2bs(av[e] - __bfloat162float(hb));
            }
            *(short8*)&Ah[ar][akq] = hv;
            if (split) *(short8*)&Al[ar][akq] = lv;
        }
        // ---- stage B: 16 coalesced k-strided loads, b128 writes
        {
            float be[16];
            const float* bp = Bb + (size_t)(k0 + bkh * 16) * DM_ + bcol;
#pragma unroll
            for (int j = 0; j < 16; ++j) be[j] = bp[(size_t)j * DM_];
            short8 h0, h1, l0, l1;
#pragma unroll
            for (int e = 0; e < 8; ++e) {
                __hip_bfloat16 hb = __float2bfloat16(be[e]);
                h0[e] = ((BF16S){hb}).s;
                l0[e] = f2bs(be[e] - __bfloat162float(hb));
                __hip_bfloat16 hb2 = __float2bfloat16(be[e + 8]);
                h1[e] = ((BF16S){hb2}).s;
                l1[e] = f2bs(be[e + 8] - __bfloat162float(hb2));
            }
            *(short8*)&Bh[bcol][bkh * 16] = h0;
            *(short8*)&Bh[bcol][bkh * 16 + 8] = h1;
            if (split) {
                *(short8*)&Bl[bcol][bkh * 16] = l0;
                *(short8*)&Bl[bcol][bkh * 16 + 8] = l1;
            }
        }
        __syncthreads();
        short8 ah[4], al[4], bh[2], bl[2];
#pragma unroll
        for (int mt = 0; mt < 4; ++mt) ah[mt] = *(const short8*)&Ah[mt * 16 + ml][kq * 8];
#pragma unroll
        for (int nt = 0; nt < 2; ++nt) bh[nt] = *(const short8*)&Bh[w * 32 + nt * 16 + ml][kq * 8];
        if (split) {
#pragma unroll
            for (int mt = 0; mt < 4; ++mt) al[mt] = *(const short8*)&Al[mt * 16 + ml][kq * 8];
#pragma unroll
            for (int nt = 0; nt < 2; ++nt) bl[nt] = *(const short8*)&Bl[w * 32 + nt * 16 + ml][kq * 8];
#pragma unroll
            for (int mt = 0; mt < 4; ++mt)
#pragma unroll
                for (int nt = 0; nt < 2; ++nt) {
                    acc[mt][nt] = __builtin_amdgcn_mfma_f32_16x16x32_bf16(ah[mt], bh[nt], acc[mt][nt], 0, 0, 0);
                    acc[mt][nt] = __builtin_amdgcn_mfma_f32_16x16x32_bf16(ah[mt], bl[nt], acc[mt][nt], 0, 0, 0);
                    acc[mt][nt] = __builtin_amdgcn_mfma_f32_16x16x32_bf16(al[mt], bh[nt], acc[mt][nt], 0, 0, 0);
                }
        } else {
#pragma unroll
            for (int mt = 0; mt < 4; ++mt)
#pragma unroll
                for (int nt = 0; nt < 2; ++nt)
                    acc[mt][nt] = __builtin_amdgcn_mfma_f32_16x16x32_bf16(ah[mt], bh[nt], acc[mt][nt], 0, 0, 0);
        }
        __syncthreads();
    }
#pragma unroll
    for (int mt = 0; mt < 4; ++mt)
#pragma unroll
        for (int nt = 0; nt < 2; ++nt)
#pragma unroll
            for (int r2 = 0; r2 < 4; ++r2) {
                int row = by * 64 + mt * 16 + kq * 4 + r2;
                int col = bx * 128 + w * 32 + nt * 16 + ml;
                C[(size_t)row * DM_ + col] = acc[mt][nt][r2] * scale;
            }
}

// ================= plain bf16 MFMA GEMM (fc). Tile 64x128, BK=32.
__global__ __launch_bounds__(256) void mfma_gemm_v2(const float* __restrict__ A,
                                                    const float* __restrict__ Bm,
                                                    float* __restrict__ C,
                                                    int M, int N, int K, float scale) {
    __shared__ alignas(16) __hip_bfloat16 Asb[64][40];   // [m][k]
    __shared__ alignas(16) __hip_bfloat16 Bsb[128][40];  // [n][k] transposed
    int nbx = N >> 7;
    int by = blockIdx.x / nbx, bx = blockIdx.x % nbx;
    int tid = threadIdx.x, lane = tid & 63, w = tid >> 6;
    int ml = lane & 15, kq = lane >> 4;

    f32x4 acc[4][2];
#pragma unroll
    for (int i = 0; i < 4; ++i)
#pragma unroll
        for (int j = 0; j < 2; ++j) acc[i][j] = (f32x4){0.f, 0.f, 0.f, 0.f};

    const float* Ab = A + (size_t)(by * 64) * K;
    const float* Bb = Bm + bx * 128;
    int ar = tid >> 2, akq = (tid & 3) * 8;
    int bcol = tid & 127, bkh = tid >> 7;

    for (int k0 = 0; k0 < K; k0 += 32) {
        {
            float av[8];
            *(float4*)&av[0] = *(const float4*)(Ab + (size_t)ar * K + k0 + akq);
            *(float4*)&av[4] = *(const float4*)(Ab + (size_t)ar * K + k0 + akq + 4);
            short8 hv;
#pragma unroll
            for (int e = 0; e < 8; ++e) hv[e] = f2bs(av[e]);
            *(short8*)&Asb[ar][akq] = hv;
        }
        {
            float be[16];
            const float* bp = Bb + (size_t)(k0 + bkh * 16) * N + bcol;
#pragma unroll
            for (int j = 0; j < 16; ++j) be[j] = bp[(size_t)j * N];
            short8 h0, h1;
#pragma unroll
            for (int e = 0; e < 8; ++e) {
                h0[e] = f2bs(be[e]);
                h1[e] = f2bs(be[e + 8]);
            }
            *(short8*)&Bsb[bcol][bkh * 16] = h0;
            *(short8*)&Bsb[bcol][bkh * 16 + 8] = h1;
        }
        __syncthreads();
        short8 af[4], bf[2];
#pragma unroll
        for (int mt = 0; mt < 4; ++mt) af[mt] = *(const short8*)&Asb[mt * 16 + ml][kq * 8];
#pragma unroll
        for (int nt = 0; nt < 2; ++nt) bf[nt] = *(const short8*)&Bsb[w * 32 + nt * 16 + ml][kq * 8];
#pragma unroll
        for (int mt = 0; mt < 4; ++mt)
#pragma unroll
            for (int nt = 0; nt < 2; ++nt)
                acc[mt][nt] = __builtin_amdgcn_mfma_f32_16x16x32_bf16(af[mt], bf[nt], acc[mt][nt], 0, 0, 0);
        __syncthreads();
    }
#pragma unroll
    for (int mt = 0; mt < 4; ++mt)
#pragma unroll
        for (int nt = 0; nt < 2; ++nt)
#pragma unroll
            for (int r = 0; r < 4; ++r) {
                int row = by * 64 + mt * 16 + kq * 4 + r;
                int col = bx * 128 + w * 32 + nt * 16 + ml;
                C[(size_t)row * N + col] = acc[mt][nt][r] * scale;
            }
}

// ================= m-score v3 + rowmap init. lane = (sample slot, d-chunk).
__global__ void m_score_v3(const float* __restrict__ q, const float* __restrict__ k,
                           const int* __restrict__ idxs, float* __restrict__ m_out,
                           int* __restrict__ rowmap) {
    int gwave = blockIdx.x * 4 + (threadIdx.x >> 6);
    int lane = threadIdx.x & 63;
    if (gwave >= B_ * H_ * S_) return;
    int l = gwave % S_;
    int bh = gwave / S_;
    int h = bh & 15, b = bh >> 4;
    int sl = lane >> 3;   // sample slot 0..7
    int dc = lane & 7;    // d-chunk 0..7 (8 floats each)

    const float* qr = q + ((size_t)(b * S_ + l)) * DM_ + h * DK_ + dc * 8;
    float4 q0 = *(const float4*)qr;
    float4 q1 = *(const float4*)(qr + 4);
    const float* kb = k + (size_t)b * S_ * DM_ + h * DK_ + dc * 8;

    float mx = -INFINITY, sm = 0.f;
#pragma unroll
    for (int c = 0; c < 5; ++c) {
        int s = c * 8 + sl;
        int idx = idxs[l * SK_ + s];
        idx = (idx < 0) ? 0 : (idx >= S_ ? S_ - 1 : idx);
        const float* kr = kb + (size_t)idx * DM_;
        float4 k0 = *(const float4*)kr;
        float4 k1 = *(const float4*)(kr + 4);
        float d = q0.x * k0.x + q0.y * k0.y + q0.z * k0.z + q0.w * k0.w +
                  q1.x * k1.x + q1.y * k1.y + q1.z * k1.z + q1.w * k1.w;
        d += __shfl_xor(d, 1, 64);
        d += __shfl_xor(d, 2, 64);
        d += __shfl_xor(d, 4, 64);
        mx = fmaxf(mx, d);
        sm += d;
    }
#pragma unroll
    for (int off = 8; off <= 32; off <<= 1) {
        mx = fmaxf(mx, __shfl_xor(mx, off, 64));
        sm += __shfl_xor(sm, off, 64);
    }
    if (lane == 0) {
        m_out[(size_t)bh * S_ + l] = mx - sm * (1.f / (float)S_);
        rowmap[(size_t)bh * S_ + l] = -1;
    }
}

// ================= top-40, single wave per (b,h), register-resident, barrier-free.
__global__ void topk_wave(const float* __restrict__ m, int* __restrict__ mtop,
                          int* __restrict__ rowmap) {
    int bh = blockIdx.x;
    int lane = threadIdx.x;  // 64 threads
    const float* mb = m + (size_t)bh * S_;
    float vals[32];
#pragma unroll
    for (int j = 0; j < 32; ++j) vals[j] = mb[j * 64 + lane];
    float lmax = -INFINITY;
    int lj = 0;
#pragma unroll
    for (int j = 0; j < 32; ++j)
        if (vals[j] > lmax) { lmax = vals[j]; lj = j; }

    for (int it = 0; it < U_; ++it) {
        float wv = lmax;
        int wi = lj * 64 + lane;  // global index
#pragma unroll
        for (int off = 1; off < 64; off <<= 1) {
            float ov = __shfl_xor(wv, off, 64);
            int oi = __shfl_xor(wi, off, 64);
            if (ov > wv || (ov == wv && oi < wi)) { wv = ov; wi = oi; }
        }
        if (lane == 0) {
            mtop[bh * U_ + it] = wi;
            rowmap[(size_t)bh * S_ + wi] = it;
        }
        if ((wi & 63) == lane) {
            int jw = wi >> 6;
#pragma unroll
            for (int t = 0; t < 32; ++t)
                if (t == jw) vals[t] = -INFINITY;
            lmax = -INFINITY;
            lj = 0;
#pragma unroll
            for (int t = 0; t < 32; ++t)
                if (vals[t] > lmax) { lmax = vals[t]; lj = t; }
        }
    }
}

// ================= v mean, stage 1
__global__ void vmean_part(const float* __restrict__ v, float* __restrict__ vpart) {
    __shared__ float part[4][DK_];
    int blk = blockIdx.x;               // bh*VCH_ + ch
    int bh = blk >> 6, ch = blk & (VCH_ - 1);
    int b = bh >> 4, h = bh & 15;
    int tid = threadIdx.x, wave = tid >> 6, lane = tid & 63;
    const float* vb = v + (size_t)(b * S_ + ch * 32) * DM_ + h * DK_;
    float s = 0.f;
#pragma unroll
    for (int i = 0; i < 8; ++i)
        s += vb[(size_t)(i * 4 + wave) * DM_ + lane];
    part[wave][lane] = s;
    __syncthreads();
    if (tid < DK_)
        vpart[(size_t)blk * DK_ + tid] =
            part[0][tid] + part[1][tid] + part[2][tid] + part[3][tid];
}

// ================= v mean, stage 2
__global__ void vmean_comb(const float* __restrict__ vpart, float* __restrict__ vm) {
    int bh = blockIdx.x, lane = threadIdx.x;
    float s = 0.f;
    for (int c = 0; c < VCH_; ++c)
        s += vpart[(size_t)(bh * VCH_ + c) * DK_ + lane];
    vm[bh * DK_ + lane] = s * (1.f / (float)S_);
}

// ================= gather selected q rows -> qsel[bh][48][64] (rows 40..47 zero)
__global__ void gather_qsel(const float* __restrict__ q, const int* __restrict__ mtop,
                            float* __restrict__ qsel) {
    int bh = blockIdx.x;
    int b = bh >> 4, h = bh & 15;
    int tid = threadIdx.x;
    int u = tid >> 2, dq = (tid & 3) * 16;
    if (u >= 48) return;
    float* dst = qsel + ((size_t)bh * 48 + u) * 64 + dq;
    if (u < U_) {
        int row = mtop[bh * U_ + u];
        row = (row < 0) ? 0 : (row >= S_ ? S_ - 1 : row);
        const float* src = q + ((size_t)(b * S_ + row)) * DM_ + h * DK_ + dq;
#pragma unroll
        for (int j = 0; j < 16; j += 4) *(float4*)(dst + j) = *(const float4*)(src + j);
    } else {
        float4 z = {0.f, 0.f, 0.f, 0.f};
#pragma unroll
        for (int j = 0; j < 16; j += 4) *(float4*)(dst + j) = z;
    }
}

// ================= split-K flash attention, block per (b,h,chunk). 512 blocks.
__global__ __launch_bounds__(256) void attn_chunk(const float* __restrict__ qsel,
                                                  const float* __restrict__ k,
                                                  const float* __restrict__ v,
                                                  float* __restrict__ Opart,
                                                  float* __restrict__ Mpart,
                                                  float* __restrict__ Lpart) {
    __shared__ alignas(16) __hip_bfloat16 Qs[48][72];    // [u][d]
    __shared__ alignas(16) __hip_bfloat16 Vt[64][136];   // [d][k-in-chunk]
    __shared__ alignas(16) __hip_bfloat16 Ps[48][136];   // [u][k-in-chunk]
    __shared__ float mpart[4][48], lpart[4][48];
    __shared__ float mrow[48];
    int blk = blockIdx.x;
    int bh = blk / NCH_, ch = blk % NCH_;
    int b = bh >> 4, h = bh & 15;
    int c0 = ch * CH_;
    int tid = threadIdx.x, lane = tid & 63, w = tid >> 6;
    int ml = lane & 15, kq = lane >> 4;

    {
        int u = tid >> 2, dq = (tid & 3) * 16;
        if (u < 48) {
            const float* src = qsel + ((size_t)bh * 48 + u) * 64 + dq;
#pragma unroll
            for (int j = 0; j < 16; j += 4) {
                float4 v4 = *(const float4*)(src + j);
                Qs[u][dq + j + 0] = __float2bfloat16(v4.x);
                Qs[u][dq + j + 1] = __float2bfloat16(v4.y);
                Qs[u][dq + j + 2] = __float2bfloat16(v4.z);
                Qs[u][dq + j + 3] = __float2bfloat16(v4.w);
            }
        }
    }
    {
        int klocal = tid >> 1, dq = (tid & 1) * 32;
        const float* vr = v + (size_t)(b * S_ + c0 + klocal) * DM_ + h * DK_ + dq;
#pragma unroll
        for (int jj = 0; jj < 32; jj += 4) {
            float4 v4 = *(const float4*)(vr + jj);
            Vt[dq + jj + 0][klocal] = __float2bfloat16(v4.x);
            Vt[dq + jj + 1][klocal] = __float2bfloat16(v4.y);
            Vt[dq + jj + 2][klocal] = __float2bfloat16(v4.z);
            Vt[dq + jj + 3][klocal] = __float2bfloat16(v4.w);
        }
    }
    __syncthreads();

    const float* Kb = k + (size_t)b * S_ * DM_ + h * DK_;
    f32x4 sreg[3][2];
#pragma unroll
    for (int i = 0; i < 3; ++i)
#pragma unroll
        for (int j = 0; j < 2; ++j) sreg[i][j] = (f32x4){0.f, 0.f, 0.f, 0.f};
#pragma unroll
    for (int ntl = 0; ntl < 2; ++ntl) {
        int krow = c0 + (w * 2 + ntl) * 16 + ml;
        const float* kr = Kb + (size_t)krow * DM_;
        float4 x0 = *(const float4*)(kr + kq * 8);
        float4 x1 = *(const float4*)(kr + kq * 8 + 4);
        float4 y0 = *(const float4*)(kr + 32 + kq * 8);
        float4 y1 = *(const float4*)(kr + 32 + kq * 8 + 4);
        short8 b0, b1;
        b0[0] = f2bs(x0.x); b0[1] = f2bs(x0.y); b0[2] = f2bs(x0.z); b0[3] = f2bs(x0.w);
        b0[4] = f2bs(x1.x); b0[5] = f2bs(x1.y); b0[6] = f2bs(x1.z); b0[7] = f2bs(x1.w);
        b1[0] = f2bs(y0.x); b1[1] = f2bs(y0.y); b1[2] = f2bs(y0.z); b1[3] = f2bs(y0.w);
        b1[4] = f2bs(y1.x); b1[5] = f2bs(y1.y); b1[6] = f2bs(y1.z); b1[7] = f2bs(y1.w);
#pragma unroll
        for (int mt = 0; mt < 3; ++mt) {
            short8 a0 = *(const short8*)&Qs[mt * 16 + ml][kq * 8];
            short8 a1 = *(const short8*)&Qs[mt * 16 + ml][32 + kq * 8];
            sreg[mt][ntl] = __builtin_amdgcn_mfma_f32_16x16x32_bf16(a0, b0, sreg[mt][ntl], 0, 0, 0);
            sreg[mt][ntl] = __builtin_amdgcn_mfma_f32_16x16x32_bf16(a1, b1, sreg[mt][ntl], 0, 0, 0);
        }
    }

    {
        float vmx[3][4];
#pragma unroll
        for (int mt = 0; mt < 3; ++mt)
#pragma unroll
            for (int r = 0; r < 4; ++r)
                vmx[mt][r] = fmaxf(sreg[mt][0][r], sreg[mt][1][r]);
#pragma unroll
        for (int mask = 1; mask <= 8; mask <<= 1)
#pragma unroll
            for (int mt = 0; mt < 3; ++mt)
#pragma unroll
                for (int r = 0; r < 4; ++r)
                    vmx[mt][r] = fmaxf(vmx[mt][r], __shfl_xor(vmx[mt][r], mask, 64));
        if (ml == 0)
#pragma unroll
            for (int mt = 0; mt < 3; ++mt)
#pragma unroll
                for (int r = 0; r < 4; ++r)
                    mpart[w][mt * 16 + kq * 4 + r] = vmx[mt][r];
    }
    __syncthreads();
    if (tid < 48)
        mrow[tid] = fmaxf(fmaxf(mpart[0][tid], mpart[1][tid]),
                          fmaxf(mpart[2][tid], mpart[3][tid]));
    __syncthreads();

    {
        float vsum[3][4] = {{0.f}};
#pragma unroll
        for (int mt = 0; mt < 3; ++mt)
#pragma unroll
            for (int ntl = 0; ntl < 2; ++ntl) {
                int col = (w * 2 + ntl) * 16 + ml;
#pragma unroll
                for (int r = 0; r < 4; ++r) {
                    int row = mt * 16 + kq * 4 + r;
                    float p = __expf(sreg[mt][ntl][r] - mrow[row]);
                    Ps[row][col] = __float2bfloat16(p);
                    vsum[mt][r] += p;
                }
            }
#pragma unroll
        for (int mask = 1; mask <= 8; mask <<= 1)
#pragma unroll
            for (int mt = 0; mt < 3; ++mt)
#pragma unroll
                for (int r = 0; r < 4; ++r)
                    vsum[mt][r] += __shfl_xor(vsum[mt][r], mask, 64);
        if (ml == 0)
#pragma unroll
            for (int mt = 0; mt < 3; ++mt)
#pragma unroll
                for (int r = 0; r < 4; ++r)
                    lpart[w][mt * 16 + kq * 4 + r] = vsum[mt][r];
    }
    __syncthreads();

    f32x4 oreg[3];
#pragma unroll
    for (int i = 0; i < 3; ++i) oreg[i] = (f32x4){0.f, 0.f, 0.f, 0.f};
#pragma unroll
    for (int kt = 0; kt < 4; ++kt) {
        short8 bfq = *(const short8*)&Vt[w * 16 + ml][kt * 32 + kq * 8];
#pragma unroll
        for (int mt = 0; mt < 3; ++mt) {
            short8 af = *(const short8*)&Ps[mt * 16 + ml][kt * 32 + kq * 8];
            oreg[mt] = __builtin_amdgcn_mfma_f32_16x16x32_bf16(af, bfq, oreg[mt], 0, 0, 0);
        }
    }
#pragma unroll
    for (int mt = 0; mt < 3; ++mt)
#pragma unroll
        for (int r = 0; r < 4; ++r) {
            int row = mt * 16 + kq * 4 + r;
            Opart[((size_t)blk * 48 + row) * 64 + w * 16 + ml] = oreg[mt][r];
        }
    if (tid < 48) {
        Mpart[(size_t)blk * 48 + tid] = mrow[tid];
        Lpart[(size_t)blk * 48 + tid] =
            lpart[0][tid] + lpart[1][tid] + lpart[2][tid] + lpart[3][tid];
    }
}

// ================= combine chunk partials -> upd (block per bh)
__global__ void attn_combine(const float* __restrict__ Opart, const float* __restrict__ Mpart,
                             const float* __restrict__ Lpart, float* __restrict__ upd) {
    __shared__ float wfac[NCH_][48];
    __shared__ float lfin[48];
    int bh = blockIdx.x, tid = threadIdx.x;
    if (tid < 48) {
        float m = -1e30f;
        for (int c = 0; c < NCH_; ++c)
            m = fmaxf(m, Mpart[(size_t)(bh * NCH_ + c) * 48 + tid]);
        float l = 0.f;
        for (int c = 0; c < NCH_; ++c) {
            float wf = __expf(Mpart[(size_t)(bh * NCH_ + c) * 48 + tid] - m);
            wfac[c][tid] = wf;
            l += wf * Lpart[(size_t)(bh * NCH_ + c) * 48 + tid];
        }
        lfin[tid] = l;
    }
    __syncthreads();
    for (int e = tid; e < U_ * DK_; e += 256) {
        int row = e >> 6, col = e & 63;
        float o = 0.f;
        for (int c = 0; c < NCH_; ++c)
            o += wfac[c][row] * Opart[((size_t)(bh * NCH_ + c) * 48 + row) * 64 + col];
        upd[((size_t)bh * U_ + row) * DK_ + col] = o / lfin[row];
    }
}

// ================= ctx one-pass: upd row if selected else vmean (float4)
__global__ void ctx_fill2(const float* __restrict__ vm, const float* __restrict__ upd,
                          const int* __restrict__ rowmap, float* __restrict__ ctx) {
    size_t i = ((size_t)blockIdx.x * 256 + threadIdx.x) * 4;  // over B*S*DM
    int c = (int)(i & (DM_ - 1));
    size_t bl = i >> 10;
    int l = (int)(bl & (S_ - 1));
    int b = (int)(bl >> 11);
    int h = c >> 6, d = c & (DK_ - 1);
    int bh = b * H_ + h;
    int u = rowmap[(size_t)bh * S_ + l];
    float4 val;
    if (u >= 0)
        val = *(const float4*)(upd + ((size_t)bh * U_ + u) * DK_ + d);
    else
        val = *(const float4*)(vm + bh * DK_ + d);
    *(float4*)(ctx + i) = val;
}

// ================= bias + residual + LayerNorm
__global__ void ln_kernel(const float* __restrict__ fcout, const float* __restrict__ fcb,
                          const float* __restrict__ resid,
                          const float* __restrict__ lnw, const float* __restrict__ lnb,
                          float* __restrict__ out) {
    __shared__ float red[256];
    int row = blockIdx.x, tid = threadIdx.x;
    float x[4];
#pragma unroll
    for (int j = 0; j < 4; ++j) {
        int c = tid + j * 256;
        x[j] = fcout[(size_t)row * DM_ + c] + fcb[c] + resid[(size_t)row * DM_ + c];
    }
    float s = x[0] + x[1] + x[2] + x[3];
    red[tid] = s;
    __syncthreads();
    for (int st = 128; st; st >>= 1) {
        if (tid < st) red[tid] += red[tid + st];
        __syncthreads();
    }
    float mu = red[0] * (1.f / (float)DM_);
    __syncthreads();
    float vs = 0.f;
#pragma unroll
    for (int j = 0; j < 4; ++j) { float d = x[j] - mu; vs += d * d; }
    red[tid] = vs;
    __syncthreads();
    for (int st = 128; st; st >>= 1) {
        if (tid < st) red[tid] += red[tid + st];
        __syncthreads();
    }
    float rstd = rsqrtf(red[0] * (1.f / (float)DM_) + 1e-6f);
#pragma unroll
    for (int j = 0; j < 4; ++j) {
        int c = tid + j * 256;
        out[(size_t)row * DM_ + c] = (x[j] - mu) * rstd * lnw[c] + lnb[c];
    }
}

// ================= launch =================

extern "C" void kernel_launch(void* const* d_in, const int* in_sizes, int n_in,
                              void* d_out, int out_size, void* d_ws, size_t ws_size,
                              hipStream_t stream) {
    if (n_in < 9 || d_ws == nullptr || d_out == nullptr) return;
    if (ws_size < 34ull * 1024 * 1024) return;

    const float* hs  = (const float*)d_in[0];
    const float* wq  = (const float*)d_in[1];
    const float* wk  = (const float*)d_in[2];
    const float* wv  = (const float*)d_in[3];
    const float* fcw = (const float*)d_in[4];
    const float* fcb = (const float*)d_in[5];
    const float* lnw = (const float*)d_in[6];
    const float* lnb = (const float*)d_in[7];
    const int* idxs  = (const int*)d_in[8];

    const size_t MD = (size_t)B_ * S_ * DM_;  // 4194304
    const int M = B_ * S_;                    // 4096
    float* ws = (float*)d_ws;
    float* out = (float*)d_out;

    float* q = ws;
    float* k = ws + MD;
    float* mbuf = ws + 2 * MD;                             // B*H*S = 65536 f
    float* vmean = mbuf + (size_t)B_ * H_ * S_;            // 2048 f
    float* upd = vmean + B_ * H_ * DK_;                    // 81920 f
    int* mtop = (int*)(upd + (size_t)B_ * H_ * U_ * DK_);  // 1280 i
    float* qsel = (float*)(mtop + B_ * H_ * U_);           // 98304 f
    float* vpart = qsel + (size_t)B_ * H_ * 48 * 64;       // 131072 f
    int* rowmap = (int*)(vpart + (size_t)B_ * H_ * VCH_ * DK_);  // 65536 i
    float* v = out;
    float* Opart = q;                                 // q dead post-gather
    float* Mpart = Opart + (size_t)512 * 48 * 64;
    float* Lpart = Mpart + (size_t)512 * 48;
    float* ctx = q;    // after Opart dead (post-combine)
    float* fcout = k;  // after k dead (post-attn_chunk)

    gemm_qkv<<<1536, 256, 0, stream>>>(hs, wq, wk, wv, q, k, v);

    m_score_v3<<<(B_ * H_ * S_) / 4, 256, 0, stream>>>(q, k, idxs, mbuf, rowmap);
    topk_wave<<<B_ * H_, 64, 0, stream>>>(mbuf, mtop, rowmap);
    vmean_part<<<B_ * H_ * VCH_, 256, 0, stream>>>(v, vpart);
    vmean_comb<<<B_ * H_, 64, 0, stream>>>(vpart, vmean);
    gather_qsel<<<B_ * H_, 256, 0, stream>>>(q, mtop, qsel);

    attn_chunk<<<B_ * H_ * NCH_, 256, 0, stream>>>(qsel, k, v, Opart, Mpart, Lpart);
    attn_combine<<<B_ * H_, 256, 0, stream>>>(Opart, Mpart, Lpart, upd);

    ctx_fill2<<<(int)(MD / 1024), 256, 0, stream>>>(vmean, upd, rowmap, ctx);

    mfma_gemm_v2<<<512, 256, 0, stream>>>(ctx, fcw, fcout, M, DM_, DM_, 1.0f);
    ln_kernel<<<M, 256, 0, stream>>>(fcout, fcb, hs, lnw, lnb, out);
}